// Round 8
// baseline (655.835 us; speedup 1.0000x reference)
//
#include <hip/hip_runtime.h>

typedef unsigned short u16;
typedef unsigned int   u32;
typedef __attribute__((ext_vector_type(4))) float f4_t;
typedef __attribute__((ext_vector_type(4))) unsigned short us4_t;

#define GG 8192
#define PP 24
#define NN 196608
#define EE 786432
#define CAP 176

// ---- packed f32 weight buffer offsets (wb region) ----
#define oWl1 0
#define oWr1 2368
#define obl1 4736
#define obr1 4768
#define oWe1 4800
#define oatt1 5312
#define obo1 5344
#define oWl2 5376
#define oWr2 5632
#define obl2 5888
#define obr2 5896
#define oWe2 5904
#define oatt2 6032
#define obo2 6040
#define ofc1W 6048
#define ofc1b 7008
#define ofc2W 7040
#define ofc2b 7552
#define ofc3W 7568
#define ofc3b 7696
#define ofc4W 7704
#define ofc4b 7736
#define ooutW 7740
#define ooutb 7748

// ---- wq buffer ----
#define oW1I 0        // 76x64 interleaved W1 (rows 74,75 zero) = 4864 floats
#define oW2P 4864     // 32x16 BN-folded W2' = 512 floats
#define oB2P 5376     // 16 floats

__device__ __forceinline__ float bf2f(u16 u){
  union { u32 i; float f; } x; x.i = ((u32)u) << 16; return x.f;
}
__device__ __forceinline__ u32 fkey(float f){
  int i = __float_as_int(f);
  return (i >= 0) ? (((u32)i) | 0x80000000u) : ~((u32)i);
}
__device__ __forceinline__ float funkey(u32 k){
  u32 i = (k & 0x80000000u) ? (k & 0x7FFFFFFFu) : ~k;
  return __uint_as_float(i);
}
__device__ __forceinline__ float lrelu(float m){ return m > 0.f ? m : 0.2f*m; }
__device__ __forceinline__ float sexp(float a){ return __expf(fminf(a, 0.f)); }
__device__ __forceinline__ float ldf(const void* p, size_t i, int isf){
  return isf ? ((const float*)p)[i] : bf2f(((const u16*)p)[i]);
}

__global__ void k_zero(float* __restrict__ out){
  int i = blockIdx.x*256 + threadIdx.x;
  if(i < GG*2) out[i] = 0.f;
}

// ---------------- per-NODE bucketing ----------------
__global__ void k_count(const int* __restrict__ dst, int* __restrict__ cnt){
  int e = blockIdx.x*256 + threadIdx.x;
  if(e < EE){
    u32 d = (u32)dst[e];
    if(d < (u32)NN) atomicAdd(&cnt[d], 1);
  }
}

__global__ void k_scanA(const int* __restrict__ cnt, int* __restrict__ offs,
                        int* __restrict__ bsum){
  __shared__ int part[1024];
  int t = threadIdx.x;
  int i = blockIdx.x*1024 + t;
  int c = cnt[i];
  part[t] = c; __syncthreads();
  for(int off=1; off<1024; off<<=1){
    int v = (t>=off) ? part[t-off] : 0;
    __syncthreads();
    part[t] += v;
    __syncthreads();
  }
  offs[i] = part[t] - c;
  if(t==1023) bsum[blockIdx.x] = part[1023];
}

__global__ void k_scanB(int* __restrict__ bsum, int* __restrict__ offs){
  __shared__ int part[256];
  int t = threadIdx.x;
  int c = (t < 192) ? bsum[t] : 0;
  part[t] = c; __syncthreads();
  for(int off=1; off<256; off<<=1){
    int v = (t>=off) ? part[t-off] : 0;
    __syncthreads();
    part[t] += v;
    __syncthreads();
  }
  if(t < 192) bsum[t] = part[t] - c;
  if(t == 255) offs[NN] = part[255];
}

__global__ void k_scanC(int* __restrict__ offs, const int* __restrict__ bsum,
                        int* __restrict__ cursor){
  int t = threadIdx.x;
  int i = blockIdx.x*1024 + t;
  int v = offs[i] + bsum[blockIdx.x];
  offs[i] = v;
  cursor[i] = v;
}

// pack: sl(5b) | dl(5b)<<5 | edge_id(20b)<<10 ; sorted by dst node
__global__ void k_scatter(const int* __restrict__ src, const int* __restrict__ dst,
                          int* __restrict__ cursor, int* __restrict__ spack){
  int e = blockIdx.x*256 + threadIdx.x;
  if(e < EE){
    u32 d = (u32)dst[e];
    if(d >= (u32)NN) return;
    int g = d / PP;
    int pos = atomicAdd(&cursor[d], 1);
    if((u32)pos < (u32)EE){
      int sl = src[e] - g*PP;
      if((u32)sl > 23u) sl = 0;
      spack[pos] = sl | ((int)(d - g*PP) << 5) | (e << 10);
    }
  }
}

// ---------- mid tier: permute ea into sorted order, f32 16-wide ----------
__global__ void k_eaperm(const int* __restrict__ spack, const int* __restrict__ offs,
                         const void* __restrict__ ea, const int* __restrict__ dflag,
                         float* __restrict__ eap){
  int i = blockIdx.x*256 + threadIdx.x;
  if(i >= EE) return;
  if(i >= offs[NN]) return;
  int isf = dflag[0];
  u32 id = ((u32)spack[i]) >> 10;
  if(id >= (u32)EE) id = 0;
  float* o = eap + (size_t)i*16;
  if(isf){
    const float* er = (const float*)ea + (size_t)id*16;
    #pragma unroll
    for(int q=0;q<4;q++) *(f4_t*)(o + q*4) = *(const f4_t*)(er + q*4);
  } else {
    const u16* er = (const u16*)ea + (size_t)id*16;
    #pragma unroll
    for(int c=0;c<16;c++) o[c] = bf2f(er[c]);
  }
}

// ---------- p tier: permute ea (16 f32) AND project layer-2 p2 = ea@We2 ----------
__global__ void k_eapermB(const int* __restrict__ spack, const int* __restrict__ offs,
                          const void* __restrict__ ea, const int* __restrict__ dflag,
                          const float* __restrict__ wb,
                          float* __restrict__ eap, float* __restrict__ p2){
  int i = blockIdx.x*256 + threadIdx.x;
  if(i >= EE) return;
  if(i >= offs[NN]) return;
  int isf = dflag[0];
  u32 id = ((u32)spack[i]) >> 10;
  if(id >= (u32)EE) id = 0;
  float eav[16];
  if(isf){
    const float* er = (const float*)ea + (size_t)id*16;
    #pragma unroll
    for(int k=0;k<16;k++) eav[k] = er[k];
  } else {
    const u16* er = (const u16*)ea + (size_t)id*16;
    #pragma unroll
    for(int k=0;k<16;k++) eav[k] = bf2f(er[k]);
  }
  float* o = eap + (size_t)i*16;
  #pragma unroll
  for(int q=0;q<4;q++){
    f4_t r; r[0]=eav[q*4+0]; r[1]=eav[q*4+1]; r[2]=eav[q*4+2]; r[3]=eav[q*4+3];
    *(f4_t*)(o + q*4) = r;
  }
  float* o2 = p2 + (size_t)i*8;
  #pragma unroll
  for(int c=0;c<8;c+=4){
    float s0=0.f, s1=0.f, s2=0.f, s3=0.f;
    #pragma unroll
    for(int k=0;k<16;k++){
      f4_t w = *(const f4_t*)(wb + oWe2 + k*8 + c);
      s0 += eav[k]*w[0]; s1 += eav[k]*w[1]; s2 += eav[k]*w[2]; s3 += eav[k]*w[3];
    }
    f4_t r; r[0]=s0; r[1]=s1; r[2]=s2; r[3]=s3;
    *(f4_t*)(o2 + c) = r;
  }
}

// ---------- fused dtype-detect + weight conversion (one block) ----------
__global__ void k_wconv(float* __restrict__ wb, float* __restrict__ wq, int* __restrict__ dflag,
    const u32* __restrict__ xw,
    const void* Wl1, const void* bl1, const void* Wr1, const void* br1,
    const void* We1, const void* att1, const void* bo1,
    const void* Wl2, const void* bl2, const void* Wr2, const void* br2,
    const void* We2, const void* att2, const void* bo2,
    const void* f1W, const void* f1b, const void* f2W, const void* f2b,
    const void* f3W, const void* f3b, const void* f4W, const void* f4b,
    const void* oW,  const void* ob)
{
  __shared__ u32 mx[256];
  int t = threadIdx.x;
  u32 m = 0;
  for(int i=t; i<2048; i+=256){
    u32 e = (xw[i] >> 7) & 0xFFu;
    m = m > e ? m : e;
  }
  mx[t] = m; __syncthreads();
  for(int off=128; off>0; off>>=1){
    if(t<off) mx[t] = mx[t] > mx[t+off] ? mx[t] : mx[t+off];
    __syncthreads();
  }
  int isf = (mx[0] > 140u) ? 1 : 0;
  if(t==0) dflag[0] = isf;
  #define CP(off,src,len) for(int i=t;i<(len);i+=256) wb[(off)+i]=ldf(src,i,isf);
  CP(oWl1,Wl1,2368) CP(oWr1,Wr1,2368) CP(obl1,bl1,32) CP(obr1,br1,32)
  CP(oWe1,We1,512)  CP(oatt1,att1,32) CP(obo1,bo1,32)
  CP(oWl2,Wl2,256)  CP(oWr2,Wr2,256)  CP(obl2,bl2,8)  CP(obr2,br2,8)
  CP(oWe2,We2,128)  CP(oatt2,att2,8)  CP(obo2,bo2,8)
  CP(ofc1W,f1W,960) CP(ofc1b,f1b,32)  CP(ofc2W,f2W,512) CP(ofc2b,f2b,16)
  CP(ofc3W,f3W,128) CP(ofc3b,f3b,8)   CP(ofc4W,f4W,32)  CP(ofc4b,f4b,4)
  CP(ooutW,oW,8)    CP(ooutb,ob,2)
  #undef CP
  for(int i=t; i<76*64; i+=256){
    int k = i>>6, cc = i&63, mat = cc>>5, c = cc&31;
    wq[oW1I + i] = (k < 74) ? ldf(mat ? Wr1 : Wl1, k*32 + c, isf) : 0.f;
  }
}

// ---------- BN-fold for layer 2 ----------
__global__ void k_prep2(float* __restrict__ wq, const float* __restrict__ wb,
                        const float* __restrict__ stats1){
  int t = threadIdx.x;
  for(int i=t; i<512; i+=256){
    int k = i>>4, cc = i&15, mat = cc>>3, c = cc&7;
    wq[oW2P + i] = stats1[k] * wb[(mat ? oWr2 : oWl2) + k*8 + c];
  }
  if(t < 16){
    int mat = t>>3, c = t&7;
    float s = wb[(mat ? obr2 : obl2) + c];
    for(int k=0;k<32;k++) s += stats1[32+k] * wb[(mat ? oWr2 : oWl2) + k*8 + c];
    wq[oB2P + t] = s;
  }
}

// ======== p-tier pass 1: coalesced eap16 reads (round-6 data flow) +
// round-7's verified LDS trim: sP[CAP][32] XOR-swizzled, sPS/sPQ overlay.
// LDS ~31 KB -> 5 blocks/CU.
__global__ __launch_bounds__(256, 5) void k_l1stats_p(
    const void* __restrict__ x, const float* __restrict__ eap,
    const float* __restrict__ wb, const float* __restrict__ wq,
    const int* __restrict__ offs, const int* __restrict__ spack, const int* __restrict__ dflag,
    float* __restrict__ p1sum, float* __restrict__ p1sq,
    float* __restrict__ h1)
{
  __shared__ __align__(16) float sP[CAP][32];    // ea@We1, f4-XOR-swizzled; later PS/PQ overlay
  __shared__ __align__(16) float sXl[24][36];
  __shared__ __align__(16) float sXr[24][36];
  __shared__ float sEv[CAP];
  __shared__ int   sSl[CAP];
  __shared__ int   sRO[25];

  const int t = threadIdx.x;
  const int g = blockIdx.x;
  const int isf = dflag[0];
  const int nb = g*PP;
  const int eb = offs[nb];
  int ecnt = offs[nb+24] - eb;
  if(ecnt < 0) ecnt = 0; if(ecnt > CAP) ecnt = CAP;

  if(t < 25){
    int v = offs[nb+t] - eb;
    if(v < 0) v = 0; if(v > CAP) v = CAP;
    sRO[t] = v;
  }
  for(int i=t; i<ecnt; i+=256){
    int sl = spack[eb+i] & 31; if(sl > 23) sl = 0;
    sSl[i] = sl;
  }

  // ---- phase A1: projection xl/xr (wave w -> rows 6w..6w+5) ----
  {
    const int c = t & 31, mat = (t>>5)&1, w = t>>6, cc = t&63;
    const float* gW = wq + oW1I;
    float bi = wb[(mat ? obr1 : obl1) + c];
    float acc[6];
    #pragma unroll
    for(int j=0;j<6;j++) acc[j] = bi;
    if(isf){
      const float* xr0 = (const float*)x + (size_t)(nb + w*6)*96;
      for(int kb=0; kb<19; kb++){
        float w0 = gW[(kb*4+0)*64 + cc];
        float w1 = gW[(kb*4+1)*64 + cc];
        float w2 = gW[(kb*4+2)*64 + cc];
        float w3 = gW[(kb*4+3)*64 + cc];
        #pragma unroll
        for(int j=0;j<6;j++){
          f4_t xv = *(const f4_t*)(xr0 + (size_t)j*96 + kb*4);
          acc[j] += xv[0]*w0 + xv[1]*w1 + xv[2]*w2 + xv[3]*w3;
        }
      }
    } else {
      const u16* xr0 = (const u16*)x + (size_t)(nb + w*6)*96;
      for(int kb=0; kb<19; kb++){
        float w0 = gW[(kb*4+0)*64 + cc];
        float w1 = gW[(kb*4+1)*64 + cc];
        float w2 = gW[(kb*4+2)*64 + cc];
        float w3 = gW[(kb*4+3)*64 + cc];
        #pragma unroll
        for(int j=0;j<6;j++){
          us4_t xv = *(const us4_t*)(xr0 + (size_t)j*96 + kb*4);
          acc[j] += bf2f(xv[0])*w0 + bf2f(xv[1])*w1 + bf2f(xv[2])*w2 + bf2f(xv[3])*w3;
        }
      }
    }
    if(mat){
      #pragma unroll
      for(int j=0;j<6;j++) sXr[w*6+j][c] = acc[j];
    } else {
      #pragma unroll
      for(int j=0;j<6;j++) sXl[w*6+j][c] = acc[j];
    }
  }

  // ---- phase A2: p1 into LDS from coalesced eap16 (L1-hot row reuse) ----
  for(int i=t; i<ecnt*8; i+=256){
    int e = i>>3, q = i&7;
    const float* er = eap + (size_t)(eb+e)*16;   // 8 tasks share this 64-B row
    float s0=0.f, s1=0.f, s2=0.f, s3=0.f;
    #pragma unroll
    for(int k=0;k<16;k++){
      float ev = er[k];
      f4_t w = *(const f4_t*)(wb + oWe1 + k*32 + q*4);
      s0 += ev*w[0]; s1 += ev*w[1]; s2 += ev*w[2]; s3 += ev*w[3];
    }
    f4_t r; r[0]=s0; r[1]=s1; r[2]=s2; r[3]=s3;
    *(f4_t*)&sP[e][((q ^ (e&7))*4)] = r;         // XOR-swizzled f4 slot
  }
  __syncthreads();   // barrier 1

  f4_t outv = {0.f,0.f,0.f,0.f}, sqv = {0.f,0.f,0.f,0.f};
  int rr = 0, ss = 0;
  if(t < 192){       // 8 lanes per row, 24 rows in parallel
    const int r = t >> 3, sub = t & 7;
    rr = r; ss = sub;
    const int a = sRO[r], b = sRO[r+1];
    const int deg = b - a;
    const float* att = wb + oatt1;

    // e-values: lane owns edges a+sub, a+sub+8, ... ; p1 from swizzled LDS
    float emax = -3.4e38f;
    for(int e=a+sub; e<b; e+=8){
      int sl = sSl[e];
      int ex = e & 7;
      float ev = 0.f;
      #pragma unroll
      for(int q=0;q<8;q++){
        f4_t pv  = *(const f4_t*)&sP[e][((q ^ ex)*4)];
        f4_t xlv = *(const f4_t*)&sXl[sl][q*4];
        f4_t xrv = *(const f4_t*)&sXr[r][q*4];
        ev += att[q*4+0]*lrelu(xlv[0]+xrv[0]+pv[0]);
        ev += att[q*4+1]*lrelu(xlv[1]+xrv[1]+pv[1]);
        ev += att[q*4+2]*lrelu(xlv[2]+xrv[2]+pv[2]);
        ev += att[q*4+3]*lrelu(xlv[3]+xrv[3]+pv[3]);
      }
      sEv[e] = ev;
      emax = fmaxf(emax, ev);
    }
    emax = fmaxf(emax, __shfl_xor(emax, 1));
    emax = fmaxf(emax, __shfl_xor(emax, 2));
    emax = fmaxf(emax, __shfl_xor(emax, 4));

    // self-loop via linearity: mean of p1 over edges; lane owns cols sub*4..+3
    float m0=0.f, m1=0.f, m2=0.f, m3=0.f;
    for(int e=a; e<b; ++e){
      f4_t pv = *(const f4_t*)&sP[e][((sub ^ (e&7))*4)];
      m0 += pv[0]; m1 += pv[1]; m2 += pv[2]; m3 += pv[3];
    }
    float invd = 1.f / (float)(deg > 0 ? deg : 1);
    float sv;
    {
      int c0 = sub*4;
      sv  = att[c0+0]*lrelu(sXl[r][c0+0] + sXr[r][c0+0] + m0*invd);
      sv += att[c0+1]*lrelu(sXl[r][c0+1] + sXr[r][c0+1] + m1*invd);
      sv += att[c0+2]*lrelu(sXl[r][c0+2] + sXr[r][c0+2] + m2*invd);
      sv += att[c0+3]*lrelu(sXl[r][c0+3] + sXr[r][c0+3] + m3*invd);
    }
    sv += __shfl_xor(sv, 1);
    sv += __shfl_xor(sv, 2);
    sv += __shfl_xor(sv, 4);

    // softmax (z in place in sEv)
    float m = fmaxf(emax, sv);
    float ssum = 0.f;
    for(int e=a+sub; e<b; e+=8){
      float z = sexp(sEv[e] - m);
      sEv[e] = z;
      ssum += z;
    }
    ssum += __shfl_xor(ssum, 1);
    ssum += __shfl_xor(ssum, 2);
    ssum += __shfl_xor(ssum, 4);
    float selfZ = sexp(sv - m);
    float rden = 1.f / fmaxf(ssum + selfZ, 1e-30f);

    // aggregation: lane owns cols sub*4..+3
    float a0=0.f, a1=0.f, a2=0.f, a3=0.f;
    for(int e=a; e<b; ++e){
      float z = sEv[e];
      f4_t xlv = *(const f4_t*)&sXl[sSl[e]][sub*4];
      a0 += z*xlv[0]; a1 += z*xlv[1]; a2 += z*xlv[2]; a3 += z*xlv[3];
    }
    f4_t xself = *(const f4_t*)&sXl[r][sub*4];
    {
      float o;
      o = (a0 + selfZ*xself[0]) * rden; o = fmaxf(o + wb[obo1+sub*4+0], 0.f); outv[0]=o; sqv[0]=o*o;
      o = (a1 + selfZ*xself[1]) * rden; o = fmaxf(o + wb[obo1+sub*4+1], 0.f); outv[1]=o; sqv[1]=o*o;
      o = (a2 + selfZ*xself[2]) * rden; o = fmaxf(o + wb[obo1+sub*4+2], 0.f); outv[2]=o; sqv[2]=o*o;
      o = (a3 + selfZ*xself[3]) * rden; o = fmaxf(o + wb[obo1+sub*4+3], 0.f); outv[3]=o; sqv[3]=o*o;
    }
    *(f4_t*)&h1[((size_t)nb + r)*32 + sub*4] = outv;
  }
  __syncthreads();   // barrier 2: all sP reads complete -> overlay is safe

  float (*sPS)[32] = (float(*)[32])&sP[0][0];
  float (*sPQ)[32] = (float(*)[32])&sP[24][0];
  if(t < 192){
    *(f4_t*)&sPS[rr][ss*4] = outv;
    *(f4_t*)&sPQ[rr][ss*4] = sqv;
  }
  __syncthreads();   // barrier 3
  if(t < 32){
    float s=0.f, q=0.f;
    #pragma unroll
    for(int r=0;r<24;r++){ s += sPS[r][t]; q += sPQ[r][t]; }
    p1sum[g*32+t] = s; p1sq[g*32+t] = q;
  }
}

// ======== p-tier pass 2: layer2 from h1, rows fully parallel, p2 precomputed ========
__global__ __launch_bounds__(256, 6) void k_fused2_p(
    const float* __restrict__ p2,
    const float* __restrict__ wb, const float* __restrict__ wq,
    const float* __restrict__ h1,
    const int* __restrict__ offs, const int* __restrict__ spack,
    float* __restrict__ gsum2, float* __restrict__ gsq2)
{
  __shared__ float sXl2[24][13];
  __shared__ float sXr2[24][13];
  __shared__ float sEv[CAP];
  __shared__ int   sSl[CAP];
  __shared__ int   sRO[25];
  __shared__ float sGS[24][8];
  __shared__ float sGQ[24][8];

  const int t = threadIdx.x;
  const int g = blockIdx.x;
  const int wid = t >> 6;
  const int lane = t & 63;
  const int nb = g*PP;
  const int eb = offs[nb];
  int ecnt = offs[nb+24] - eb;
  if(ecnt < 0) ecnt = 0; if(ecnt > CAP) ecnt = CAP;

  if(t < 25){
    int v = offs[nb+t] - eb;
    if(v < 0) v = 0; if(v > CAP) v = CAP;
    sRO[t] = v;
  }
  for(int i=t; i<ecnt; i+=256){
    int sl = spack[eb+i] & 31; if(sl > 23) sl = 0;
    sSl[i] = sl;
  }
  // projection xl2/xr2 (BN folded): wave wid computes rows 6*wid..6*wid+5
  {
    int rz = wid*6;
    for(int i=lane; i<96; i+=64){
      int rl = i>>4, cc = i&15;
      int r = rz + rl;
      float s = wq[oB2P + cc];
      const float* hr = h1 + ((size_t)nb + r)*32;
      #pragma unroll
      for(int q=0;q<8;q++){
        f4_t hv = *(const f4_t*)(hr + q*4);
        s += hv[0]*wq[oW2P+(q*4+0)*16+cc] + hv[1]*wq[oW2P+(q*4+1)*16+cc]
           + hv[2]*wq[oW2P+(q*4+2)*16+cc] + hv[3]*wq[oW2P+(q*4+3)*16+cc];
      }
      if(cc < 8) sXl2[r][cc] = s; else sXr2[r][cc-8] = s;
    }
  }
  __syncthreads();   // barrier 1

  if(t < 192){
    const int r = t >> 3, sub = t & 7;
    const int a = sRO[r], b = sRO[r+1];
    const int deg = b - a;
    const float* att2 = wb + oatt2;

    float emax = -3.4e38f;
    for(int e=a+sub; e<b; e+=8){
      int sl = sSl[e];
      const float* pe = p2 + (size_t)(eb+e)*8;
      float ev = 0.f;
      #pragma unroll
      for(int j=0;j<8;j++)
        ev += att2[j]*lrelu(sXl2[sl][j] + sXr2[r][j] + pe[j]);
      sEv[e] = ev;
      emax = fmaxf(emax, ev);
    }
    emax = fmaxf(emax, __shfl_xor(emax, 1));
    emax = fmaxf(emax, __shfl_xor(emax, 2));
    emax = fmaxf(emax, __shfl_xor(emax, 4));

    // self-loop via mean p2; lane owns col sub
    float mpc = 0.f;
    for(int e=a; e<b; ++e)
      mpc += p2[(size_t)(eb+e)*8 + sub];
    float invd = 1.f / (float)(deg > 0 ? deg : 1);
    float sv = att2[sub]*lrelu(sXl2[r][sub] + sXr2[r][sub] + mpc*invd);
    sv += __shfl_xor(sv, 1);
    sv += __shfl_xor(sv, 2);
    sv += __shfl_xor(sv, 4);

    float m = fmaxf(emax, sv);
    float ssum = 0.f;
    for(int e=a+sub; e<b; e+=8){
      float z = sexp(sEv[e] - m);
      sEv[e] = z;
      ssum += z;
    }
    ssum += __shfl_xor(ssum, 1);
    ssum += __shfl_xor(ssum, 2);
    ssum += __shfl_xor(ssum, 4);
    float selfZ = sexp(sv - m);
    float rden = 1.f / fmaxf(ssum + selfZ, 1e-30f);

    float acc = 0.f;
    for(int e=a; e<b; ++e)
      acc += sEv[e] * sXl2[sSl[e]][sub];
    float o = (acc + selfZ*sXl2[r][sub]) * rden;
    float s = 1.f / (1.f + __expf(-(o + wb[obo2+sub])));
    sGS[r][sub] = s;
    sGQ[r][sub] = s*s;
  }
  __syncthreads();   // barrier 2
  if(t < 8){
    float gs=0.f, gq=0.f;
    #pragma unroll
    for(int r=0;r<24;r++){ gs += sGS[r][t]; gq += sGQ[r][t]; }
    gsum2[g*8+t] = gs; gsq2[g*8+t] = gq;
  }
}

// ======== mid tier (round-3) kernels, verbatim fallback ========
__global__ __launch_bounds__(256, 6) void k_l1stats(
    const void* __restrict__ x, const void* __restrict__ ea, const float* __restrict__ eap,
    const float* __restrict__ wb, const float* __restrict__ wq,
    const int* __restrict__ offs, const int* __restrict__ spack, const int* __restrict__ dflag,
    float* __restrict__ p1sum, float* __restrict__ p1sq,
    float* __restrict__ h1, int use_h1)
{
  __shared__ __align__(16) float sEaF[CAP][16];
  __shared__ __align__(16) float sXl[24][36];
  __shared__ float sXr[24][33];
  __shared__ float sEaSum[24][17];
  __shared__ float sEv[CAP];
  __shared__ int   sSl[CAP];
  __shared__ int   sRO[25];
  __shared__ float sSelfE[24];
  __shared__ float sPS[4][32], sPQ[4][32];

  const int t = threadIdx.x;
  const int g = blockIdx.x;
  const int wid = t >> 6;
  const int lane = t & 63;
  const int isf = dflag[0];
  const int nb = g*PP;
  const int eb = offs[nb];
  int ecnt = offs[nb+24] - eb; if(ecnt < 0) ecnt = 0; if(ecnt > CAP) ecnt = CAP;

  if(t < 25){
    int v = offs[nb+t] - eb;
    if(v < 0) v = 0; if(v > CAP) v = CAP;
    sRO[t] = v;
  }
  if(eap){
    for(int i=t; i<ecnt; i+=256) sSl[i] = spack[eb+i] & 1023;
    for(int i=t; i<ecnt*4; i+=256){
      int e = i>>2, q = i&3;
      *(f4_t*)&sEaF[e][q*4] = *(const f4_t*)(eap + ((size_t)(eb+e))*16 + q*4);
    }
  } else {
    for(int i=t; i<ecnt; i+=256){
      int sp = spack[eb+i];
      sSl[i] = sp & 1023;
      u32 id = ((u32)sp) >> 10;
      if(id >= (u32)EE) id = 0;
      if(isf){
        const float* er = (const float*)ea + (size_t)id*16;
        #pragma unroll
        for(int q=0;q<4;q++) *(f4_t*)&sEaF[i][q*4] = *(const f4_t*)(er + q*4);
      } else {
        #pragma unroll
        for(int c=0;c<16;c++) sEaF[i][c] = bf2f(((const u16*)ea)[(size_t)id*16 + c]);
      }
    }
  }
  {
    int rz = wid*6;
    for(int i=lane; i<6*17; i+=64) sEaSum[rz + i/17][i%17] = 0.f;
  }

  {
    const int c = t & 31, mat = (t>>5)&1, w = wid, cc = t&63;
    const float* gW = wq + oW1I;
    float bi = wb[(mat ? obr1 : obl1) + c];
    float acc[6];
    #pragma unroll
    for(int j=0;j<6;j++) acc[j] = bi;
    if(isf){
      const float* xr0 = (const float*)x + (size_t)(nb + w*6)*96;
      for(int kb=0; kb<19; kb++){
        float w0 = gW[(kb*4+0)*64 + cc];
        float w1 = gW[(kb*4+1)*64 + cc];
        float w2 = gW[(kb*4+2)*64 + cc];
        float w3 = gW[(kb*4+3)*64 + cc];
        #pragma unroll
        for(int j=0;j<6;j++){
          f4_t xv = *(const f4_t*)(xr0 + (size_t)j*96 + kb*4);
          acc[j] += xv[0]*w0 + xv[1]*w1 + xv[2]*w2 + xv[3]*w3;
        }
      }
    } else {
      const u16* xr0 = (const u16*)x + (size_t)(nb + w*6)*96;
      for(int kb=0; kb<19; kb++){
        float w0 = gW[(kb*4+0)*64 + cc];
        float w1 = gW[(kb*4+1)*64 + cc];
        float w2 = gW[(kb*4+2)*64 + cc];
        float w3 = gW[(kb*4+3)*64 + cc];
        #pragma unroll
        for(int j=0;j<6;j++){
          us4_t xv = *(const us4_t*)(xr0 + (size_t)j*96 + kb*4);
          acc[j] += bf2f(xv[0])*w0 + bf2f(xv[1])*w1 + bf2f(xv[2])*w2 + bf2f(xv[3])*w3;
        }
      }
    }
    if(mat){
      #pragma unroll
      for(int j=0;j<6;j++) sXr[w*6+j][c] = acc[j];
    } else {
      #pragma unroll
      for(int j=0;j<6;j++) sXl[w*6+j][c] = acc[j];
    }
  }
  __syncthreads();

  const int r0 = wid*6;
  const int a0 = sRO[r0], a1 = sRO[r0+6];
  const int c = t & 31, eo = (t>>5)&1;

  float wr[16];
  #pragma unroll
  for(int k=0;k<16;k++) wr[k] = wb[oWe1 + k*32 + c];
  const float av = wb[oatt1 + c];
  const float bv = wb[obo1 + c];

  for(int base=a0; base<a1; base+=2){
    int e = base + eo;
    bool valid = (e < a1);
    int ec = valid ? e : a0;
    int sp = sSl[ec];
    int sl = sp & 31; if(sl > 23) sl = 0;
    int dl = (sp >> 5) & 31; if(dl > 23) dl = 0;
    f4_t A0 = *(const f4_t*)&sEaF[ec][0];
    f4_t A1 = *(const f4_t*)&sEaF[ec][4];
    f4_t A2 = *(const f4_t*)&sEaF[ec][8];
    f4_t A3 = *(const f4_t*)&sEaF[ec][12];
    float p = A0[0]*wr[0]+A0[1]*wr[1]+A0[2]*wr[2]+A0[3]*wr[3]
            + A1[0]*wr[4]+A1[1]*wr[5]+A1[2]*wr[6]+A1[3]*wr[7]
            + A2[0]*wr[8]+A2[1]*wr[9]+A2[2]*wr[10]+A2[3]*wr[11]
            + A3[0]*wr[12]+A3[1]*wr[13]+A3[2]*wr[14]+A3[3]*wr[15];
    if(valid && c < 16) atomicAdd(&sEaSum[dl][c], sEaF[ec][c]);
    float v = lrelu(sXl[sl][c] + sXr[dl][c] + p) * av;
    v += __shfl_xor(v, 16);
    v += __shfl_xor(v, 8);
    v += __shfl_xor(v, 4);
    v += __shfl_xor(v, 2);
    v += __shfl_xor(v, 1);
    if(valid && c == 0) sEv[e] = v;
  }

  #pragma unroll
  for(int rp=0; rp<3; rp++){
    int r = r0 + rp*2 + eo;
    int deg = sRO[r+1] - sRO[r];
    float invd = 1.f / (float)(deg > 0 ? deg : 1);
    float mp = 0.f;
    #pragma unroll
    for(int k=0;k<16;k++) mp += sEaSum[r][k] * wr[k];
    float v = lrelu(sXl[r][c] + sXr[r][c] + mp*invd) * av;
    v += __shfl_xor(v, 16);
    v += __shfl_xor(v, 8);
    v += __shfl_xor(v, 4);
    v += __shfl_xor(v, 2);
    v += __shfl_xor(v, 1);
    if(c == 0) sSelfE[r] = v;
  }

  float ps = 0.f, pq = 0.f;
  const int h = (t >> 5) & 1;
  #pragma unroll
  for(int j=0;j<6;j++){
    int r = r0 + j;
    int a = sRO[r], b = sRO[r+1];
    float selfE = sSelfE[r];
    float mx = -3.4e38f;
    for(int e=a+lane; e<b; e+=64) mx = fmaxf(mx, sEv[e]);
    mx = fmaxf(mx, __shfl_xor(mx, 32));
    mx = fmaxf(mx, __shfl_xor(mx, 16));
    mx = fmaxf(mx, __shfl_xor(mx, 8));
    mx = fmaxf(mx, __shfl_xor(mx, 4));
    mx = fmaxf(mx, __shfl_xor(mx, 2));
    mx = fmaxf(mx, __shfl_xor(mx, 1));
    float m = fmaxf(mx, selfE);
    float ds = 0.f;
    for(int e=a+lane; e<b; e+=64){
      float z = sexp(sEv[e] - m);
      sEv[e] = z;
      ds += z;
    }
    ds += __shfl_xor(ds, 32);
    ds += __shfl_xor(ds, 16);
    ds += __shfl_xor(ds, 8);
    ds += __shfl_xor(ds, 4);
    ds += __shfl_xor(ds, 2);
    ds += __shfl_xor(ds, 1);
    float selfZ = sexp(selfE - m);
    float rden = 1.f / fmaxf(ds + selfZ, 1e-30f);
    float acc = 0.f;
    for(int e=a+h; e<b; e+=2){
      int sl = sSl[e] & 31; if(sl > 23) sl = 0;
      acc += sEv[e] * sXl[sl][c];
    }
    acc += __shfl_xor(acc, 32);
    float out = (acc + selfZ * sXl[r][c]) * rden;
    out = fmaxf(out + bv, 0.f);
    if(h == 0){
      if(use_h1) h1[((size_t)nb + r)*32 + c] = out;
      ps += out; pq += out*out;
    }
  }
  if(h == 0){ sPS[wid][c] = ps; sPQ[wid][c] = pq; }
  __syncthreads();
  if(t < 32){
    p1sum[g*32+t] = sPS[0][t]+sPS[1][t]+sPS[2][t]+sPS[3][t];
    p1sq[g*32+t]  = sPQ[0][t]+sPQ[1][t]+sPQ[2][t]+sPQ[3][t];
  }
}

// ---------------- BN stats -> affine ----------------
__global__ void k_reduce(const float* __restrict__ ps, const float* __restrict__ pq,
                         const void* __restrict__ gamma, const void* __restrict__ beta,
                         const int* __restrict__ dflag,
                         float* __restrict__ stats, int F){
  __shared__ float rs[256], rq[256];
  int f = blockIdx.x, t = threadIdx.x;
  float s=0.f, q=0.f;
  for(int g=t; g<GG; g+=256){ s += ps[g*F+f]; q += pq[g*F+f]; }
  rs[t]=s; rq[t]=q; __syncthreads();
  for(int off=128; off>0; off>>=1){
    if(t<off){ rs[t]+=rs[t+off]; rq[t]+=rq[t+off]; }
    __syncthreads();
  }
  if(t==0){
    int isf = dflag[0];
    float mu  = rs[0] * (1.f/(float)NN);
    float var = rq[0] * (1.f/(float)NN) - mu*mu;
    if(var < 0.f) var = 0.f;
    float sc  = ldf(gamma,f,isf) / sqrtf(var + 1e-5f);
    stats[f]   = sc;
    stats[F+f] = ldf(beta,f,isf) - mu*sc;
  }
}

// -------- mid-tier layer2 from stored h1, wave-local (round-3, verbatim) --------
__global__ __launch_bounds__(256, 6) void k_fused2_h1(
    const void* __restrict__ ea, const float* __restrict__ eap,
    const float* __restrict__ wb, const float* __restrict__ wq,
    const float* __restrict__ h1,
    const int* __restrict__ offs, const int* __restrict__ spack, const int* __restrict__ dflag,
    float* __restrict__ gsum2, float* __restrict__ gsq2)
{
  __shared__ __align__(16) float sEaF[CAP][16];
  __shared__ float sXl2[24][12], sXr2[24][12];
  __shared__ float sEaSum[24][17];
  __shared__ float sEv[CAP];
  __shared__ int   sSl[CAP];
  __shared__ int   sRO[25];
  __shared__ float sSelfE[24];
  __shared__ float sGS[4][8], sGQ[4][8];

  const int t = threadIdx.x;
  const int g = blockIdx.x;
  const int wid = t >> 6;
  const int lane = t & 63;
  const int isf = dflag[0];
  const int nb = g*PP;
  const int eb = offs[nb];
  int ecnt = offs[nb+24] - eb; if(ecnt < 0) ecnt = 0; if(ecnt > CAP) ecnt = CAP;

  if(t < 25){
    int v = offs[nb+t] - eb;
    if(v < 0) v = 0; if(v > CAP) v = CAP;
    sRO[t] = v;
  }
  if(eap){
    for(int i=t; i<ecnt; i+=256) sSl[i] = spack[eb+i] & 1023;
    for(int i=t; i<ecnt*4; i+=256){
      int e = i>>2, q = i&3;
      *(f4_t*)&sEaF[e][q*4] = *(const f4_t*)(eap + ((size_t)(eb+e))*16 + q*4);
    }
  } else {
    for(int i=t; i<ecnt; i+=256){
      int sp = spack[eb+i];
      sSl[i] = sp & 1023;
      u32 id = ((u32)sp) >> 10;
      if(id >= (u32)EE) id = 0;
      if(isf){
        const float* er = (const float*)ea + (size_t)id*16;
        #pragma unroll
        for(int q=0;q<4;q++) *(f4_t*)&sEaF[i][q*4] = *(const f4_t*)(er + q*4);
      } else {
        #pragma unroll
        for(int c=0;c<16;c++) sEaF[i][c] = bf2f(((const u16*)ea)[(size_t)id*16 + c]);
      }
    }
  }
  {
    int rz = wid*6;
    for(int i=lane; i<6*17; i+=64) sEaSum[rz + i/17][i%17] = 0.f;
    for(int i=lane; i<96; i+=64){
      int rl = i>>4, cc = i&15;
      int r = rz + rl;
      float s = wq[oB2P + cc];
      const float* hr = h1 + ((size_t)nb + r)*32;
      #pragma unroll
      for(int q=0;q<8;q++){
        f4_t hv = *(const f4_t*)(hr + q*4);
        s += hv[0]*wq[oW2P+(q*4+0)*16+cc] + hv[1]*wq[oW2P+(q*4+1)*16+cc]
           + hv[2]*wq[oW2P+(q*4+2)*16+cc] + hv[3]*wq[oW2P+(q*4+3)*16+cc];
      }
      if(cc < 8) sXl2[r][cc] = s; else sXr2[r][cc-8] = s;
    }
  }
  __syncthreads();

  const int r0 = wid*6;
  const int a0 = sRO[r0], a1 = sRO[r0+6];
  const int c = t & 7;
  const int eo = lane >> 3;

  float wr[16];
  #pragma unroll
  for(int k=0;k<16;k++) wr[k] = wb[oWe2 + k*8 + c];
  const float av = wb[oatt2 + c];
  const float bv = wb[obo2 + c];

  for(int base=a0; base<a1; base+=8){
    int e = base + eo;
    bool valid = (e < a1);
    int ec = valid ? e : a0;
    int sp = sSl[ec];
    int sl = sp & 31; if(sl > 23) sl = 0;
    int dl = (sp >> 5) & 31; if(dl > 23) dl = 0;
    f4_t A0 = *(const f4_t*)&sEaF[ec][0];
    f4_t A1 = *(const f4_t*)&sEaF[ec][4];
    f4_t A2 = *(const f4_t*)&sEaF[ec][8];
    f4_t A3 = *(const f4_t*)&sEaF[ec][12];
    float p = A0[0]*wr[0]+A0[1]*wr[1]+A0[2]*wr[2]+A0[3]*wr[3]
            + A1[0]*wr[4]+A1[1]*wr[5]+A1[2]*wr[6]+A1[3]*wr[7]
            + A2[0]*wr[8]+A2[1]*wr[9]+A2[2]*wr[10]+A2[3]*wr[11]
            + A3[0]*wr[12]+A3[1]*wr[13]+A3[2]*wr[14]+A3[3]*wr[15];
    if(valid){
      atomicAdd(&sEaSum[dl][c],   sEaF[ec][c]);
      atomicAdd(&sEaSum[dl][c+8], sEaF[ec][c+8]);
    }
    float v = lrelu(sXl2[sl][c] + sXr2[dl][c] + p) * av;
    v += __shfl_xor(v, 4);
    v += __shfl_xor(v, 2);
    v += __shfl_xor(v, 1);
    if(valid && c == 0) sEv[e] = v;
  }

  {
    int rr = r0 + (eo < 6 ? eo : 0);
    bool valid = (eo < 6);
    int deg = sRO[rr+1] - sRO[rr];
    float invd = 1.f / (float)(deg > 0 ? deg : 1);
    float mp = 0.f;
    #pragma unroll
    for(int k=0;k<16;k++) mp += sEaSum[rr][k] * wr[k];
    float v = lrelu(sXl2[rr][c] + sXr2[rr][c] + mp*invd) * av;
    v += __shfl_xor(v, 4);
    v += __shfl_xor(v, 2);
    v += __shfl_xor(v, 1);
    if(valid && c == 0) sSelfE[rr] = v;
  }

  float gs = 0.f, gq = 0.f;
  #pragma unroll
  for(int j=0;j<6;j++){
    int r = r0 + j;
    int a = sRO[r], b = sRO[r+1];
    float selfE = sSelfE[r];
    float mx = -3.4e38f;
    for(int e=a+lane; e<b; e+=64) mx = fmaxf(mx, sEv[e]);
    mx = fmaxf(mx, __shfl_xor(mx, 32));
    mx = fmaxf(mx, __shfl_xor(mx, 16));
    mx = fmaxf(mx, __shfl_xor(mx, 8));
    mx = fmaxf(mx, __shfl_xor(mx, 4));
    mx = fmaxf(mx, __shfl_xor(mx, 2));
    mx = fmaxf(mx, __shfl_xor(mx, 1));
    float m = fmaxf(mx, selfE);
    float ds = 0.f;
    for(int e=a+lane; e<b; e+=64){
      float z = sexp(sEv[e] - m);
      sEv[e] = z;
      ds += z;
    }
    ds += __shfl_xor(ds, 32);
    ds += __shfl_xor(ds, 16);
    ds += __shfl_xor(ds, 8);
    ds += __shfl_xor(ds, 4);
    ds += __shfl_xor(ds, 2);
    ds += __shfl_xor(ds, 1);
    float selfZ = sexp(selfE - m);
    float rden = 1.f / fmaxf(ds + selfZ, 1e-30f);
    float acc = 0.f;
    for(int e=a+eo; e<b; e+=8){
      int sl = sSl[e] & 31; if(sl > 23) sl = 0;
      acc += sEv[e] * sXl2[sl][c];
    }
    acc += __shfl_xor(acc, 8);
    acc += __shfl_xor(acc, 16);
    acc += __shfl_xor(acc, 32);
    float out = (acc + selfZ * sXl2[r][c]) * rden;
    float s = 1.f / (1.f + __expf(-(out + bv)));
    if(eo == 0){ gs += s; gq += s*s; }
  }
  if(eo == 0){ sGS[wid][c] = gs; sGQ[wid][c] = gq; }
  __syncthreads();
  if(t < 8){
    gsum2[g*8+t] = sGS[0][t]+sGS[1][t]+sGS[2][t]+sGS[3][t];
    gsq2[g*8+t]  = sGQ[0][t]+sGQ[1][t]+sGQ[2][t]+sGQ[3][t];
  }
}

// -------- fallback: recompute layer1 + layer2 (ws-lean, round-3 verbatim) --------
__global__ __launch_bounds__(256) void k_fused2_rec(
    const void* __restrict__ x, const void* __restrict__ ea,
    const float* __restrict__ wb, const float* __restrict__ stats1,
    const int* __restrict__ offs, const int* __restrict__ spack, const int* __restrict__ dflag,
    float* __restrict__ gsum2, float* __restrict__ gsq2)
{
  __shared__ float sXrow[24][76];
  __shared__ float sEaF[CAP][17];
  __shared__ __align__(16) float sXl[24][36];
  __shared__ __align__(16) float sXr[24][36];
  __shared__ __align__(16) float sOut[24][36];
  __shared__ float sH[24][33];
  __shared__ float sXl2[24][12], sXr2[24][12], sOut2[24][12];
  __shared__ float sEapSum[24][32];
  __shared__ float sEv[CAP], sEz[CAP];
  __shared__ int   sSp[CAP];
  __shared__ int   sDeg[24];
  __shared__ u32   sMaxU[24];
  __shared__ float sMaxF[24], sDen[24], sSelfZ[24];
  __shared__ float sAtt[32], sBo[32], sSc[32], sSh[32];

  const int t = threadIdx.x;
  const int g = blockIdx.x;
  const int isf = dflag[0];
  int eb = offs[g*24], ee = offs[(g+1)*24];
  if(eb < 0) eb = 0; if(eb > EE) eb = EE;
  if(ee < eb) ee = eb; if(ee > EE) ee = EE;
  int ecnt = ee - eb; if(ecnt > CAP) ecnt = CAP;

  for(int i=t; i<24*74; i+=256){
    int r = i/74, c = i%74;
    sXrow[r][c] = ldf(x, (size_t)(g*PP + r)*96 + c, isf);
  }
  for(int i=t; i<CAP; i+=256) sSp[i] = (i<ecnt) ? spack[eb+i] : 0;
  if(t < 32){ sAtt[t]=wb[oatt1+t]; sBo[t]=wb[obo1+t]; sSc[t]=stats1[t]; sSh[t]=stats1[32+t]; }
  if(t < 24){ sDeg[t]=0; sMaxU[t]=0u; sDen[t]=0.f; }
  for(int i=t; i<24*32; i+=256) sEapSum[i>>5][i&31] = 0.f;
  __syncthreads();
  for(int i=t; i<CAP*16; i+=256){
    int e = i>>4, c = i&15;
    float v = 0.f;
    if(e < ecnt){
      u32 id = ((u32)sSp[e]) >> 10;
      if(id >= (u32)EE) id = 0;
      v = ldf(ea, (size_t)id*16 + c, isf);
    }
    sEaF[e][c] = v;
  }
  __syncthreads();

  {
    int c = t & 31, rr0 = t >> 5;
    for(int r = rr0; r < 24; r += 8){
      float al = wb[obl1+c], ar = wb[obr1+c];
      for(int k=0;k<74;k++){
        float xv = sXrow[r][k];
        al += xv * wb[oWl1 + k*32 + c];
        ar += xv * wb[oWr1 + k*32 + c];
      }
      sXl[r][c] = al; sXr[r][c] = ar;
    }
  }
  __syncthreads();

  for(int e=t; e<ecnt; e+=256){
    int sp = sSp[e];
    int sl = sp & 31; if(sl > 23) sl = 0;
    int dl = (sp >> 5) & 31; if(dl > 23) dl = 0;
    float ev = 0.f;
    for(int c=0;c<32;c++){
      float p = 0.f;
      for(int k=0;k<16;k++) p += sEaF[e][k] * wb[oWe1 + k*32 + c];
      atomicAdd(&sEapSum[dl][c], p);
      ev += lrelu(sXl[sl][c] + sXr[dl][c] + p) * sAtt[c];
    }
    sEv[e] = ev;
    atomicMax(&sMaxU[dl], fkey(ev));
    atomicAdd(&sDeg[dl], 1);
  }
  __syncthreads();

  if(t < 24){
    float invd = 1.f / (float)(sDeg[t] > 0 ? sDeg[t] : 1);
    float ev = 0.f;
    for(int c=0;c<32;c++)
      ev += lrelu(sXl[t][c] + sXr[t][c] + sEapSum[t][c]*invd) * sAtt[c];
    float mxv = (sDeg[t] > 0) ? fmaxf(funkey(sMaxU[t]), ev) : ev;
    sMaxF[t] = mxv;
    float z = sexp(ev - mxv);
    sSelfZ[t] = z;
    sDen[t] = z;
  }
  __syncthreads();

  for(int e=t; e<ecnt; e+=256){
    int dl = (sSp[e]>>5)&31; if(dl > 23) dl = 0;
    float z = sexp(sEv[e] - sMaxF[dl]);
    sEz[e] = z;
    atomicAdd(&sDen[dl], z);
  }
  __syncthreads();

  for(int e=t; e<ecnt; e+=256){
    int dl = (sSp[e]>>5)&31; if(dl > 23) dl = 0;
    sEz[e] /= fmaxf(sDen[dl], 1e-30f);
  }
  if(t < 24) sSelfZ[t] /= fmaxf(sDen[t], 1e-30f);
  __syncthreads();

  for(int o=t; o<24*8; o+=256){
    int nl = o >> 3, cq = (o & 7)*4;
    float al = sSelfZ[nl];
    f4_t xv = *(const f4_t*)&sXl[nl][cq];
    f4_t r;
    #pragma unroll
    for(int j=0;j<4;j++) r[j] = al*xv[j];
    *(f4_t*)&sOut[nl][cq] = r;
  }
  __syncthreads();

  for(int o=t; o<ecnt*8; o+=256){
    int e = o >> 3, cq = (o & 7)*4;
    int sp = sSp[e];
    int sl = sp & 31; if(sl > 23) sl = 0;
    int dl = (sp >> 5) & 31; if(dl > 23) dl = 0;
    float al = sEz[e];
    f4_t xv = *(const f4_t*)&sXl[sl][cq];
    atomicAdd(&sOut[dl][cq+0], al*xv[0]);
    atomicAdd(&sOut[dl][cq+1], al*xv[1]);
    atomicAdd(&sOut[dl][cq+2], al*xv[2]);
    atomicAdd(&sOut[dl][cq+3], al*xv[3]);
  }
  __syncthreads();

  for(int i=t; i<24*32; i+=256){
    int r = i>>5, c = i&31;
    float v = fmaxf(sOut[r][c] + sBo[c], 0.f);
    sH[r][c] = v*sSc[c] + sSh[c];
  }
  __syncthreads();
  if(t < 24){ sDeg[t]=0; sMaxU[t]=0u; sDen[t]=0.f; }
  for(int i=t; i<24*8; i+=256) sEapSum[i>>3][i&7] = 0.f;
  __syncthreads();

  if(t < 24*8*2){
    int mat = t/192, rem = t%192, r = rem/8, c = rem&7;
    const float* Wm = wb + (mat ? oWr2 : oWl2);
    float s = wb[(mat ? obr2 : obl2) + c];
    for(int k=0;k<32;k++) s += sH[r][k]*Wm[k*8+c];
    if(mat) sXr2[r][c] = s; else sXl2[r][c] = s;
  }
  __syncthreads();

  for(int e=t; e<ecnt; e+=256){
    int sp = sSp[e];
    int sl = sp & 31; if(sl > 23) sl = 0;
    int dl = (sp >> 5) & 31; if(dl > 23) dl = 0;
    float ev = 0.f;
    for(int c=0;c<8;c++){
      float p = 0.f;
      for(int k=0;k<16;k++) p += sEaF[e][k] * wb[oWe2 + k*8 + c];
      atomicAdd(&sEapSum[dl][c], p);
      ev += lrelu(sXl2[sl][c] + sXr2[dl][c] + p) * wb[oatt2+c];
    }
    sEv[e] = ev;
    atomicMax(&sMaxU[dl], fkey(ev));
    atomicAdd(&sDeg[dl], 1);
  }
  __syncthreads();

  if(t < 24){
    float invd = 1.f / (float)(sDeg[t] > 0 ? sDeg[t] : 1);
    float ev = 0.f;
    for(int c=0;c<8;c++)
      ev += lrelu(sXl2[t][c] + sXr2[t][c] + sEapSum[t][c]*invd) * wb[oatt2+c];
    float mxv = (sDeg[t] > 0) ? fmaxf(funkey(sMaxU[t]), ev) : ev;
    sMaxF[t] = mxv;
    float z = sexp(ev - mxv);
    sSelfZ[t] = z;
    sDen[t] = z;
  }
  __syncthreads();

  for(int e=t; e<ecnt; e+=256){
    int dl = (sSp[e]>>5)&31; if(dl > 23) dl = 0;
    float z = sexp(sEv[e] - sMaxF[dl]);
    sEz[e] = z;
    atomicAdd(&sDen[dl], z);
  }
  __syncthreads();

  for(int e=t; e<ecnt; e+=256){
    int dl = (sSp[e]>>5)&31; if(dl > 23) dl = 0;
    sEz[e] /= fmaxf(sDen[dl], 1e-30f);
  }
  if(t < 24) sSelfZ[t] /= fmaxf(sDen[t], 1e-30f);
  __syncthreads();

  for(int o=t; o<24*8; o+=256){
    int nl = o >> 3, c = o & 7;
    sOut2[nl][c] = sSelfZ[nl] * sXl2[nl][c];
  }
  __syncthreads();

  for(int o=t; o<ecnt*8; o+=256){
    int e = o >> 3, c = o & 7;
    int sp = sSp[e];
    int sl = sp & 31; if(sl > 23) sl = 0;
    int dl = (sp >> 5) & 31; if(dl > 23) dl = 0;
    atomicAdd(&sOut2[dl][c], sEz[e]*sXl2[sl][c]);
  }
  __syncthreads();

  if(t < 8){
    float gs=0.f, gq=0.f;
    for(int nl=0; nl<24; nl++){
      float v = sOut2[nl][t] + wb[obo2+t];
      float s = 1.f / (1.f + __expf(-v));
      gs += s; gq += s*s;
    }
    gsum2[g*8+t] = gs; gsq2[g*8+t] = gq;
  }
}

// ---------------- MLP head ----------------
__global__ __launch_bounds__(256) void k_mlp(
    const float* __restrict__ gsum2, const float* __restrict__ stats2,
    const void* __restrict__ x, const int* __restrict__ dflag,
    const float* __restrict__ wb, float* __restrict__ out)
{
  __shared__ float w[1702];
  int t = threadIdx.x;
  for(int i=t; i<1702; i+=256) w[i] = wb[6048+i];
  __syncthreads();
  int g = blockIdx.x*256 + t;
  int isf = dflag[0];
  float a[30], b[32];
  for(int c=0;c<8;c++) a[c] = stats2[c]*(gsum2[(size_t)g*8+c]*(1.f/24.f)) + stats2[8+c];
  size_t xoff = (size_t)g*PP*96 + 74;
  for(int j=0;j<22;j++) a[8+j] = ldf(x, xoff+j, isf);
  for(int o=0;o<32;o++){ float s = w[960+o];  for(int i=0;i<30;i++) s += a[i]*w[i*32+o];      b[o]=fmaxf(s,0.f); }
  for(int o=0;o<16;o++){ float s = w[1504+o]; for(int i=0;i<32;i++) s += b[i]*w[992+i*16+o];  a[o]=fmaxf(s,0.f); }
  for(int o=0;o<8;o++){  float s = w[1648+o]; for(int i=0;i<16;i++) s += a[i]*w[1520+i*8+o];  b[o]=fmaxf(s,0.f); }
  for(int o=0;o<4;o++){  float s = w[1688+o]; for(int i=0;i<8;i++)  s += b[i]*w[1656+i*4+o];  a[o]=fmaxf(s,0.f); }
  for(int o=0;o<2;o++){
    float s = w[1700+o];
    for(int i=0;i<4;i++) s += a[i]*w[1692+i*2+o];
    out[(size_t)g*2+o] = s;
  }
}

extern "C" void kernel_launch(void* const* d_in, const int* in_sizes, int n_in,
                              void* d_out, int out_size, void* d_ws, size_t ws_size,
                              hipStream_t stream)
{
  (void)in_sizes; (void)n_in; (void)out_size;
  const void* x    = d_in[0];
  const int* eidx  = (const int*)d_in[1];
  const void* ea   = d_in[2];

  const int* srcA = eidx;
  const int* dstA = eidx + EE;

  constexpr size_t O_WB    = 0;
  constexpr size_t O_WQ    = 32768;
  constexpr size_t O_OFFS  = 57344;
  constexpr size_t O_CUR   = O_OFFS + (size_t)(NN+512)*4;
  constexpr size_t O_SPACK = O_CUR  + (size_t)NN*4;
  constexpr size_t O_P1S   = O_SPACK + (size_t)EE*4;
  constexpr size_t O_P1Q   = O_P1S   + (size_t)GG*32*4;
  constexpr size_t O_ST1   = O_P1Q   + (size_t)GG*32*4;
  constexpr size_t O_GS2   = O_ST1   + 256;
  constexpr size_t O_GQ2   = O_GS2   + (size_t)GG*8*4;
  constexpr size_t O_ST2   = O_GQ2   + (size_t)GG*8*4;
  constexpr size_t O_FLAG  = O_ST2   + 256;
  constexpr size_t REQUIRED_BASE = O_FLAG + 256;
  constexpr size_t O_H1    = REQUIRED_BASE;
  constexpr size_t REQUIRED_BIG = O_H1 + (size_t)NN*32*4;
  constexpr size_t O_EAP1  = REQUIRED_BIG;                       // eap16: EE*16 f32
  constexpr size_t O_P2    = O_EAP1 + (size_t)EE*16*4;           // p2: EE*8 f32
  constexpr size_t REQUIRED_P = O_P2 + (size_t)EE*8*4;
  constexpr size_t REQUIRED_EAP16 = O_EAP1 + (size_t)EE*16*4;

  if(ws_size < REQUIRED_BASE){
    k_zero<<<(GG*2+255)/256, 256, 0, stream>>>((float*)d_out);
    return;
  }
  const int use_h1  = (ws_size >= REQUIRED_BIG)   ? 1 : 0;
  const int use_p   = (use_h1 && ws_size >= REQUIRED_P) ? 1 : 0;
  const int use_eap = (!use_p && ws_size >= REQUIRED_EAP16) ? 1 : 0;

  char* W = (char*)d_ws;
  float* wb     = (float*)(W + O_WB);
  float* wq     = (float*)(W + O_WQ);
  int*   offs   = (int*)(W + O_OFFS);
  int*   bsum   = offs + NN + 64;
  int*   cnt    = (int*)(W + O_CUR);
  int*   cursor = (int*)(W + O_CUR);
  int*   spack  = (int*)(W + O_SPACK);
  float* p1sum  = (float*)(W + O_P1S);
  float* p1sq   = (float*)(W + O_P1Q);
  float* stats1 = (float*)(W + O_ST1);
  float* gsum2  = (float*)(W + O_GS2);
  float* gsq2   = (float*)(W + O_GQ2);
  float* stats2 = (float*)(W + O_ST2);
  int*   dflag  = (int*)(W + O_FLAG);
  float* h1     = (float*)(W + O_H1);
  float* eap1   = (float*)(W + O_EAP1);
  float* p2     = (float*)(W + O_P2);

  hipMemsetAsync(cnt, 0, (size_t)NN*sizeof(int), stream);
  k_count  <<<EE/256, 256, 0, stream>>>(dstA, cnt);
  k_scanA  <<<192, 1024, 0, stream>>>(cnt, offs, bsum);
  k_scanB  <<<1, 256, 0, stream>>>(bsum, offs);
  k_scanC  <<<192, 1024, 0, stream>>>(offs, bsum, cursor);
  k_scatter<<<EE/256, 256, 0, stream>>>(srcA, dstA, cursor, spack);
  k_wconv  <<<1, 256, 0, stream>>>(wb, wq, dflag, (const u32*)x,
            d_in[4], d_in[5], d_in[6], d_in[7], d_in[8], d_in[9], d_in[10],
            d_in[11], d_in[12], d_in[13], d_in[14], d_in[15], d_in[16], d_in[17],
            d_in[22], d_in[23], d_in[24], d_in[25], d_in[26], d_in[27],
            d_in[28], d_in[29], d_in[30], d_in[31]);
  if(use_p){
    k_eapermB<<<EE/256, 256, 0, stream>>>(spack, offs, ea, dflag, wb, eap1, p2);
    k_l1stats_p<<<GG, 256, 0, stream>>>(x, eap1, wb, wq, offs, spack, dflag,
                                        p1sum, p1sq, h1);
  } else {
    if(use_eap)
      k_eaperm<<<EE/256, 256, 0, stream>>>(spack, offs, ea, dflag, eap1);
    k_l1stats<<<GG, 256, 0, stream>>>(x, ea, use_eap ? eap1 : (float*)nullptr,
                                      wb, wq, offs, spack, dflag,
                                      p1sum, p1sq, h1, use_h1);
  }
  k_reduce <<<32, 256, 0, stream>>>(p1sum, p1sq, d_in[18], d_in[19], dflag, stats1, 32);
  k_prep2  <<<1, 256, 0, stream>>>(wq, wb, stats1);
  if(use_p)
    k_fused2_p<<<GG, 256, 0, stream>>>(p2, wb, wq, h1, offs, spack, gsum2, gsq2);
  else if(use_h1)
    k_fused2_h1<<<GG, 256, 0, stream>>>(ea, use_eap ? eap1 : (float*)nullptr,
                                        wb, wq, h1, offs, spack, dflag, gsum2, gsq2);
  else
    k_fused2_rec<<<GG, 256, 0, stream>>>(x, ea, wb, stats1, offs, spack, dflag, gsum2, gsq2);
  k_reduce <<<8, 256, 0, stream>>>(gsum2, gsq2, d_in[20], d_in[21], dflag, stats2, 8);
  k_mlp    <<<GG/256, 256, 0, stream>>>(gsum2, stats2, x, dflag, wb, (float*)d_out);
}

// Round 9
// 595.668 us; speedup vs baseline: 1.1010x; 1.1010x over previous
//
#include <hip/hip_runtime.h>

typedef unsigned short u16;
typedef unsigned int   u32;
typedef __attribute__((ext_vector_type(4))) float f4_t;
typedef __attribute__((ext_vector_type(4))) unsigned short us4_t;

#define GG 8192
#define PP 24
#define NN 196608
#define EE 786432
#define CAP 176

// ---- packed f32 weight buffer offsets (wb region) ----
#define oWl1 0
#define oWr1 2368
#define obl1 4736
#define obr1 4768
#define oWe1 4800
#define oatt1 5312
#define obo1 5344
#define oWl2 5376
#define oWr2 5632
#define obl2 5888
#define obr2 5896
#define oWe2 5904
#define oatt2 6032
#define obo2 6040
#define ofc1W 6048
#define ofc1b 7008
#define ofc2W 7040
#define ofc2b 7552
#define ofc3W 7568
#define ofc3b 7696
#define ofc4W 7704
#define ofc4b 7736
#define ooutW 7740
#define ooutb 7748

// ---- wq buffer ----
#define oW1I 0        // 76x64 interleaved W1 (rows 74,75 zero) = 4864 floats
#define oW2P 4864     // 32x16 BN-folded W2' = 512 floats
#define oB2P 5376     // 16 floats

__device__ __forceinline__ float bf2f(u16 u){
  union { u32 i; float f; } x; x.i = ((u32)u) << 16; return x.f;
}
__device__ __forceinline__ u32 fkey(float f){
  int i = __float_as_int(f);
  return (i >= 0) ? (((u32)i) | 0x80000000u) : ~((u32)i);
}
__device__ __forceinline__ float funkey(u32 k){
  u32 i = (k & 0x80000000u) ? (k & 0x7FFFFFFFu) : ~k;
  return __uint_as_float(i);
}
__device__ __forceinline__ float lrelu(float m){ return m > 0.f ? m : 0.2f*m; }
__device__ __forceinline__ float sexp(float a){ return __expf(fminf(a, 0.f)); }
__device__ __forceinline__ float ldf(const void* p, size_t i, int isf){
  return isf ? ((const float*)p)[i] : bf2f(((const u16*)p)[i]);
}

__global__ void k_zero(float* __restrict__ out){
  int i = blockIdx.x*256 + threadIdx.x;
  if(i < GG*2) out[i] = 0.f;
}

// ---------------- per-NODE bucketing ----------------
__global__ void k_count(const int* __restrict__ dst, int* __restrict__ cnt){
  int e = blockIdx.x*256 + threadIdx.x;
  if(e < EE){
    u32 d = (u32)dst[e];
    if(d < (u32)NN) atomicAdd(&cnt[d], 1);
  }
}

__global__ void k_scanA(const int* __restrict__ cnt, int* __restrict__ offs,
                        int* __restrict__ bsum){
  __shared__ int part[1024];
  int t = threadIdx.x;
  int i = blockIdx.x*1024 + t;
  int c = cnt[i];
  part[t] = c; __syncthreads();
  for(int off=1; off<1024; off<<=1){
    int v = (t>=off) ? part[t-off] : 0;
    __syncthreads();
    part[t] += v;
    __syncthreads();
  }
  offs[i] = part[t] - c;
  if(t==1023) bsum[blockIdx.x] = part[1023];
}

__global__ void k_scanB(int* __restrict__ bsum, int* __restrict__ offs){
  __shared__ int part[256];
  int t = threadIdx.x;
  int c = (t < 192) ? bsum[t] : 0;
  part[t] = c; __syncthreads();
  for(int off=1; off<256; off<<=1){
    int v = (t>=off) ? part[t-off] : 0;
    __syncthreads();
    part[t] += v;
    __syncthreads();
  }
  if(t < 192) bsum[t] = part[t] - c;
  if(t == 255) offs[NN] = part[255];
}

__global__ void k_scanC(int* __restrict__ offs, const int* __restrict__ bsum,
                        int* __restrict__ cursor){
  int t = threadIdx.x;
  int i = blockIdx.x*1024 + t;
  int v = offs[i] + bsum[blockIdx.x];
  offs[i] = v;
  cursor[i] = v;
}

// pack: sl(5b) | dl(5b)<<5 | edge_id(20b)<<10 ; sorted by dst node
__global__ void k_scatter(const int* __restrict__ src, const int* __restrict__ dst,
                          int* __restrict__ cursor, int* __restrict__ spack){
  int e = blockIdx.x*256 + threadIdx.x;
  if(e < EE){
    u32 d = (u32)dst[e];
    if(d >= (u32)NN) return;
    int g = d / PP;
    int pos = atomicAdd(&cursor[d], 1);
    if((u32)pos < (u32)EE){
      int sl = src[e] - g*PP;
      if((u32)sl > 23u) sl = 0;
      spack[pos] = sl | ((int)(d - g*PP) << 5) | (e << 10);
    }
  }
}

// ---------- mid tier: permute ea into sorted order, f32 16-wide ----------
__global__ void k_eaperm(const int* __restrict__ spack, const int* __restrict__ offs,
                         const void* __restrict__ ea, const int* __restrict__ dflag,
                         float* __restrict__ eap){
  int i = blockIdx.x*256 + threadIdx.x;
  if(i >= EE) return;
  if(i >= offs[NN]) return;
  int isf = dflag[0];
  u32 id = ((u32)spack[i]) >> 10;
  if(id >= (u32)EE) id = 0;
  float* o = eap + (size_t)i*16;
  if(isf){
    const float* er = (const float*)ea + (size_t)id*16;
    #pragma unroll
    for(int q=0;q<4;q++) *(f4_t*)(o + q*4) = *(const f4_t*)(er + q*4);
  } else {
    const u16* er = (const u16*)ea + (size_t)id*16;
    #pragma unroll
    for(int c=0;c<16;c++) o[c] = bf2f(er[c]);
  }
}

// ---------- p tier: permute ea (16 f32) AND project layer-2 p2 = ea@We2 ----------
__global__ void k_eapermB(const int* __restrict__ spack, const int* __restrict__ offs,
                          const void* __restrict__ ea, const int* __restrict__ dflag,
                          const float* __restrict__ wb,
                          float* __restrict__ eap, float* __restrict__ p2){
  int i = blockIdx.x*256 + threadIdx.x;
  if(i >= EE) return;
  if(i >= offs[NN]) return;
  int isf = dflag[0];
  u32 id = ((u32)spack[i]) >> 10;
  if(id >= (u32)EE) id = 0;
  float eav[16];
  if(isf){
    const float* er = (const float*)ea + (size_t)id*16;
    #pragma unroll
    for(int k=0;k<16;k++) eav[k] = er[k];
  } else {
    const u16* er = (const u16*)ea + (size_t)id*16;
    #pragma unroll
    for(int k=0;k<16;k++) eav[k] = bf2f(er[k]);
  }
  float* o = eap + (size_t)i*16;
  #pragma unroll
  for(int q=0;q<4;q++){
    f4_t r; r[0]=eav[q*4+0]; r[1]=eav[q*4+1]; r[2]=eav[q*4+2]; r[3]=eav[q*4+3];
    *(f4_t*)(o + q*4) = r;
  }
  float* o2 = p2 + (size_t)i*8;
  #pragma unroll
  for(int c=0;c<8;c+=4){
    float s0=0.f, s1=0.f, s2=0.f, s3=0.f;
    #pragma unroll
    for(int k=0;k<16;k++){
      f4_t w = *(const f4_t*)(wb + oWe2 + k*8 + c);
      s0 += eav[k]*w[0]; s1 += eav[k]*w[1]; s2 += eav[k]*w[2]; s3 += eav[k]*w[3];
    }
    f4_t r; r[0]=s0; r[1]=s1; r[2]=s2; r[3]=s3;
    *(f4_t*)(o2 + c) = r;
  }
}

// ---------- fused dtype-detect + weight conversion (one block) ----------
__global__ void k_wconv(float* __restrict__ wb, float* __restrict__ wq, int* __restrict__ dflag,
    const u32* __restrict__ xw,
    const void* Wl1, const void* bl1, const void* Wr1, const void* br1,
    const void* We1, const void* att1, const void* bo1,
    const void* Wl2, const void* bl2, const void* Wr2, const void* br2,
    const void* We2, const void* att2, const void* bo2,
    const void* f1W, const void* f1b, const void* f2W, const void* f2b,
    const void* f3W, const void* f3b, const void* f4W, const void* f4b,
    const void* oW,  const void* ob)
{
  __shared__ u32 mx[256];
  int t = threadIdx.x;
  u32 m = 0;
  for(int i=t; i<2048; i+=256){
    u32 e = (xw[i] >> 7) & 0xFFu;
    m = m > e ? m : e;
  }
  mx[t] = m; __syncthreads();
  for(int off=128; off>0; off>>=1){
    if(t<off) mx[t] = mx[t] > mx[t+off] ? mx[t] : mx[t+off];
    __syncthreads();
  }
  int isf = (mx[0] > 140u) ? 1 : 0;
  if(t==0) dflag[0] = isf;
  #define CP(off,src,len) for(int i=t;i<(len);i+=256) wb[(off)+i]=ldf(src,i,isf);
  CP(oWl1,Wl1,2368) CP(oWr1,Wr1,2368) CP(obl1,bl1,32) CP(obr1,br1,32)
  CP(oWe1,We1,512)  CP(oatt1,att1,32) CP(obo1,bo1,32)
  CP(oWl2,Wl2,256)  CP(oWr2,Wr2,256)  CP(obl2,bl2,8)  CP(obr2,br2,8)
  CP(oWe2,We2,128)  CP(oatt2,att2,8)  CP(obo2,bo2,8)
  CP(ofc1W,f1W,960) CP(ofc1b,f1b,32)  CP(ofc2W,f2W,512) CP(ofc2b,f2b,16)
  CP(ofc3W,f3W,128) CP(ofc3b,f3b,8)   CP(ofc4W,f4W,32)  CP(ofc4b,f4b,4)
  CP(ooutW,oW,8)    CP(ooutb,ob,2)
  #undef CP
  for(int i=t; i<76*64; i+=256){
    int k = i>>6, cc = i&63, mat = cc>>5, c = cc&31;
    wq[oW1I + i] = (k < 74) ? ldf(mat ? Wr1 : Wl1, k*32 + c, isf) : 0.f;
  }
}

// ---------- BN-fold for layer 2 ----------
__global__ void k_prep2(float* __restrict__ wq, const float* __restrict__ wb,
                        const float* __restrict__ stats1){
  int t = threadIdx.x;
  for(int i=t; i<512; i+=256){
    int k = i>>4, cc = i&15, mat = cc>>3, c = cc&7;
    wq[oW2P + i] = stats1[k] * wb[(mat ? oWr2 : oWl2) + k*8 + c];
  }
  if(t < 16){
    int mat = t>>3, c = t&7;
    float s = wb[(mat ? obr2 : obl2) + c];
    for(int k=0;k<32;k++) s += stats1[32+k] * wb[(mat ? oWr2 : oWl2) + k*8 + c];
    wq[oB2P + t] = s;
  }
}

// ======== p-tier pass 1: rows parallel, p1 computed into LDS (not HBM) ========
// LDS ~40 KB -> 4 blocks/CU. sP padded to 36 floats/row: stride 144 B rotates
// banks by 4 per edge (128-B stride would put every row on the same 4 banks).
// Measured (round 6): 198 us, VALUBusy 35%, FETCH 65.7 MB, WRITE 26.6 MB.
// Round-7/8 experiments (in-kernel gather; XOR-swizzle + overlay + (256,5)
// reg cap 48) both measured SLOWER (303 / 268 us) -> this config is kept.
__global__ __launch_bounds__(256, 4) void k_l1stats_p(
    const void* __restrict__ x, const float* __restrict__ eap,
    const float* __restrict__ wb, const float* __restrict__ wq,
    const int* __restrict__ offs, const int* __restrict__ spack, const int* __restrict__ dflag,
    float* __restrict__ p1sum, float* __restrict__ p1sq,
    float* __restrict__ h1)
{
  __shared__ __align__(16) float sP[CAP][36];    // ea@We1 per edge (cols 0..31)
  __shared__ __align__(16) float sXl[24][36];
  __shared__ __align__(16) float sXr[24][36];
  __shared__ __align__(16) float sPS[24][32];
  __shared__ __align__(16) float sPQ[24][32];
  __shared__ float sEv[CAP];
  __shared__ int   sSl[CAP];
  __shared__ int   sRO[25];

  const int t = threadIdx.x;
  const int g = blockIdx.x;
  const int isf = dflag[0];
  const int nb = g*PP;
  const int eb = offs[nb];
  int ecnt = offs[nb+24] - eb;
  if(ecnt < 0) ecnt = 0; if(ecnt > CAP) ecnt = CAP;

  if(t < 25){
    int v = offs[nb+t] - eb;
    if(v < 0) v = 0; if(v > CAP) v = CAP;
    sRO[t] = v;
  }
  for(int i=t; i<ecnt; i+=256){
    int sl = spack[eb+i] & 31; if(sl > 23) sl = 0;
    sSl[i] = sl;
  }

  // ---- phase A1: projection xl/xr (wave w -> rows 6w..6w+5) ----
  {
    const int c = t & 31, mat = (t>>5)&1, w = t>>6, cc = t&63;
    const float* gW = wq + oW1I;
    float bi = wb[(mat ? obr1 : obl1) + c];
    float acc[6];
    #pragma unroll
    for(int j=0;j<6;j++) acc[j] = bi;
    if(isf){
      const float* xr0 = (const float*)x + (size_t)(nb + w*6)*96;
      for(int kb=0; kb<19; kb++){
        float w0 = gW[(kb*4+0)*64 + cc];
        float w1 = gW[(kb*4+1)*64 + cc];
        float w2 = gW[(kb*4+2)*64 + cc];
        float w3 = gW[(kb*4+3)*64 + cc];
        #pragma unroll
        for(int j=0;j<6;j++){
          f4_t xv = *(const f4_t*)(xr0 + (size_t)j*96 + kb*4);
          acc[j] += xv[0]*w0 + xv[1]*w1 + xv[2]*w2 + xv[3]*w3;
        }
      }
    } else {
      const u16* xr0 = (const u16*)x + (size_t)(nb + w*6)*96;
      for(int kb=0; kb<19; kb++){
        float w0 = gW[(kb*4+0)*64 + cc];
        float w1 = gW[(kb*4+1)*64 + cc];
        float w2 = gW[(kb*4+2)*64 + cc];
        float w3 = gW[(kb*4+3)*64 + cc];
        #pragma unroll
        for(int j=0;j<6;j++){
          us4_t xv = *(const us4_t*)(xr0 + (size_t)j*96 + kb*4);
          acc[j] += bf2f(xv[0])*w0 + bf2f(xv[1])*w1 + bf2f(xv[2])*w2 + bf2f(xv[3])*w3;
        }
      }
    }
    if(mat){
      #pragma unroll
      for(int j=0;j<6;j++) sXr[w*6+j][c] = acc[j];
    } else {
      #pragma unroll
      for(int j=0;j<6;j++) sXl[w*6+j][c] = acc[j];
    }
  }

  // ---- phase A2: p1 into LDS. task (e, q): cols q*4..q*4+3 of edge e ----
  for(int i=t; i<ecnt*8; i+=256){
    int e = i>>3, q = i&7;
    const float* er = eap + (size_t)(eb+e)*16;   // L1/L2-hot (8 tasks share row)
    float s0=0.f, s1=0.f, s2=0.f, s3=0.f;
    #pragma unroll
    for(int k=0;k<16;k++){
      float ev = er[k];
      f4_t w = *(const f4_t*)(wb + oWe1 + k*32 + q*4);
      s0 += ev*w[0]; s1 += ev*w[1]; s2 += ev*w[2]; s3 += ev*w[3];
    }
    f4_t r; r[0]=s0; r[1]=s1; r[2]=s2; r[3]=s3;
    *(f4_t*)&sP[e][q*4] = r;                     // e*144 + q*16 bytes: 16-B aligned
  }
  __syncthreads();   // barrier 1

  if(t < 192){       // 8 lanes per row, 24 rows in parallel
    const int r = t >> 3, sub = t & 7;
    const int a = sRO[r], b = sRO[r+1];
    const int deg = b - a;
    const float* att = wb + oatt1;

    // e-values: lane owns edges a+sub, a+sub+8, ... ; p1 from LDS
    float emax = -3.4e38f;
    for(int e=a+sub; e<b; e+=8){
      int sl = sSl[e];
      float ev = 0.f;
      #pragma unroll
      for(int q=0;q<8;q++){
        f4_t pv  = *(const f4_t*)&sP[e][q*4];
        f4_t xlv = *(const f4_t*)&sXl[sl][q*4];
        f4_t xrv = *(const f4_t*)&sXr[r][q*4];
        ev += att[q*4+0]*lrelu(xlv[0]+xrv[0]+pv[0]);
        ev += att[q*4+1]*lrelu(xlv[1]+xrv[1]+pv[1]);
        ev += att[q*4+2]*lrelu(xlv[2]+xrv[2]+pv[2]);
        ev += att[q*4+3]*lrelu(xlv[3]+xrv[3]+pv[3]);
      }
      sEv[e] = ev;
      emax = fmaxf(emax, ev);
    }
    emax = fmaxf(emax, __shfl_xor(emax, 1));
    emax = fmaxf(emax, __shfl_xor(emax, 2));
    emax = fmaxf(emax, __shfl_xor(emax, 4));

    // self-loop via linearity: mean of p1 over edges; lane owns cols sub*4..+3
    float m0=0.f, m1=0.f, m2=0.f, m3=0.f;
    for(int e=a; e<b; ++e){
      f4_t pv = *(const f4_t*)&sP[e][sub*4];     // banks (e*4+sub*4)%32: conflict-free
      m0 += pv[0]; m1 += pv[1]; m2 += pv[2]; m3 += pv[3];
    }
    float invd = 1.f / (float)(deg > 0 ? deg : 1);
    float sv;
    {
      int c0 = sub*4;
      sv  = att[c0+0]*lrelu(sXl[r][c0+0] + sXr[r][c0+0] + m0*invd);
      sv += att[c0+1]*lrelu(sXl[r][c0+1] + sXr[r][c0+1] + m1*invd);
      sv += att[c0+2]*lrelu(sXl[r][c0+2] + sXr[r][c0+2] + m2*invd);
      sv += att[c0+3]*lrelu(sXl[r][c0+3] + sXr[r][c0+3] + m3*invd);
    }
    sv += __shfl_xor(sv, 1);
    sv += __shfl_xor(sv, 2);
    sv += __shfl_xor(sv, 4);

    // softmax (z in place in sEv)
    float m = fmaxf(emax, sv);
    float ssum = 0.f;
    for(int e=a+sub; e<b; e+=8){
      float z = sexp(sEv[e] - m);
      sEv[e] = z;
      ssum += z;
    }
    ssum += __shfl_xor(ssum, 1);
    ssum += __shfl_xor(ssum, 2);
    ssum += __shfl_xor(ssum, 4);
    float selfZ = sexp(sv - m);
    float rden = 1.f / fmaxf(ssum + selfZ, 1e-30f);

    // aggregation: lane owns cols sub*4..+3
    float a0=0.f, a1=0.f, a2=0.f, a3=0.f;
    for(int e=a; e<b; ++e){
      float z = sEv[e];
      f4_t xlv = *(const f4_t*)&sXl[sSl[e]][sub*4];
      a0 += z*xlv[0]; a1 += z*xlv[1]; a2 += z*xlv[2]; a3 += z*xlv[3];
    }
    f4_t xself = *(const f4_t*)&sXl[r][sub*4];
    f4_t outv, sqv;
    {
      float o;
      o = (a0 + selfZ*xself[0]) * rden; o = fmaxf(o + wb[obo1+sub*4+0], 0.f); outv[0]=o; sqv[0]=o*o;
      o = (a1 + selfZ*xself[1]) * rden; o = fmaxf(o + wb[obo1+sub*4+1], 0.f); outv[1]=o; sqv[1]=o*o;
      o = (a2 + selfZ*xself[2]) * rden; o = fmaxf(o + wb[obo1+sub*4+2], 0.f); outv[2]=o; sqv[2]=o*o;
      o = (a3 + selfZ*xself[3]) * rden; o = fmaxf(o + wb[obo1+sub*4+3], 0.f); outv[3]=o; sqv[3]=o*o;
    }
    *(f4_t*)&h1[((size_t)nb + r)*32 + sub*4] = outv;
    *(f4_t*)&sPS[r][sub*4] = outv;
    *(f4_t*)&sPQ[r][sub*4] = sqv;
  }
  __syncthreads();   // barrier 2
  if(t < 32){
    float s=0.f, q=0.f;
    #pragma unroll
    for(int r=0;r<24;r++){ s += sPS[r][t]; q += sPQ[r][t]; }
    p1sum[g*32+t] = s; p1sq[g*32+t] = q;
  }
}

// ======== p-tier pass 2: layer2 from h1, rows fully parallel, p2 precomputed ========
__global__ __launch_bounds__(256, 6) void k_fused2_p(
    const float* __restrict__ p2,
    const float* __restrict__ wb, const float* __restrict__ wq,
    const float* __restrict__ h1,
    const int* __restrict__ offs, const int* __restrict__ spack,
    float* __restrict__ gsum2, float* __restrict__ gsq2)
{
  __shared__ float sXl2[24][13];
  __shared__ float sXr2[24][13];
  __shared__ float sEv[CAP];
  __shared__ int   sSl[CAP];
  __shared__ int   sRO[25];
  __shared__ float sGS[24][8];
  __shared__ float sGQ[24][8];

  const int t = threadIdx.x;
  const int g = blockIdx.x;
  const int wid = t >> 6;
  const int lane = t & 63;
  const int nb = g*PP;
  const int eb = offs[nb];
  int ecnt = offs[nb+24] - eb;
  if(ecnt < 0) ecnt = 0; if(ecnt > CAP) ecnt = CAP;

  if(t < 25){
    int v = offs[nb+t] - eb;
    if(v < 0) v = 0; if(v > CAP) v = CAP;
    sRO[t] = v;
  }
  for(int i=t; i<ecnt; i+=256){
    int sl = spack[eb+i] & 31; if(sl > 23) sl = 0;
    sSl[i] = sl;
  }
  // projection xl2/xr2 (BN folded): wave wid computes rows 6*wid..6*wid+5
  {
    int rz = wid*6;
    for(int i=lane; i<96; i+=64){
      int rl = i>>4, cc = i&15;
      int r = rz + rl;
      float s = wq[oB2P + cc];
      const float* hr = h1 + ((size_t)nb + r)*32;
      #pragma unroll
      for(int q=0;q<8;q++){
        f4_t hv = *(const f4_t*)(hr + q*4);
        s += hv[0]*wq[oW2P+(q*4+0)*16+cc] + hv[1]*wq[oW2P+(q*4+1)*16+cc]
           + hv[2]*wq[oW2P+(q*4+2)*16+cc] + hv[3]*wq[oW2P+(q*4+3)*16+cc];
      }
      if(cc < 8) sXl2[r][cc] = s; else sXr2[r][cc-8] = s;
    }
  }
  __syncthreads();   // barrier 1

  if(t < 192){
    const int r = t >> 3, sub = t & 7;
    const int a = sRO[r], b = sRO[r+1];
    const int deg = b - a;
    const float* att2 = wb + oatt2;

    float emax = -3.4e38f;
    for(int e=a+sub; e<b; e+=8){
      int sl = sSl[e];
      const float* pe = p2 + (size_t)(eb+e)*8;
      float ev = 0.f;
      #pragma unroll
      for(int j=0;j<8;j++)
        ev += att2[j]*lrelu(sXl2[sl][j] + sXr2[r][j] + pe[j]);
      sEv[e] = ev;
      emax = fmaxf(emax, ev);
    }
    emax = fmaxf(emax, __shfl_xor(emax, 1));
    emax = fmaxf(emax, __shfl_xor(emax, 2));
    emax = fmaxf(emax, __shfl_xor(emax, 4));

    // self-loop via mean p2; lane owns col sub
    float mpc = 0.f;
    for(int e=a; e<b; ++e)
      mpc += p2[(size_t)(eb+e)*8 + sub];
    float invd = 1.f / (float)(deg > 0 ? deg : 1);
    float sv = att2[sub]*lrelu(sXl2[r][sub] + sXr2[r][sub] + mpc*invd);
    sv += __shfl_xor(sv, 1);
    sv += __shfl_xor(sv, 2);
    sv += __shfl_xor(sv, 4);

    float m = fmaxf(emax, sv);
    float ssum = 0.f;
    for(int e=a+sub; e<b; e+=8){
      float z = sexp(sEv[e] - m);
      sEv[e] = z;
      ssum += z;
    }
    ssum += __shfl_xor(ssum, 1);
    ssum += __shfl_xor(ssum, 2);
    ssum += __shfl_xor(ssum, 4);
    float selfZ = sexp(sv - m);
    float rden = 1.f / fmaxf(ssum + selfZ, 1e-30f);

    float acc = 0.f;
    for(int e=a; e<b; ++e)
      acc += sEv[e] * sXl2[sSl[e]][sub];
    float o = (acc + selfZ*sXl2[r][sub]) * rden;
    float s = 1.f / (1.f + __expf(-(o + wb[obo2+sub])));
    sGS[r][sub] = s;
    sGQ[r][sub] = s*s;
  }
  __syncthreads();   // barrier 2
  if(t < 8){
    float gs=0.f, gq=0.f;
    #pragma unroll
    for(int r=0;r<24;r++){ gs += sGS[r][t]; gq += sGQ[r][t]; }
    gsum2[g*8+t] = gs; gsq2[g*8+t] = gq;
  }
}

// ======== mid tier (round-3, measured 705us) kernels, verbatim fallback ========
__global__ __launch_bounds__(256, 6) void k_l1stats(
    const void* __restrict__ x, const void* __restrict__ ea, const float* __restrict__ eap,
    const float* __restrict__ wb, const float* __restrict__ wq,
    const int* __restrict__ offs, const int* __restrict__ spack, const int* __restrict__ dflag,
    float* __restrict__ p1sum, float* __restrict__ p1sq,
    float* __restrict__ h1, int use_h1)
{
  __shared__ __align__(16) float sEaF[CAP][16];
  __shared__ __align__(16) float sXl[24][36];
  __shared__ float sXr[24][33];
  __shared__ float sEaSum[24][17];
  __shared__ float sEv[CAP];
  __shared__ int   sSl[CAP];
  __shared__ int   sRO[25];
  __shared__ float sSelfE[24];
  __shared__ float sPS[4][32], sPQ[4][32];

  const int t = threadIdx.x;
  const int g = blockIdx.x;
  const int wid = t >> 6;
  const int lane = t & 63;
  const int isf = dflag[0];
  const int nb = g*PP;
  const int eb = offs[nb];
  int ecnt = offs[nb+24] - eb; if(ecnt < 0) ecnt = 0; if(ecnt > CAP) ecnt = CAP;

  if(t < 25){
    int v = offs[nb+t] - eb;
    if(v < 0) v = 0; if(v > CAP) v = CAP;
    sRO[t] = v;
  }
  if(eap){
    for(int i=t; i<ecnt; i+=256) sSl[i] = spack[eb+i] & 1023;
    for(int i=t; i<ecnt*4; i+=256){
      int e = i>>2, q = i&3;
      *(f4_t*)&sEaF[e][q*4] = *(const f4_t*)(eap + ((size_t)(eb+e))*16 + q*4);
    }
  } else {
    for(int i=t; i<ecnt; i+=256){
      int sp = spack[eb+i];
      sSl[i] = sp & 1023;
      u32 id = ((u32)sp) >> 10;
      if(id >= (u32)EE) id = 0;
      if(isf){
        const float* er = (const float*)ea + (size_t)id*16;
        #pragma unroll
        for(int q=0;q<4;q++) *(f4_t*)&sEaF[i][q*4] = *(const f4_t*)(er + q*4);
      } else {
        #pragma unroll
        for(int c=0;c<16;c++) sEaF[i][c] = bf2f(((const u16*)ea)[(size_t)id*16 + c]);
      }
    }
  }
  {
    int rz = wid*6;
    for(int i=lane; i<6*17; i+=64) sEaSum[rz + i/17][i%17] = 0.f;
  }

  {
    const int c = t & 31, mat = (t>>5)&1, w = wid, cc = t&63;
    const float* gW = wq + oW1I;
    float bi = wb[(mat ? obr1 : obl1) + c];
    float acc[6];
    #pragma unroll
    for(int j=0;j<6;j++) acc[j] = bi;
    if(isf){
      const float* xr0 = (const float*)x + (size_t)(nb + w*6)*96;
      for(int kb=0; kb<19; kb++){
        float w0 = gW[(kb*4+0)*64 + cc];
        float w1 = gW[(kb*4+1)*64 + cc];
        float w2 = gW[(kb*4+2)*64 + cc];
        float w3 = gW[(kb*4+3)*64 + cc];
        #pragma unroll
        for(int j=0;j<6;j++){
          f4_t xv = *(const f4_t*)(xr0 + (size_t)j*96 + kb*4);
          acc[j] += xv[0]*w0 + xv[1]*w1 + xv[2]*w2 + xv[3]*w3;
        }
      }
    } else {
      const u16* xr0 = (const u16*)x + (size_t)(nb + w*6)*96;
      for(int kb=0; kb<19; kb++){
        float w0 = gW[(kb*4+0)*64 + cc];
        float w1 = gW[(kb*4+1)*64 + cc];
        float w2 = gW[(kb*4+2)*64 + cc];
        float w3 = gW[(kb*4+3)*64 + cc];
        #pragma unroll
        for(int j=0;j<6;j++){
          us4_t xv = *(const us4_t*)(xr0 + (size_t)j*96 + kb*4);
          acc[j] += bf2f(xv[0])*w0 + bf2f(xv[1])*w1 + bf2f(xv[2])*w2 + bf2f(xv[3])*w3;
        }
      }
    }
    if(mat){
      #pragma unroll
      for(int j=0;j<6;j++) sXr[w*6+j][c] = acc[j];
    } else {
      #pragma unroll
      for(int j=0;j<6;j++) sXl[w*6+j][c] = acc[j];
    }
  }
  __syncthreads();

  const int r0 = wid*6;
  const int a0 = sRO[r0], a1 = sRO[r0+6];
  const int c = t & 31, eo = (t>>5)&1;

  float wr[16];
  #pragma unroll
  for(int k=0;k<16;k++) wr[k] = wb[oWe1 + k*32 + c];
  const float av = wb[oatt1 + c];
  const float bv = wb[obo1 + c];

  for(int base=a0; base<a1; base+=2){
    int e = base + eo;
    bool valid = (e < a1);
    int ec = valid ? e : a0;
    int sp = sSl[ec];
    int sl = sp & 31; if(sl > 23) sl = 0;
    int dl = (sp >> 5) & 31; if(dl > 23) dl = 0;
    f4_t A0 = *(const f4_t*)&sEaF[ec][0];
    f4_t A1 = *(const f4_t*)&sEaF[ec][4];
    f4_t A2 = *(const f4_t*)&sEaF[ec][8];
    f4_t A3 = *(const f4_t*)&sEaF[ec][12];
    float p = A0[0]*wr[0]+A0[1]*wr[1]+A0[2]*wr[2]+A0[3]*wr[3]
            + A1[0]*wr[4]+A1[1]*wr[5]+A1[2]*wr[6]+A1[3]*wr[7]
            + A2[0]*wr[8]+A2[1]*wr[9]+A2[2]*wr[10]+A2[3]*wr[11]
            + A3[0]*wr[12]+A3[1]*wr[13]+A3[2]*wr[14]+A3[3]*wr[15];
    if(valid && c < 16) atomicAdd(&sEaSum[dl][c], sEaF[ec][c]);
    float v = lrelu(sXl[sl][c] + sXr[dl][c] + p) * av;
    v += __shfl_xor(v, 16);
    v += __shfl_xor(v, 8);
    v += __shfl_xor(v, 4);
    v += __shfl_xor(v, 2);
    v += __shfl_xor(v, 1);
    if(valid && c == 0) sEv[e] = v;
  }

  #pragma unroll
  for(int rp=0; rp<3; rp++){
    int r = r0 + rp*2 + eo;
    int deg = sRO[r+1] - sRO[r];
    float invd = 1.f / (float)(deg > 0 ? deg : 1);
    float mp = 0.f;
    #pragma unroll
    for(int k=0;k<16;k++) mp += sEaSum[r][k] * wr[k];
    float v = lrelu(sXl[r][c] + sXr[r][c] + mp*invd) * av;
    v += __shfl_xor(v, 16);
    v += __shfl_xor(v, 8);
    v += __shfl_xor(v, 4);
    v += __shfl_xor(v, 2);
    v += __shfl_xor(v, 1);
    if(c == 0) sSelfE[r] = v;
  }

  float ps = 0.f, pq = 0.f;
  const int h = (t >> 5) & 1;
  #pragma unroll
  for(int j=0;j<6;j++){
    int r = r0 + j;
    int a = sRO[r], b = sRO[r+1];
    float selfE = sSelfE[r];
    float mx = -3.4e38f;
    for(int e=a+lane; e<b; e+=64) mx = fmaxf(mx, sEv[e]);
    mx = fmaxf(mx, __shfl_xor(mx, 32));
    mx = fmaxf(mx, __shfl_xor(mx, 16));
    mx = fmaxf(mx, __shfl_xor(mx, 8));
    mx = fmaxf(mx, __shfl_xor(mx, 4));
    mx = fmaxf(mx, __shfl_xor(mx, 2));
    mx = fmaxf(mx, __shfl_xor(mx, 1));
    float m = fmaxf(mx, selfE);
    float ds = 0.f;
    for(int e=a+lane; e<b; e+=64){
      float z = sexp(sEv[e] - m);
      sEv[e] = z;
      ds += z;
    }
    ds += __shfl_xor(ds, 32);
    ds += __shfl_xor(ds, 16);
    ds += __shfl_xor(ds, 8);
    ds += __shfl_xor(ds, 4);
    ds += __shfl_xor(ds, 2);
    ds += __shfl_xor(ds, 1);
    float selfZ = sexp(selfE - m);
    float rden = 1.f / fmaxf(ds + selfZ, 1e-30f);
    float acc = 0.f;
    for(int e=a+h; e<b; e+=2){
      int sl = sSl[e] & 31; if(sl > 23) sl = 0;
      acc += sEv[e] * sXl[sl][c];
    }
    acc += __shfl_xor(acc, 32);
    float out = (acc + selfZ * sXl[r][c]) * rden;
    out = fmaxf(out + bv, 0.f);
    if(h == 0){
      if(use_h1) h1[((size_t)nb + r)*32 + c] = out;
      ps += out; pq += out*out;
    }
  }
  if(h == 0){ sPS[wid][c] = ps; sPQ[wid][c] = pq; }
  __syncthreads();
  if(t < 32){
    p1sum[g*32+t] = sPS[0][t]+sPS[1][t]+sPS[2][t]+sPS[3][t];
    p1sq[g*32+t]  = sPQ[0][t]+sPQ[1][t]+sPQ[2][t]+sPQ[3][t];
  }
}

// ---------------- BN stats -> affine ----------------
__global__ void k_reduce(const float* __restrict__ ps, const float* __restrict__ pq,
                         const void* __restrict__ gamma, const void* __restrict__ beta,
                         const int* __restrict__ dflag,
                         float* __restrict__ stats, int F){
  __shared__ float rs[256], rq[256];
  int f = blockIdx.x, t = threadIdx.x;
  float s=0.f, q=0.f;
  for(int g=t; g<GG; g+=256){ s += ps[g*F+f]; q += pq[g*F+f]; }
  rs[t]=s; rq[t]=q; __syncthreads();
  for(int off=128; off>0; off>>=1){
    if(t<off){ rs[t]+=rs[t+off]; rq[t]+=rq[t+off]; }
    __syncthreads();
  }
  if(t==0){
    int isf = dflag[0];
    float mu  = rs[0] * (1.f/(float)NN);
    float var = rq[0] * (1.f/(float)NN) - mu*mu;
    if(var < 0.f) var = 0.f;
    float sc  = ldf(gamma,f,isf) / sqrtf(var + 1e-5f);
    stats[f]   = sc;
    stats[F+f] = ldf(beta,f,isf) - mu*sc;
  }
}

// -------- mid-tier layer2 from stored h1, wave-local (round-3, verbatim) --------
__global__ __launch_bounds__(256, 6) void k_fused2_h1(
    const void* __restrict__ ea, const float* __restrict__ eap,
    const float* __restrict__ wb, const float* __restrict__ wq,
    const float* __restrict__ h1,
    const int* __restrict__ offs, const int* __restrict__ spack, const int* __restrict__ dflag,
    float* __restrict__ gsum2, float* __restrict__ gsq2)
{
  __shared__ __align__(16) float sEaF[CAP][16];
  __shared__ float sXl2[24][12], sXr2[24][12];
  __shared__ float sEaSum[24][17];
  __shared__ float sEv[CAP];
  __shared__ int   sSl[CAP];
  __shared__ int   sRO[25];
  __shared__ float sSelfE[24];
  __shared__ float sGS[4][8], sGQ[4][8];

  const int t = threadIdx.x;
  const int g = blockIdx.x;
  const int wid = t >> 6;
  const int lane = t & 63;
  const int isf = dflag[0];
  const int nb = g*PP;
  const int eb = offs[nb];
  int ecnt = offs[nb+24] - eb; if(ecnt < 0) ecnt = 0; if(ecnt > CAP) ecnt = CAP;

  if(t < 25){
    int v = offs[nb+t] - eb;
    if(v < 0) v = 0; if(v > CAP) v = CAP;
    sRO[t] = v;
  }
  if(eap){
    for(int i=t; i<ecnt; i+=256) sSl[i] = spack[eb+i] & 1023;
    for(int i=t; i<ecnt*4; i+=256){
      int e = i>>2, q = i&3;
      *(f4_t*)&sEaF[e][q*4] = *(const f4_t*)(eap + ((size_t)(eb+e))*16 + q*4);
    }
  } else {
    for(int i=t; i<ecnt; i+=256){
      int sp = spack[eb+i];
      sSl[i] = sp & 1023;
      u32 id = ((u32)sp) >> 10;
      if(id >= (u32)EE) id = 0;
      if(isf){
        const float* er = (const float*)ea + (size_t)id*16;
        #pragma unroll
        for(int q=0;q<4;q++) *(f4_t*)&sEaF[i][q*4] = *(const f4_t*)(er + q*4);
      } else {
        #pragma unroll
        for(int c=0;c<16;c++) sEaF[i][c] = bf2f(((const u16*)ea)[(size_t)id*16 + c]);
      }
    }
  }
  {
    int rz = wid*6;
    for(int i=lane; i<6*17; i+=64) sEaSum[rz + i/17][i%17] = 0.f;
    for(int i=lane; i<96; i+=64){
      int rl = i>>4, cc = i&15;
      int r = rz + rl;
      float s = wq[oB2P + cc];
      const float* hr = h1 + ((size_t)nb + r)*32;
      #pragma unroll
      for(int q=0;q<8;q++){
        f4_t hv = *(const f4_t*)(hr + q*4);
        s += hv[0]*wq[oW2P+(q*4+0)*16+cc] + hv[1]*wq[oW2P+(q*4+1)*16+cc]
           + hv[2]*wq[oW2P+(q*4+2)*16+cc] + hv[3]*wq[oW2P+(q*4+3)*16+cc];
      }
      if(cc < 8) sXl2[r][cc] = s; else sXr2[r][cc-8] = s;
    }
  }
  __syncthreads();

  const int r0 = wid*6;
  const int a0 = sRO[r0], a1 = sRO[r0+6];
  const int c = t & 7;
  const int eo = lane >> 3;

  float wr[16];
  #pragma unroll
  for(int k=0;k<16;k++) wr[k] = wb[oWe2 + k*8 + c];
  const float av = wb[oatt2 + c];
  const float bv = wb[obo2 + c];

  for(int base=a0; base<a1; base+=8){
    int e = base + eo;
    bool valid = (e < a1);
    int ec = valid ? e : a0;
    int sp = sSl[ec];
    int sl = sp & 31; if(sl > 23) sl = 0;
    int dl = (sp >> 5) & 31; if(dl > 23) dl = 0;
    f4_t A0 = *(const f4_t*)&sEaF[ec][0];
    f4_t A1 = *(const f4_t*)&sEaF[ec][4];
    f4_t A2 = *(const f4_t*)&sEaF[ec][8];
    f4_t A3 = *(const f4_t*)&sEaF[ec][12];
    float p = A0[0]*wr[0]+A0[1]*wr[1]+A0[2]*wr[2]+A0[3]*wr[3]
            + A1[0]*wr[4]+A1[1]*wr[5]+A1[2]*wr[6]+A1[3]*wr[7]
            + A2[0]*wr[8]+A2[1]*wr[9]+A2[2]*wr[10]+A2[3]*wr[11]
            + A3[0]*wr[12]+A3[1]*wr[13]+A3[2]*wr[14]+A3[3]*wr[15];
    if(valid){
      atomicAdd(&sEaSum[dl][c],   sEaF[ec][c]);
      atomicAdd(&sEaSum[dl][c+8], sEaF[ec][c+8]);
    }
    float v = lrelu(sXl2[sl][c] + sXr2[dl][c] + p) * av;
    v += __shfl_xor(v, 4);
    v += __shfl_xor(v, 2);
    v += __shfl_xor(v, 1);
    if(valid && c == 0) sEv[e] = v;
  }

  {
    int rr = r0 + (eo < 6 ? eo : 0);
    bool valid = (eo < 6);
    int deg = sRO[rr+1] - sRO[rr];
    float invd = 1.f / (float)(deg > 0 ? deg : 1);
    float mp = 0.f;
    #pragma unroll
    for(int k=0;k<16;k++) mp += sEaSum[rr][k] * wr[k];
    float v = lrelu(sXl2[rr][c] + sXr2[rr][c] + mp*invd) * av;
    v += __shfl_xor(v, 4);
    v += __shfl_xor(v, 2);
    v += __shfl_xor(v, 1);
    if(valid && c == 0) sSelfE[rr] = v;
  }

  float gs = 0.f, gq = 0.f;
  #pragma unroll
  for(int j=0;j<6;j++){
    int r = r0 + j;
    int a = sRO[r], b = sRO[r+1];
    float selfE = sSelfE[r];
    float mx = -3.4e38f;
    for(int e=a+lane; e<b; e+=64) mx = fmaxf(mx, sEv[e]);
    mx = fmaxf(mx, __shfl_xor(mx, 32));
    mx = fmaxf(mx, __shfl_xor(mx, 16));
    mx = fmaxf(mx, __shfl_xor(mx, 8));
    mx = fmaxf(mx, __shfl_xor(mx, 4));
    mx = fmaxf(mx, __shfl_xor(mx, 2));
    mx = fmaxf(mx, __shfl_xor(mx, 1));
    float m = fmaxf(mx, selfE);
    float ds = 0.f;
    for(int e=a+lane; e<b; e+=64){
      float z = sexp(sEv[e] - m);
      sEv[e] = z;
      ds += z;
    }
    ds += __shfl_xor(ds, 32);
    ds += __shfl_xor(ds, 16);
    ds += __shfl_xor(ds, 8);
    ds += __shfl_xor(ds, 4);
    ds += __shfl_xor(ds, 2);
    ds += __shfl_xor(ds, 1);
    float selfZ = sexp(selfE - m);
    float rden = 1.f / fmaxf(ds + selfZ, 1e-30f);
    float acc = 0.f;
    for(int e=a+eo; e<b; e+=8){
      int sl = sSl[e] & 31; if(sl > 23) sl = 0;
      acc += sEv[e] * sXl2[sl][c];
    }
    acc += __shfl_xor(acc, 8);
    acc += __shfl_xor(acc, 16);
    acc += __shfl_xor(acc, 32);
    float out = (acc + selfZ * sXl2[r][c]) * rden;
    float s = 1.f / (1.f + __expf(-(out + bv)));
    if(eo == 0){ gs += s; gq += s*s; }
  }
  if(eo == 0){ sGS[wid][c] = gs; sGQ[wid][c] = gq; }
  __syncthreads();
  if(t < 8){
    gsum2[g*8+t] = sGS[0][t]+sGS[1][t]+sGS[2][t]+sGS[3][t];
    gsq2[g*8+t]  = sGQ[0][t]+sGQ[1][t]+sGQ[2][t]+sGQ[3][t];
  }
}

// -------- fallback: recompute layer1 + layer2 (ws-lean, round-3 verbatim) --------
__global__ __launch_bounds__(256) void k_fused2_rec(
    const void* __restrict__ x, const void* __restrict__ ea,
    const float* __restrict__ wb, const float* __restrict__ stats1,
    const int* __restrict__ offs, const int* __restrict__ spack, const int* __restrict__ dflag,
    float* __restrict__ gsum2, float* __restrict__ gsq2)
{
  __shared__ float sXrow[24][76];
  __shared__ float sEaF[CAP][17];
  __shared__ __align__(16) float sXl[24][36];
  __shared__ __align__(16) float sXr[24][36];
  __shared__ __align__(16) float sOut[24][36];
  __shared__ float sH[24][33];
  __shared__ float sXl2[24][12], sXr2[24][12], sOut2[24][12];
  __shared__ float sEapSum[24][32];
  __shared__ float sEv[CAP], sEz[CAP];
  __shared__ int   sSp[CAP];
  __shared__ int   sDeg[24];
  __shared__ u32   sMaxU[24];
  __shared__ float sMaxF[24], sDen[24], sSelfZ[24];
  __shared__ float sAtt[32], sBo[32], sSc[32], sSh[32];

  const int t = threadIdx.x;
  const int g = blockIdx.x;
  const int isf = dflag[0];
  int eb = offs[g*24], ee = offs[(g+1)*24];
  if(eb < 0) eb = 0; if(eb > EE) eb = EE;
  if(ee < eb) ee = eb; if(ee > EE) ee = EE;
  int ecnt = ee - eb; if(ecnt > CAP) ecnt = CAP;

  for(int i=t; i<24*74; i+=256){
    int r = i/74, c = i%74;
    sXrow[r][c] = ldf(x, (size_t)(g*PP + r)*96 + c, isf);
  }
  for(int i=t; i<CAP; i+=256) sSp[i] = (i<ecnt) ? spack[eb+i] : 0;
  if(t < 32){ sAtt[t]=wb[oatt1+t]; sBo[t]=wb[obo1+t]; sSc[t]=stats1[t]; sSh[t]=stats1[32+t]; }
  if(t < 24){ sDeg[t]=0; sMaxU[t]=0u; sDen[t]=0.f; }
  for(int i=t; i<24*32; i+=256) sEapSum[i>>5][i&31] = 0.f;
  __syncthreads();
  for(int i=t; i<CAP*16; i+=256){
    int e = i>>4, c = i&15;
    float v = 0.f;
    if(e < ecnt){
      u32 id = ((u32)sSp[e]) >> 10;
      if(id >= (u32)EE) id = 0;
      v = ldf(ea, (size_t)id*16 + c, isf);
    }
    sEaF[e][c] = v;
  }
  __syncthreads();

  {
    int c = t & 31, rr0 = t >> 5;
    for(int r = rr0; r < 24; r += 8){
      float al = wb[obl1+c], ar = wb[obr1+c];
      for(int k=0;k<74;k++){
        float xv = sXrow[r][k];
        al += xv * wb[oWl1 + k*32 + c];
        ar += xv * wb[oWr1 + k*32 + c];
      }
      sXl[r][c] = al; sXr[r][c] = ar;
    }
  }
  __syncthreads();

  for(int e=t; e<ecnt; e+=256){
    int sp = sSp[e];
    int sl = sp & 31; if(sl > 23) sl = 0;
    int dl = (sp >> 5) & 31; if(dl > 23) dl = 0;
    float ev = 0.f;
    for(int c=0;c<32;c++){
      float p = 0.f;
      for(int k=0;k<16;k++) p += sEaF[e][k] * wb[oWe1 + k*32 + c];
      atomicAdd(&sEapSum[dl][c], p);
      ev += lrelu(sXl[sl][c] + sXr[dl][c] + p) * sAtt[c];
    }
    sEv[e] = ev;
    atomicMax(&sMaxU[dl], fkey(ev));
    atomicAdd(&sDeg[dl], 1);
  }
  __syncthreads();

  if(t < 24){
    float invd = 1.f / (float)(sDeg[t] > 0 ? sDeg[t] : 1);
    float ev = 0.f;
    for(int c=0;c<32;c++)
      ev += lrelu(sXl[t][c] + sXr[t][c] + sEapSum[t][c]*invd) * sAtt[c];
    float mxv = (sDeg[t] > 0) ? fmaxf(funkey(sMaxU[t]), ev) : ev;
    sMaxF[t] = mxv;
    float z = sexp(ev - mxv);
    sSelfZ[t] = z;
    sDen[t] = z;
  }
  __syncthreads();

  for(int e=t; e<ecnt; e+=256){
    int dl = (sSp[e]>>5)&31; if(dl > 23) dl = 0;
    float z = sexp(sEv[e] - sMaxF[dl]);
    sEz[e] = z;
    atomicAdd(&sDen[dl], z);
  }
  __syncthreads();

  for(int e=t; e<ecnt; e+=256){
    int dl = (sSp[e]>>5)&31; if(dl > 23) dl = 0;
    sEz[e] /= fmaxf(sDen[dl], 1e-30f);
  }
  if(t < 24) sSelfZ[t] /= fmaxf(sDen[t], 1e-30f);
  __syncthreads();

  for(int o=t; o<24*8; o+=256){
    int nl = o >> 3, cq = (o & 7)*4;
    float al = sSelfZ[nl];
    f4_t xv = *(const f4_t*)&sXl[nl][cq];
    f4_t r;
    #pragma unroll
    for(int j=0;j<4;j++) r[j] = al*xv[j];
    *(f4_t*)&sOut[nl][cq] = r;
  }
  __syncthreads();

  for(int o=t; o<ecnt*8; o+=256){
    int e = o >> 3, cq = (o & 7)*4;
    int sp = sSp[e];
    int sl = sp & 31; if(sl > 23) sl = 0;
    int dl = (sp >> 5) & 31; if(dl > 23) dl = 0;
    float al = sEz[e];
    f4_t xv = *(const f4_t*)&sXl[sl][cq];
    atomicAdd(&sOut[dl][cq+0], al*xv[0]);
    atomicAdd(&sOut[dl][cq+1], al*xv[1]);
    atomicAdd(&sOut[dl][cq+2], al*xv[2]);
    atomicAdd(&sOut[dl][cq+3], al*xv[3]);
  }
  __syncthreads();

  for(int i=t; i<24*32; i+=256){
    int r = i>>5, c = i&31;
    float v = fmaxf(sOut[r][c] + sBo[c], 0.f);
    sH[r][c] = v*sSc[c] + sSh[c];
  }
  __syncthreads();
  if(t < 24){ sDeg[t]=0; sMaxU[t]=0u; sDen[t]=0.f; }
  for(int i=t; i<24*8; i+=256) sEapSum[i>>3][i&7] = 0.f;
  __syncthreads();

  if(t < 24*8*2){
    int mat = t/192, rem = t%192, r = rem/8, c = rem&7;
    const float* Wm = wb + (mat ? oWr2 : oWl2);
    float s = wb[(mat ? obr2 : obl2) + c];
    for(int k=0;k<32;k++) s += sH[r][k]*Wm[k*8+c];
    if(mat) sXr2[r][c] = s; else sXl2[r][c] = s;
  }
  __syncthreads();

  for(int e=t; e<ecnt; e+=256){
    int sp = sSp[e];
    int sl = sp & 31; if(sl > 23) sl = 0;
    int dl = (sp >> 5) & 31; if(dl > 23) dl = 0;
    float ev = 0.f;
    for(int c=0;c<8;c++){
      float p = 0.f;
      for(int k=0;k<16;k++) p += sEaF[e][k] * wb[oWe2 + k*8 + c];
      atomicAdd(&sEapSum[dl][c], p);
      ev += lrelu(sXl2[sl][c] + sXr2[dl][c] + p) * wb[oatt2+c];
    }
    sEv[e] = ev;
    atomicMax(&sMaxU[dl], fkey(ev));
    atomicAdd(&sDeg[dl], 1);
  }
  __syncthreads();

  if(t < 24){
    float invd = 1.f / (float)(sDeg[t] > 0 ? sDeg[t] : 1);
    float ev = 0.f;
    for(int c=0;c<8;c++)
      ev += lrelu(sXl2[t][c] + sXr2[t][c] + sEapSum[t][c]*invd) * wb[oatt2+c];
    float mxv = (sDeg[t] > 0) ? fmaxf(funkey(sMaxU[t]), ev) : ev;
    sMaxF[t] = mxv;
    float z = sexp(ev - mxv);
    sSelfZ[t] = z;
    sDen[t] = z;
  }
  __syncthreads();

  for(int e=t; e<ecnt; e+=256){
    int dl = (sSp[e]>>5)&31; if(dl > 23) dl = 0;
    float z = sexp(sEv[e] - sMaxF[dl]);
    sEz[e] = z;
    atomicAdd(&sDen[dl], z);
  }
  __syncthreads();

  for(int e=t; e<ecnt; e+=256){
    int dl = (sSp[e]>>5)&31; if(dl > 23) dl = 0;
    sEz[e] /= fmaxf(sDen[dl], 1e-30f);
  }
  if(t < 24) sSelfZ[t] /= fmaxf(sDen[t], 1e-30f);
  __syncthreads();

  for(int o=t; o<24*8; o+=256){
    int nl = o >> 3, c = o & 7;
    sOut2[nl][c] = sSelfZ[nl] * sXl2[nl][c];
  }
  __syncthreads();

  for(int o=t; o<ecnt*8; o+=256){
    int e = o >> 3, c = o & 7;
    int sp = sSp[e];
    int sl = sp & 31; if(sl > 23) sl = 0;
    int dl = (sp >> 5) & 31; if(dl > 23) dl = 0;
    atomicAdd(&sOut2[dl][c], sEz[e]*sXl2[sl][c]);
  }
  __syncthreads();

  if(t < 8){
    float gs=0.f, gq=0.f;
    for(int nl=0; nl<24; nl++){
      float v = sOut2[nl][t] + wb[obo2+t];
      float s = 1.f / (1.f + __expf(-v));
      gs += s; gq += s*s;
    }
    gsum2[g*8+t] = gs; gsq2[g*8+t] = gq;
  }
}

// ---------------- MLP head ----------------
__global__ __launch_bounds__(256) void k_mlp(
    const float* __restrict__ gsum2, const float* __restrict__ stats2,
    const void* __restrict__ x, const int* __restrict__ dflag,
    const float* __restrict__ wb, float* __restrict__ out)
{
  __shared__ float w[1702];
  int t = threadIdx.x;
  for(int i=t; i<1702; i+=256) w[i] = wb[6048+i];
  __syncthreads();
  int g = blockIdx.x*256 + t;
  int isf = dflag[0];
  float a[30], b[32];
  for(int c=0;c<8;c++) a[c] = stats2[c]*(gsum2[(size_t)g*8+c]*(1.f/24.f)) + stats2[8+c];
  size_t xoff = (size_t)g*PP*96 + 74;
  for(int j=0;j<22;j++) a[8+j] = ldf(x, xoff+j, isf);
  for(int o=0;o<32;o++){ float s = w[960+o];  for(int i=0;i<30;i++) s += a[i]*w[i*32+o];      b[o]=fmaxf(s,0.f); }
  for(int o=0;o<16;o++){ float s = w[1504+o]; for(int i=0;i<32;i++) s += b[i]*w[992+i*16+o];  a[o]=fmaxf(s,0.f); }
  for(int o=0;o<8;o++){  float s = w[1648+o]; for(int i=0;i<16;i++) s += a[i]*w[1520+i*8+o];  b[o]=fmaxf(s,0.f); }
  for(int o=0;o<4;o++){  float s = w[1688+o]; for(int i=0;i<8;i++)  s += b[i]*w[1656+i*4+o];  a[o]=fmaxf(s,0.f); }
  for(int o=0;o<2;o++){
    float s = w[1700+o];
    for(int i=0;i<4;i++) s += a[i]*w[1692+i*2+o];
    out[(size_t)g*2+o] = s;
  }
}

extern "C" void kernel_launch(void* const* d_in, const int* in_sizes, int n_in,
                              void* d_out, int out_size, void* d_ws, size_t ws_size,
                              hipStream_t stream)
{
  (void)in_sizes; (void)n_in; (void)out_size;
  const void* x    = d_in[0];
  const int* eidx  = (const int*)d_in[1];
  const void* ea   = d_in[2];

  const int* srcA = eidx;
  const int* dstA = eidx + EE;

  constexpr size_t O_WB    = 0;
  constexpr size_t O_WQ    = 32768;
  constexpr size_t O_OFFS  = 57344;
  constexpr size_t O_CUR   = O_OFFS + (size_t)(NN+512)*4;
  constexpr size_t O_SPACK = O_CUR  + (size_t)NN*4;
  constexpr size_t O_P1S   = O_SPACK + (size_t)EE*4;
  constexpr size_t O_P1Q   = O_P1S   + (size_t)GG*32*4;
  constexpr size_t O_ST1   = O_P1Q   + (size_t)GG*32*4;
  constexpr size_t O_GS2   = O_ST1   + 256;
  constexpr size_t O_GQ2   = O_GS2   + (size_t)GG*8*4;
  constexpr size_t O_ST2   = O_GQ2   + (size_t)GG*8*4;
  constexpr size_t O_FLAG  = O_ST2   + 256;
  constexpr size_t REQUIRED_BASE = O_FLAG + 256;
  constexpr size_t O_H1    = REQUIRED_BASE;
  constexpr size_t REQUIRED_BIG = O_H1 + (size_t)NN*32*4;
  constexpr size_t O_EAP1  = REQUIRED_BIG;                       // eap16: EE*16 f32
  constexpr size_t O_P2    = O_EAP1 + (size_t)EE*16*4;           // p2: EE*8 f32
  constexpr size_t REQUIRED_P = O_P2 + (size_t)EE*8*4;
  constexpr size_t REQUIRED_EAP16 = O_EAP1 + (size_t)EE*16*4;

  if(ws_size < REQUIRED_BASE){
    k_zero<<<(GG*2+255)/256, 256, 0, stream>>>((float*)d_out);
    return;
  }
  const int use_h1  = (ws_size >= REQUIRED_BIG)   ? 1 : 0;
  const int use_p   = (use_h1 && ws_size >= REQUIRED_P) ? 1 : 0;
  const int use_eap = (!use_p && ws_size >= REQUIRED_EAP16) ? 1 : 0;

  char* W = (char*)d_ws;
  float* wb     = (float*)(W + O_WB);
  float* wq     = (float*)(W + O_WQ);
  int*   offs   = (int*)(W + O_OFFS);
  int*   bsum   = offs + NN + 64;
  int*   cnt    = (int*)(W + O_CUR);
  int*   cursor = (int*)(W + O_CUR);
  int*   spack  = (int*)(W + O_SPACK);
  float* p1sum  = (float*)(W + O_P1S);
  float* p1sq   = (float*)(W + O_P1Q);
  float* stats1 = (float*)(W + O_ST1);
  float* gsum2  = (float*)(W + O_GS2);
  float* gsq2   = (float*)(W + O_GQ2);
  float* stats2 = (float*)(W + O_ST2);
  int*   dflag  = (int*)(W + O_FLAG);
  float* h1     = (float*)(W + O_H1);
  float* eap1   = (float*)(W + O_EAP1);
  float* p2     = (float*)(W + O_P2);

  hipMemsetAsync(cnt, 0, (size_t)NN*sizeof(int), stream);
  k_count  <<<EE/256, 256, 0, stream>>>(dstA, cnt);
  k_scanA  <<<192, 1024, 0, stream>>>(cnt, offs, bsum);
  k_scanB  <<<1, 256, 0, stream>>>(bsum, offs);
  k_scanC  <<<192, 1024, 0, stream>>>(offs, bsum, cursor);
  k_scatter<<<EE/256, 256, 0, stream>>>(srcA, dstA, cursor, spack);
  k_wconv  <<<1, 256, 0, stream>>>(wb, wq, dflag, (const u32*)x,
            d_in[4], d_in[5], d_in[6], d_in[7], d_in[8], d_in[9], d_in[10],
            d_in[11], d_in[12], d_in[13], d_in[14], d_in[15], d_in[16], d_in[17],
            d_in[22], d_in[23], d_in[24], d_in[25], d_in[26], d_in[27],
            d_in[28], d_in[29], d_in[30], d_in[31]);
  if(use_p){
    k_eapermB<<<EE/256, 256, 0, stream>>>(spack, offs, ea, dflag, wb, eap1, p2);
    k_l1stats_p<<<GG, 256, 0, stream>>>(x, eap1, wb, wq, offs, spack, dflag,
                                        p1sum, p1sq, h1);
  } else {
    if(use_eap)
      k_eaperm<<<EE/256, 256, 0, stream>>>(spack, offs, ea, dflag, eap1);
    k_l1stats<<<GG, 256, 0, stream>>>(x, ea, use_eap ? eap1 : (float*)nullptr,
                                      wb, wq, offs, spack, dflag,
                                      p1sum, p1sq, h1, use_h1);
  }
  k_reduce <<<32, 256, 0, stream>>>(p1sum, p1sq, d_in[18], d_in[19], dflag, stats1, 32);
  k_prep2  <<<1, 256, 0, stream>>>(wq, wb, stats1);
  if(use_p)
    k_fused2_p<<<GG, 256, 0, stream>>>(p2, wb, wq, h1, offs, spack, gsum2, gsq2);
  else if(use_h1)
    k_fused2_h1<<<GG, 256, 0, stream>>>(ea, use_eap ? eap1 : (float*)nullptr,
                                        wb, wq, h1, offs, spack, dflag, gsum2, gsq2);
  else
    k_fused2_rec<<<GG, 256, 0, stream>>>(x, ea, wb, stats1, offs, spack, dflag, gsum2, gsq2);
  k_reduce <<<8, 256, 0, stream>>>(gsum2, gsq2, d_in[20], d_in[21], dflag, stats2, 8);
  k_mlp    <<<GG/256, 256, 0, stream>>>(gsum2, stats2, x, dflag, wb, (float*)d_out);
}

// Round 10
// 592.185 us; speedup vs baseline: 1.1075x; 1.0059x over previous
//
#include <hip/hip_runtime.h>

typedef unsigned short u16;
typedef unsigned int   u32;
typedef __attribute__((ext_vector_type(4))) float f4_t;
typedef __attribute__((ext_vector_type(4))) unsigned short us4_t;
typedef __attribute__((ext_vector_type(4))) unsigned int   u4_t;

#define GG 8192
#define PP 24
#define NN 196608
#define EE 786432
#define CAP 176

// ---- packed f32 weight buffer offsets (wb region) ----
#define oWl1 0
#define oWr1 2368
#define obl1 4736
#define obr1 4768
#define oWe1 4800
#define oatt1 5312
#define obo1 5344
#define oWl2 5376
#define oWr2 5632
#define obl2 5888
#define obr2 5896
#define oWe2 5904
#define oatt2 6032
#define obo2 6040
#define ofc1W 6048
#define ofc1b 7008
#define ofc2W 7040
#define ofc2b 7552
#define ofc3W 7568
#define ofc3b 7696
#define ofc4W 7704
#define ofc4b 7736
#define ooutW 7740
#define ooutb 7748

// ---- wq buffer ----
#define oW1I 0        // 76x64 interleaved W1 (rows 74,75 zero) = 4864 floats
#define oW2P 4864     // 32x16 BN-folded W2' = 512 floats
#define oB2P 5376     // 16 floats

__device__ __forceinline__ float bf2f(u16 u){
  union { u32 i; float f; } x; x.i = ((u32)u) << 16; return x.f;
}
__device__ __forceinline__ u32 fkey(float f){
  int i = __float_as_int(f);
  return (i >= 0) ? (((u32)i) | 0x80000000u) : ~((u32)i);
}
__device__ __forceinline__ float funkey(u32 k){
  u32 i = (k & 0x80000000u) ? (k & 0x7FFFFFFFu) : ~k;
  return __uint_as_float(i);
}
__device__ __forceinline__ float lrelu(float m){ return m > 0.f ? m : 0.2f*m; }
__device__ __forceinline__ float sexp(float a){ return __expf(fminf(a, 0.f)); }
__device__ __forceinline__ float ldf(const void* p, size_t i, int isf){
  return isf ? ((const float*)p)[i] : bf2f(((const u16*)p)[i]);
}

__global__ void k_zero(float* __restrict__ out){
  int i = blockIdx.x*256 + threadIdx.x;
  if(i < GG*2) out[i] = 0.f;
}

// ---------------- per-NODE bucketing ----------------
__global__ void k_count(const int* __restrict__ dst, int* __restrict__ cnt){
  int e = blockIdx.x*256 + threadIdx.x;
  if(e < EE){
    u32 d = (u32)dst[e];
    if(d < (u32)NN) atomicAdd(&cnt[d], 1);
  }
}

__global__ void k_scanA(const int* __restrict__ cnt, int* __restrict__ offs,
                        int* __restrict__ bsum){
  __shared__ int part[1024];
  int t = threadIdx.x;
  int i = blockIdx.x*1024 + t;
  int c = cnt[i];
  part[t] = c; __syncthreads();
  for(int off=1; off<1024; off<<=1){
    int v = (t>=off) ? part[t-off] : 0;
    __syncthreads();
    part[t] += v;
    __syncthreads();
  }
  offs[i] = part[t] - c;
  if(t==1023) bsum[blockIdx.x] = part[1023];
}

__global__ void k_scanB(int* __restrict__ bsum, int* __restrict__ offs){
  __shared__ int part[256];
  int t = threadIdx.x;
  int c = (t < 192) ? bsum[t] : 0;
  part[t] = c; __syncthreads();
  for(int off=1; off<256; off<<=1){
    int v = (t>=off) ? part[t-off] : 0;
    __syncthreads();
    part[t] += v;
    __syncthreads();
  }
  if(t < 192) bsum[t] = part[t] - c;
  if(t == 255) offs[NN] = part[255];
}

__global__ void k_scanC(int* __restrict__ offs, const int* __restrict__ bsum,
                        int* __restrict__ cursor){
  int t = threadIdx.x;
  int i = blockIdx.x*1024 + t;
  int v = offs[i] + bsum[blockIdx.x];
  offs[i] = v;
  cursor[i] = v;
}

// pack: sl(5b) | dl(5b)<<5 | edge_id(20b)<<10 ; sorted by dst node
__global__ void k_scatter(const int* __restrict__ src, const int* __restrict__ dst,
                          int* __restrict__ cursor, int* __restrict__ spack){
  int e = blockIdx.x*256 + threadIdx.x;
  if(e < EE){
    u32 d = (u32)dst[e];
    if(d >= (u32)NN) return;
    int g = d / PP;
    int pos = atomicAdd(&cursor[d], 1);
    if((u32)pos < (u32)EE){
      int sl = src[e] - g*PP;
      if((u32)sl > 23u) sl = 0;
      spack[pos] = sl | ((int)(d - g*PP) << 5) | (e << 10);
    }
  }
}

// ---------- mid tier: permute ea into sorted order, f32 16-wide ----------
__global__ void k_eaperm(const int* __restrict__ spack, const int* __restrict__ offs,
                         const void* __restrict__ ea, const int* __restrict__ dflag,
                         float* __restrict__ eap){
  int i = blockIdx.x*256 + threadIdx.x;
  if(i >= EE) return;
  if(i >= offs[NN]) return;
  int isf = dflag[0];
  u32 id = ((u32)spack[i]) >> 10;
  if(id >= (u32)EE) id = 0;
  float* o = eap + (size_t)i*16;
  if(isf){
    const float* er = (const float*)ea + (size_t)id*16;
    #pragma unroll
    for(int q=0;q<4;q++) *(f4_t*)(o + q*4) = *(const f4_t*)(er + q*4);
  } else {
    const u16* er = (const u16*)ea + (size_t)id*16;
    #pragma unroll
    for(int c=0;c<16;c++) o[c] = bf2f(er[c]);
  }
}

// ---------- p tier: permute ea in INPUT dtype (lossless) AND p2 = ea@We2 ----------
// bf16 inputs: eap row = 16 u16 (32 B, raw copy).  f32 inputs: 16 f32 (64 B).
__global__ void k_eapermB(const int* __restrict__ spack, const int* __restrict__ offs,
                          const void* __restrict__ ea, const int* __restrict__ dflag,
                          const float* __restrict__ wb,
                          void* __restrict__ eap, float* __restrict__ p2){
  int i = blockIdx.x*256 + threadIdx.x;
  if(i >= EE) return;
  if(i >= offs[NN]) return;
  int isf = dflag[0];
  u32 id = ((u32)spack[i]) >> 10;
  if(id >= (u32)EE) id = 0;
  float eav[16];
  if(isf){
    const float* er = (const float*)ea + (size_t)id*16;
    #pragma unroll
    for(int k=0;k<16;k++) eav[k] = er[k];
    float* o = (float*)eap + (size_t)i*16;
    #pragma unroll
    for(int q=0;q<4;q++) *(f4_t*)(o + q*4) = *(const f4_t*)(er + q*4);
  } else {
    const u16* er = (const u16*)ea + (size_t)id*16;
    #pragma unroll
    for(int k=0;k<16;k++) eav[k] = bf2f(er[k]);
    // raw 32-B copy, lossless
    const u4_t* s4 = (const u4_t*)er;
    u4_t* o4 = (u4_t*)((u16*)eap + (size_t)i*16);
    o4[0] = s4[0];
    o4[1] = s4[1];
  }
  float* o2 = p2 + (size_t)i*8;
  #pragma unroll
  for(int c=0;c<8;c+=4){
    float s0=0.f, s1=0.f, s2=0.f, s3=0.f;
    #pragma unroll
    for(int k=0;k<16;k++){
      f4_t w = *(const f4_t*)(wb + oWe2 + k*8 + c);
      s0 += eav[k]*w[0]; s1 += eav[k]*w[1]; s2 += eav[k]*w[2]; s3 += eav[k]*w[3];
    }
    f4_t r; r[0]=s0; r[1]=s1; r[2]=s2; r[3]=s3;
    *(f4_t*)(o2 + c) = r;
  }
}

// ---------- fused dtype-detect + weight conversion (one block) ----------
__global__ void k_wconv(float* __restrict__ wb, float* __restrict__ wq, int* __restrict__ dflag,
    const u32* __restrict__ xw,
    const void* Wl1, const void* bl1, const void* Wr1, const void* br1,
    const void* We1, const void* att1, const void* bo1,
    const void* Wl2, const void* bl2, const void* Wr2, const void* br2,
    const void* We2, const void* att2, const void* bo2,
    const void* f1W, const void* f1b, const void* f2W, const void* f2b,
    const void* f3W, const void* f3b, const void* f4W, const void* f4b,
    const void* oW,  const void* ob)
{
  __shared__ u32 mx[256];
  int t = threadIdx.x;
  u32 m = 0;
  for(int i=t; i<2048; i+=256){
    u32 e = (xw[i] >> 7) & 0xFFu;
    m = m > e ? m : e;
  }
  mx[t] = m; __syncthreads();
  for(int off=128; off>0; off>>=1){
    if(t<off) mx[t] = mx[t] > mx[t+off] ? mx[t] : mx[t+off];
    __syncthreads();
  }
  int isf = (mx[0] > 140u) ? 1 : 0;
  if(t==0) dflag[0] = isf;
  #define CP(off,src,len) for(int i=t;i<(len);i+=256) wb[(off)+i]=ldf(src,i,isf);
  CP(oWl1,Wl1,2368) CP(oWr1,Wr1,2368) CP(obl1,bl1,32) CP(obr1,br1,32)
  CP(oWe1,We1,512)  CP(oatt1,att1,32) CP(obo1,bo1,32)
  CP(oWl2,Wl2,256)  CP(oWr2,Wr2,256)  CP(obl2,bl2,8)  CP(obr2,br2,8)
  CP(oWe2,We2,128)  CP(oatt2,att2,8)  CP(obo2,bo2,8)
  CP(ofc1W,f1W,960) CP(ofc1b,f1b,32)  CP(ofc2W,f2W,512) CP(ofc2b,f2b,16)
  CP(ofc3W,f3W,128) CP(ofc3b,f3b,8)   CP(ofc4W,f4W,32)  CP(ofc4b,f4b,4)
  CP(ooutW,oW,8)    CP(ooutb,ob,2)
  #undef CP
  for(int i=t; i<76*64; i+=256){
    int k = i>>6, cc = i&63, mat = cc>>5, c = cc&31;
    wq[oW1I + i] = (k < 74) ? ldf(mat ? Wr1 : Wl1, k*32 + c, isf) : 0.f;
  }
}

// ---------- BN-fold for layer 2 ----------
__global__ void k_prep2(float* __restrict__ wq, const float* __restrict__ wb,
                        const float* __restrict__ stats1){
  int t = threadIdx.x;
  for(int i=t; i<512; i+=256){
    int k = i>>4, cc = i&15, mat = cc>>3, c = cc&7;
    wq[oW2P + i] = stats1[k] * wb[(mat ? oWr2 : oWl2) + k*8 + c];
  }
  if(t < 16){
    int mat = t>>3, c = t&7;
    float s = wb[(mat ? obr2 : obl2) + c];
    for(int k=0;k<32;k++) s += stats1[32+k] * wb[(mat ? oWr2 : oWl2) + k*8 + c];
    wq[oB2P + t] = s;
  }
}

// ======== p-tier pass 1: rows parallel, p1 computed into LDS (not HBM) ========
// LDS ~40 KB -> 4 blocks/CU. sP padded to 36 floats/row (144-B stride rotates
// banks). Config measured 198 us (round 6/9); round-7/8 variants were slower.
// Only change vs round 9: phase A2 reads eap in INPUT dtype (u16 when bf16) —
// same coalesced row-shared pattern, half the bytes.
__global__ __launch_bounds__(256, 4) void k_l1stats_p(
    const void* __restrict__ x, const void* __restrict__ eap,
    const float* __restrict__ wb, const float* __restrict__ wq,
    const int* __restrict__ offs, const int* __restrict__ spack, const int* __restrict__ dflag,
    float* __restrict__ p1sum, float* __restrict__ p1sq,
    float* __restrict__ h1)
{
  __shared__ __align__(16) float sP[CAP][36];    // ea@We1 per edge (cols 0..31)
  __shared__ __align__(16) float sXl[24][36];
  __shared__ __align__(16) float sXr[24][36];
  __shared__ __align__(16) float sPS[24][32];
  __shared__ __align__(16) float sPQ[24][32];
  __shared__ float sEv[CAP];
  __shared__ int   sSl[CAP];
  __shared__ int   sRO[25];

  const int t = threadIdx.x;
  const int g = blockIdx.x;
  const int isf = dflag[0];
  const int nb = g*PP;
  const int eb = offs[nb];
  int ecnt = offs[nb+24] - eb;
  if(ecnt < 0) ecnt = 0; if(ecnt > CAP) ecnt = CAP;

  if(t < 25){
    int v = offs[nb+t] - eb;
    if(v < 0) v = 0; if(v > CAP) v = CAP;
    sRO[t] = v;
  }
  for(int i=t; i<ecnt; i+=256){
    int sl = spack[eb+i] & 31; if(sl > 23) sl = 0;
    sSl[i] = sl;
  }

  // ---- phase A1: projection xl/xr (wave w -> rows 6w..6w+5) ----
  {
    const int c = t & 31, mat = (t>>5)&1, w = t>>6, cc = t&63;
    const float* gW = wq + oW1I;
    float bi = wb[(mat ? obr1 : obl1) + c];
    float acc[6];
    #pragma unroll
    for(int j=0;j<6;j++) acc[j] = bi;
    if(isf){
      const float* xr0 = (const float*)x + (size_t)(nb + w*6)*96;
      for(int kb=0; kb<19; kb++){
        float w0 = gW[(kb*4+0)*64 + cc];
        float w1 = gW[(kb*4+1)*64 + cc];
        float w2 = gW[(kb*4+2)*64 + cc];
        float w3 = gW[(kb*4+3)*64 + cc];
        #pragma unroll
        for(int j=0;j<6;j++){
          f4_t xv = *(const f4_t*)(xr0 + (size_t)j*96 + kb*4);
          acc[j] += xv[0]*w0 + xv[1]*w1 + xv[2]*w2 + xv[3]*w3;
        }
      }
    } else {
      const u16* xr0 = (const u16*)x + (size_t)(nb + w*6)*96;
      for(int kb=0; kb<19; kb++){
        float w0 = gW[(kb*4+0)*64 + cc];
        float w1 = gW[(kb*4+1)*64 + cc];
        float w2 = gW[(kb*4+2)*64 + cc];
        float w3 = gW[(kb*4+3)*64 + cc];
        #pragma unroll
        for(int j=0;j<6;j++){
          us4_t xv = *(const us4_t*)(xr0 + (size_t)j*96 + kb*4);
          acc[j] += bf2f(xv[0])*w0 + bf2f(xv[1])*w1 + bf2f(xv[2])*w2 + bf2f(xv[3])*w3;
        }
      }
    }
    if(mat){
      #pragma unroll
      for(int j=0;j<6;j++) sXr[w*6+j][c] = acc[j];
    } else {
      #pragma unroll
      for(int j=0;j<6;j++) sXl[w*6+j][c] = acc[j];
    }
  }

  // ---- phase A2: p1 into LDS. task (e, q): cols q*4..q*4+3 of edge e ----
  for(int i=t; i<ecnt*8; i+=256){
    int e = i>>3, q = i&7;
    float ev[16];
    if(isf){
      const float* er = (const float*)eap + (size_t)(eb+e)*16;  // 64-B row, 8 tasks share
      #pragma unroll
      for(int qq=0;qq<4;qq++){
        f4_t v = *(const f4_t*)(er + qq*4);
        ev[qq*4+0]=v[0]; ev[qq*4+1]=v[1]; ev[qq*4+2]=v[2]; ev[qq*4+3]=v[3];
      }
    } else {
      const u16* er = (const u16*)eap + (size_t)(eb+e)*16;      // 32-B row, 8 tasks share
      #pragma unroll
      for(int qq=0;qq<4;qq++){
        us4_t v = *(const us4_t*)(er + qq*4);
        ev[qq*4+0]=bf2f(v[0]); ev[qq*4+1]=bf2f(v[1]); ev[qq*4+2]=bf2f(v[2]); ev[qq*4+3]=bf2f(v[3]);
      }
    }
    float s0=0.f, s1=0.f, s2=0.f, s3=0.f;
    #pragma unroll
    for(int k=0;k<16;k++){
      f4_t w = *(const f4_t*)(wb + oWe1 + k*32 + q*4);
      s0 += ev[k]*w[0]; s1 += ev[k]*w[1]; s2 += ev[k]*w[2]; s3 += ev[k]*w[3];
    }
    f4_t r; r[0]=s0; r[1]=s1; r[2]=s2; r[3]=s3;
    *(f4_t*)&sP[e][q*4] = r;                     // e*144 + q*16 bytes: 16-B aligned
  }
  __syncthreads();   // barrier 1

  if(t < 192){       // 8 lanes per row, 24 rows in parallel
    const int r = t >> 3, sub = t & 7;
    const int a = sRO[r], b = sRO[r+1];
    const int deg = b - a;
    const float* att = wb + oatt1;

    // e-values: lane owns edges a+sub, a+sub+8, ... ; p1 from LDS
    float emax = -3.4e38f;
    for(int e=a+sub; e<b; e+=8){
      int sl = sSl[e];
      float ev = 0.f;
      #pragma unroll
      for(int q=0;q<8;q++){
        f4_t pv  = *(const f4_t*)&sP[e][q*4];
        f4_t xlv = *(const f4_t*)&sXl[sl][q*4];
        f4_t xrv = *(const f4_t*)&sXr[r][q*4];
        ev += att[q*4+0]*lrelu(xlv[0]+xrv[0]+pv[0]);
        ev += att[q*4+1]*lrelu(xlv[1]+xrv[1]+pv[1]);
        ev += att[q*4+2]*lrelu(xlv[2]+xrv[2]+pv[2]);
        ev += att[q*4+3]*lrelu(xlv[3]+xrv[3]+pv[3]);
      }
      sEv[e] = ev;
      emax = fmaxf(emax, ev);
    }
    emax = fmaxf(emax, __shfl_xor(emax, 1));
    emax = fmaxf(emax, __shfl_xor(emax, 2));
    emax = fmaxf(emax, __shfl_xor(emax, 4));

    // self-loop via linearity: mean of p1 over edges; lane owns cols sub*4..+3
    float m0=0.f, m1=0.f, m2=0.f, m3=0.f;
    for(int e=a; e<b; ++e){
      f4_t pv = *(const f4_t*)&sP[e][sub*4];     // banks (e*4+sub*4)%32: conflict-free
      m0 += pv[0]; m1 += pv[1]; m2 += pv[2]; m3 += pv[3];
    }
    float invd = 1.f / (float)(deg > 0 ? deg : 1);
    float sv;
    {
      int c0 = sub*4;
      sv  = att[c0+0]*lrelu(sXl[r][c0+0] + sXr[r][c0+0] + m0*invd);
      sv += att[c0+1]*lrelu(sXl[r][c0+1] + sXr[r][c0+1] + m1*invd);
      sv += att[c0+2]*lrelu(sXl[r][c0+2] + sXr[r][c0+2] + m2*invd);
      sv += att[c0+3]*lrelu(sXl[r][c0+3] + sXr[r][c0+3] + m3*invd);
    }
    sv += __shfl_xor(sv, 1);
    sv += __shfl_xor(sv, 2);
    sv += __shfl_xor(sv, 4);

    // softmax (z in place in sEv)
    float m = fmaxf(emax, sv);
    float ssum = 0.f;
    for(int e=a+sub; e<b; e+=8){
      float z = sexp(sEv[e] - m);
      sEv[e] = z;
      ssum += z;
    }
    ssum += __shfl_xor(ssum, 1);
    ssum += __shfl_xor(ssum, 2);
    ssum += __shfl_xor(ssum, 4);
    float selfZ = sexp(sv - m);
    float rden = 1.f / fmaxf(ssum + selfZ, 1e-30f);

    // aggregation: lane owns cols sub*4..+3
    float a0=0.f, a1=0.f, a2=0.f, a3=0.f;
    for(int e=a; e<b; ++e){
      float z = sEv[e];
      f4_t xlv = *(const f4_t*)&sXl[sSl[e]][sub*4];
      a0 += z*xlv[0]; a1 += z*xlv[1]; a2 += z*xlv[2]; a3 += z*xlv[3];
    }
    f4_t xself = *(const f4_t*)&sXl[r][sub*4];
    f4_t outv, sqv;
    {
      float o;
      o = (a0 + selfZ*xself[0]) * rden; o = fmaxf(o + wb[obo1+sub*4+0], 0.f); outv[0]=o; sqv[0]=o*o;
      o = (a1 + selfZ*xself[1]) * rden; o = fmaxf(o + wb[obo1+sub*4+1], 0.f); outv[1]=o; sqv[1]=o*o;
      o = (a2 + selfZ*xself[2]) * rden; o = fmaxf(o + wb[obo1+sub*4+2], 0.f); outv[2]=o; sqv[2]=o*o;
      o = (a3 + selfZ*xself[3]) * rden; o = fmaxf(o + wb[obo1+sub*4+3], 0.f); outv[3]=o; sqv[3]=o*o;
    }
    *(f4_t*)&h1[((size_t)nb + r)*32 + sub*4] = outv;
    *(f4_t*)&sPS[r][sub*4] = outv;
    *(f4_t*)&sPQ[r][sub*4] = sqv;
  }
  __syncthreads();   // barrier 2
  if(t < 32){
    float s=0.f, q=0.f;
    #pragma unroll
    for(int r=0;r<24;r++){ s += sPS[r][t]; q += sPQ[r][t]; }
    p1sum[g*32+t] = s; p1sq[g*32+t] = q;
  }
}

// ======== p-tier pass 2: layer2 from h1, rows parallel; p2 staged in LDS ========
__global__ __launch_bounds__(256, 6) void k_fused2_p(
    const float* __restrict__ p2,
    const float* __restrict__ wb, const float* __restrict__ wq,
    const float* __restrict__ h1,
    const int* __restrict__ offs, const int* __restrict__ spack,
    float* __restrict__ gsum2, float* __restrict__ gsq2)
{
  __shared__ __align__(16) float sP2[CAP][12];   // p2 tile; pad-12 rotates banks
  __shared__ float sXl2[24][13];
  __shared__ float sXr2[24][13];
  __shared__ float sEv[CAP];
  __shared__ int   sSl[CAP];
  __shared__ int   sRO[25];
  __shared__ float sGS[24][8];
  __shared__ float sGQ[24][8];

  const int t = threadIdx.x;
  const int g = blockIdx.x;
  const int wid = t >> 6;
  const int lane = t & 63;
  const int nb = g*PP;
  const int eb = offs[nb];
  int ecnt = offs[nb+24] - eb;
  if(ecnt < 0) ecnt = 0; if(ecnt > CAP) ecnt = CAP;

  if(t < 25){
    int v = offs[nb+t] - eb;
    if(v < 0) v = 0; if(v > CAP) v = CAP;
    sRO[t] = v;
  }
  for(int i=t; i<ecnt; i+=256){
    int sl = spack[eb+i] & 31; if(sl > 23) sl = 0;
    sSl[i] = sl;
  }
  // stage p2 tile: coalesced f4 loads, one pass
  for(int i=t; i<ecnt*2; i+=256){
    int e = i>>1, half = i&1;
    f4_t v = *(const f4_t*)(p2 + (size_t)(eb+e)*8 + half*4);
    *(f4_t*)&sP2[e][half*4] = v;     // e*48 + half*16 bytes: 16-B aligned
  }
  // projection xl2/xr2 (BN folded): wave wid computes rows 6*wid..6*wid+5
  {
    int rz = wid*6;
    for(int i=lane; i<96; i+=64){
      int rl = i>>4, cc = i&15;
      int r = rz + rl;
      float s = wq[oB2P + cc];
      const float* hr = h1 + ((size_t)nb + r)*32;
      #pragma unroll
      for(int q=0;q<8;q++){
        f4_t hv = *(const f4_t*)(hr + q*4);
        s += hv[0]*wq[oW2P+(q*4+0)*16+cc] + hv[1]*wq[oW2P+(q*4+1)*16+cc]
           + hv[2]*wq[oW2P+(q*4+2)*16+cc] + hv[3]*wq[oW2P+(q*4+3)*16+cc];
      }
      if(cc < 8) sXl2[r][cc] = s; else sXr2[r][cc-8] = s;
    }
  }
  __syncthreads();   // barrier 1

  if(t < 192){
    const int r = t >> 3, sub = t & 7;
    const int a = sRO[r], b = sRO[r+1];
    const int deg = b - a;
    const float* att2 = wb + oatt2;

    float emax = -3.4e38f;
    for(int e=a+sub; e<b; e+=8){
      int sl = sSl[e];
      f4_t q0 = *(const f4_t*)&sP2[e][0];
      f4_t q1 = *(const f4_t*)&sP2[e][4];
      float ev = 0.f;
      #pragma unroll
      for(int j=0;j<4;j++) ev += att2[j]  *lrelu(sXl2[sl][j]   + sXr2[r][j]   + q0[j]);
      #pragma unroll
      for(int j=0;j<4;j++) ev += att2[4+j]*lrelu(sXl2[sl][4+j] + sXr2[r][4+j] + q1[j]);
      sEv[e] = ev;
      emax = fmaxf(emax, ev);
    }
    emax = fmaxf(emax, __shfl_xor(emax, 1));
    emax = fmaxf(emax, __shfl_xor(emax, 2));
    emax = fmaxf(emax, __shfl_xor(emax, 4));

    // self-loop via mean p2 (LDS); lane owns col sub
    float mpc = 0.f;
    for(int e=a; e<b; ++e)
      mpc += sP2[e][sub];
    float invd = 1.f / (float)(deg > 0 ? deg : 1);
    float sv = att2[sub]*lrelu(sXl2[r][sub] + sXr2[r][sub] + mpc*invd);
    sv += __shfl_xor(sv, 1);
    sv += __shfl_xor(sv, 2);
    sv += __shfl_xor(sv, 4);

    float m = fmaxf(emax, sv);
    float ssum = 0.f;
    for(int e=a+sub; e<b; e+=8){
      float z = sexp(sEv[e] - m);
      sEv[e] = z;
      ssum += z;
    }
    ssum += __shfl_xor(ssum, 1);
    ssum += __shfl_xor(ssum, 2);
    ssum += __shfl_xor(ssum, 4);
    float selfZ = sexp(sv - m);
    float rden = 1.f / fmaxf(ssum + selfZ, 1e-30f);

    float acc = 0.f;
    for(int e=a; e<b; ++e)
      acc += sEv[e] * sXl2[sSl[e]][sub];
    float o = (acc + selfZ*sXl2[r][sub]) * rden;
    float s = 1.f / (1.f + __expf(-(o + wb[obo2+sub])));
    sGS[r][sub] = s;
    sGQ[r][sub] = s*s;
  }
  __syncthreads();   // barrier 2
  if(t < 8){
    float gs=0.f, gq=0.f;
    #pragma unroll
    for(int r=0;r<24;r++){ gs += sGS[r][t]; gq += sGQ[r][t]; }
    gsum2[g*8+t] = gs; gsq2[g*8+t] = gq;
  }
}

// ======== mid tier (round-3) kernels, verbatim fallback ========
__global__ __launch_bounds__(256, 6) void k_l1stats(
    const void* __restrict__ x, const void* __restrict__ ea, const float* __restrict__ eap,
    const float* __restrict__ wb, const float* __restrict__ wq,
    const int* __restrict__ offs, const int* __restrict__ spack, const int* __restrict__ dflag,
    float* __restrict__ p1sum, float* __restrict__ p1sq,
    float* __restrict__ h1, int use_h1)
{
  __shared__ __align__(16) float sEaF[CAP][16];
  __shared__ __align__(16) float sXl[24][36];
  __shared__ float sXr[24][33];
  __shared__ float sEaSum[24][17];
  __shared__ float sEv[CAP];
  __shared__ int   sSl[CAP];
  __shared__ int   sRO[25];
  __shared__ float sSelfE[24];
  __shared__ float sPS[4][32], sPQ[4][32];

  const int t = threadIdx.x;
  const int g = blockIdx.x;
  const int wid = t >> 6;
  const int lane = t & 63;
  const int isf = dflag[0];
  const int nb = g*PP;
  const int eb = offs[nb];
  int ecnt = offs[nb+24] - eb; if(ecnt < 0) ecnt = 0; if(ecnt > CAP) ecnt = CAP;

  if(t < 25){
    int v = offs[nb+t] - eb;
    if(v < 0) v = 0; if(v > CAP) v = CAP;
    sRO[t] = v;
  }
  if(eap){
    for(int i=t; i<ecnt; i+=256) sSl[i] = spack[eb+i] & 1023;
    for(int i=t; i<ecnt*4; i+=256){
      int e = i>>2, q = i&3;
      *(f4_t*)&sEaF[e][q*4] = *(const f4_t*)(eap + ((size_t)(eb+e))*16 + q*4);
    }
  } else {
    for(int i=t; i<ecnt; i+=256){
      int sp = spack[eb+i];
      sSl[i] = sp & 1023;
      u32 id = ((u32)sp) >> 10;
      if(id >= (u32)EE) id = 0;
      if(isf){
        const float* er = (const float*)ea + (size_t)id*16;
        #pragma unroll
        for(int q=0;q<4;q++) *(f4_t*)&sEaF[i][q*4] = *(const f4_t*)(er + q*4);
      } else {
        #pragma unroll
        for(int c=0;c<16;c++) sEaF[i][c] = bf2f(((const u16*)ea)[(size_t)id*16 + c]);
      }
    }
  }
  {
    int rz = wid*6;
    for(int i=lane; i<6*17; i+=64) sEaSum[rz + i/17][i%17] = 0.f;
  }

  {
    const int c = t & 31, mat = (t>>5)&1, w = wid, cc = t&63;
    const float* gW = wq + oW1I;
    float bi = wb[(mat ? obr1 : obl1) + c];
    float acc[6];
    #pragma unroll
    for(int j=0;j<6;j++) acc[j] = bi;
    if(isf){
      const float* xr0 = (const float*)x + (size_t)(nb + w*6)*96;
      for(int kb=0; kb<19; kb++){
        float w0 = gW[(kb*4+0)*64 + cc];
        float w1 = gW[(kb*4+1)*64 + cc];
        float w2 = gW[(kb*4+2)*64 + cc];
        float w3 = gW[(kb*4+3)*64 + cc];
        #pragma unroll
        for(int j=0;j<6;j++){
          f4_t xv = *(const f4_t*)(xr0 + (size_t)j*96 + kb*4);
          acc[j] += xv[0]*w0 + xv[1]*w1 + xv[2]*w2 + xv[3]*w3;
        }
      }
    } else {
      const u16* xr0 = (const u16*)x + (size_t)(nb + w*6)*96;
      for(int kb=0; kb<19; kb++){
        float w0 = gW[(kb*4+0)*64 + cc];
        float w1 = gW[(kb*4+1)*64 + cc];
        float w2 = gW[(kb*4+2)*64 + cc];
        float w3 = gW[(kb*4+3)*64 + cc];
        #pragma unroll
        for(int j=0;j<6;j++){
          us4_t xv = *(const us4_t*)(xr0 + (size_t)j*96 + kb*4);
          acc[j] += bf2f(xv[0])*w0 + bf2f(xv[1])*w1 + bf2f(xv[2])*w2 + bf2f(xv[3])*w3;
        }
      }
    }
    if(mat){
      #pragma unroll
      for(int j=0;j<6;j++) sXr[w*6+j][c] = acc[j];
    } else {
      #pragma unroll
      for(int j=0;j<6;j++) sXl[w*6+j][c] = acc[j];
    }
  }
  __syncthreads();

  const int r0 = wid*6;
  const int a0 = sRO[r0], a1 = sRO[r0+6];
  const int c = t & 31, eo = (t>>5)&1;

  float wr[16];
  #pragma unroll
  for(int k=0;k<16;k++) wr[k] = wb[oWe1 + k*32 + c];
  const float av = wb[oatt1 + c];
  const float bv = wb[obo1 + c];

  for(int base=a0; base<a1; base+=2){
    int e = base + eo;
    bool valid = (e < a1);
    int ec = valid ? e : a0;
    int sp = sSl[ec];
    int sl = sp & 31; if(sl > 23) sl = 0;
    int dl = (sp >> 5) & 31; if(dl > 23) dl = 0;
    f4_t A0 = *(const f4_t*)&sEaF[ec][0];
    f4_t A1 = *(const f4_t*)&sEaF[ec][4];
    f4_t A2 = *(const f4_t*)&sEaF[ec][8];
    f4_t A3 = *(const f4_t*)&sEaF[ec][12];
    float p = A0[0]*wr[0]+A0[1]*wr[1]+A0[2]*wr[2]+A0[3]*wr[3]
            + A1[0]*wr[4]+A1[1]*wr[5]+A1[2]*wr[6]+A1[3]*wr[7]
            + A2[0]*wr[8]+A2[1]*wr[9]+A2[2]*wr[10]+A2[3]*wr[11]
            + A3[0]*wr[12]+A3[1]*wr[13]+A3[2]*wr[14]+A3[3]*wr[15];
    if(valid && c < 16) atomicAdd(&sEaSum[dl][c], sEaF[ec][c]);
    float v = lrelu(sXl[sl][c] + sXr[dl][c] + p) * av;
    v += __shfl_xor(v, 16);
    v += __shfl_xor(v, 8);
    v += __shfl_xor(v, 4);
    v += __shfl_xor(v, 2);
    v += __shfl_xor(v, 1);
    if(valid && c == 0) sEv[e] = v;
  }

  #pragma unroll
  for(int rp=0; rp<3; rp++){
    int r = r0 + rp*2 + eo;
    int deg = sRO[r+1] - sRO[r];
    float invd = 1.f / (float)(deg > 0 ? deg : 1);
    float mp = 0.f;
    #pragma unroll
    for(int k=0;k<16;k++) mp += sEaSum[r][k] * wr[k];
    float v = lrelu(sXl[r][c] + sXr[r][c] + mp*invd) * av;
    v += __shfl_xor(v, 16);
    v += __shfl_xor(v, 8);
    v += __shfl_xor(v, 4);
    v += __shfl_xor(v, 2);
    v += __shfl_xor(v, 1);
    if(c == 0) sSelfE[r] = v;
  }

  float ps = 0.f, pq = 0.f;
  const int h = (t >> 5) & 1;
  #pragma unroll
  for(int j=0;j<6;j++){
    int r = r0 + j;
    int a = sRO[r], b = sRO[r+1];
    float selfE = sSelfE[r];
    float mx = -3.4e38f;
    for(int e=a+lane; e<b; e+=64) mx = fmaxf(mx, sEv[e]);
    mx = fmaxf(mx, __shfl_xor(mx, 32));
    mx = fmaxf(mx, __shfl_xor(mx, 16));
    mx = fmaxf(mx, __shfl_xor(mx, 8));
    mx = fmaxf(mx, __shfl_xor(mx, 4));
    mx = fmaxf(mx, __shfl_xor(mx, 2));
    mx = fmaxf(mx, __shfl_xor(mx, 1));
    float m = fmaxf(mx, selfE);
    float ds = 0.f;
    for(int e=a+lane; e<b; e+=64){
      float z = sexp(sEv[e] - m);
      sEv[e] = z;
      ds += z;
    }
    ds += __shfl_xor(ds, 32);
    ds += __shfl_xor(ds, 16);
    ds += __shfl_xor(ds, 8);
    ds += __shfl_xor(ds, 4);
    ds += __shfl_xor(ds, 2);
    ds += __shfl_xor(ds, 1);
    float selfZ = sexp(selfE - m);
    float rden = 1.f / fmaxf(ds + selfZ, 1e-30f);
    float acc = 0.f;
    for(int e=a+h; e<b; e+=2){
      int sl = sSl[e] & 31; if(sl > 23) sl = 0;
      acc += sEv[e] * sXl[sl][c];
    }
    acc += __shfl_xor(acc, 32);
    float out = (acc + selfZ * sXl[r][c]) * rden;
    out = fmaxf(out + bv, 0.f);
    if(h == 0){
      if(use_h1) h1[((size_t)nb + r)*32 + c] = out;
      ps += out; pq += out*out;
    }
  }
  if(h == 0){ sPS[wid][c] = ps; sPQ[wid][c] = pq; }
  __syncthreads();
  if(t < 32){
    p1sum[g*32+t] = sPS[0][t]+sPS[1][t]+sPS[2][t]+sPS[3][t];
    p1sq[g*32+t]  = sPQ[0][t]+sPQ[1][t]+sPQ[2][t]+sPQ[3][t];
  }
}

// ---------------- BN stats -> affine ----------------
__global__ void k_reduce(const float* __restrict__ ps, const float* __restrict__ pq,
                         const void* __restrict__ gamma, const void* __restrict__ beta,
                         const int* __restrict__ dflag,
                         float* __restrict__ stats, int F){
  __shared__ float rs[256], rq[256];
  int f = blockIdx.x, t = threadIdx.x;
  float s=0.f, q=0.f;
  for(int g=t; g<GG; g+=256){ s += ps[g*F+f]; q += pq[g*F+f]; }
  rs[t]=s; rq[t]=q; __syncthreads();
  for(int off=128; off>0; off>>=1){
    if(t<off){ rs[t]+=rs[t+off]; rq[t]+=rq[t+off]; }
    __syncthreads();
  }
  if(t==0){
    int isf = dflag[0];
    float mu  = rs[0] * (1.f/(float)NN);
    float var = rq[0] * (1.f/(float)NN) - mu*mu;
    if(var < 0.f) var = 0.f;
    float sc  = ldf(gamma,f,isf) / sqrtf(var + 1e-5f);
    stats[f]   = sc;
    stats[F+f] = ldf(beta,f,isf) - mu*sc;
  }
}

// -------- mid-tier layer2 from stored h1, wave-local (round-3, verbatim) --------
__global__ __launch_bounds__(256, 6) void k_fused2_h1(
    const void* __restrict__ ea, const float* __restrict__ eap,
    const float* __restrict__ wb, const float* __restrict__ wq,
    const float* __restrict__ h1,
    const int* __restrict__ offs, const int* __restrict__ spack, const int* __restrict__ dflag,
    float* __restrict__ gsum2, float* __restrict__ gsq2)
{
  __shared__ __align__(16) float sEaF[CAP][16];
  __shared__ float sXl2[24][12], sXr2[24][12];
  __shared__ float sEaSum[24][17];
  __shared__ float sEv[CAP];
  __shared__ int   sSl[CAP];
  __shared__ int   sRO[25];
  __shared__ float sSelfE[24];
  __shared__ float sGS[4][8], sGQ[4][8];

  const int t = threadIdx.x;
  const int g = blockIdx.x;
  const int wid = t >> 6;
  const int lane = t & 63;
  const int isf = dflag[0];
  const int nb = g*PP;
  const int eb = offs[nb];
  int ecnt = offs[nb+24] - eb; if(ecnt < 0) ecnt = 0; if(ecnt > CAP) ecnt = CAP;

  if(t < 25){
    int v = offs[nb+t] - eb;
    if(v < 0) v = 0; if(v > CAP) v = CAP;
    sRO[t] = v;
  }
  if(eap){
    for(int i=t; i<ecnt; i+=256) sSl[i] = spack[eb+i] & 1023;
    for(int i=t; i<ecnt*4; i+=256){
      int e = i>>2, q = i&3;
      *(f4_t*)&sEaF[e][q*4] = *(const f4_t*)(eap + ((size_t)(eb+e))*16 + q*4);
    }
  } else {
    for(int i=t; i<ecnt; i+=256){
      int sp = spack[eb+i];
      sSl[i] = sp & 1023;
      u32 id = ((u32)sp) >> 10;
      if(id >= (u32)EE) id = 0;
      if(isf){
        const float* er = (const float*)ea + (size_t)id*16;
        #pragma unroll
        for(int q=0;q<4;q++) *(f4_t*)&sEaF[i][q*4] = *(const f4_t*)(er + q*4);
      } else {
        #pragma unroll
        for(int c=0;c<16;c++) sEaF[i][c] = bf2f(((const u16*)ea)[(size_t)id*16 + c]);
      }
    }
  }
  {
    int rz = wid*6;
    for(int i=lane; i<6*17; i+=64) sEaSum[rz + i/17][i%17] = 0.f;
    for(int i=lane; i<96; i+=64){
      int rl = i>>4, cc = i&15;
      int r = rz + rl;
      float s = wq[oB2P + cc];
      const float* hr = h1 + ((size_t)nb + r)*32;
      #pragma unroll
      for(int q=0;q<8;q++){
        f4_t hv = *(const f4_t*)(hr + q*4);
        s += hv[0]*wq[oW2P+(q*4+0)*16+cc] + hv[1]*wq[oW2P+(q*4+1)*16+cc]
           + hv[2]*wq[oW2P+(q*4+2)*16+cc] + hv[3]*wq[oW2P+(q*4+3)*16+cc];
      }
      if(cc < 8) sXl2[r][cc] = s; else sXr2[r][cc-8] = s;
    }
  }
  __syncthreads();

  const int r0 = wid*6;
  const int a0 = sRO[r0], a1 = sRO[r0+6];
  const int c = t & 7;
  const int eo = lane >> 3;

  float wr[16];
  #pragma unroll
  for(int k=0;k<16;k++) wr[k] = wb[oWe2 + k*8 + c];
  const float av = wb[oatt2 + c];
  const float bv = wb[obo2 + c];

  for(int base=a0; base<a1; base+=8){
    int e = base + eo;
    bool valid = (e < a1);
    int ec = valid ? e : a0;
    int sp = sSl[ec];
    int sl = sp & 31; if(sl > 23) sl = 0;
    int dl = (sp >> 5) & 31; if(dl > 23) dl = 0;
    f4_t A0 = *(const f4_t*)&sEaF[ec][0];
    f4_t A1 = *(const f4_t*)&sEaF[ec][4];
    f4_t A2 = *(const f4_t*)&sEaF[ec][8];
    f4_t A3 = *(const f4_t*)&sEaF[ec][12];
    float p = A0[0]*wr[0]+A0[1]*wr[1]+A0[2]*wr[2]+A0[3]*wr[3]
            + A1[0]*wr[4]+A1[1]*wr[5]+A1[2]*wr[6]+A1[3]*wr[7]
            + A2[0]*wr[8]+A2[1]*wr[9]+A2[2]*wr[10]+A2[3]*wr[11]
            + A3[0]*wr[12]+A3[1]*wr[13]+A3[2]*wr[14]+A3[3]*wr[15];
    if(valid){
      atomicAdd(&sEaSum[dl][c],   sEaF[ec][c]);
      atomicAdd(&sEaSum[dl][c+8], sEaF[ec][c+8]);
    }
    float v = lrelu(sXl2[sl][c] + sXr2[dl][c] + p) * av;
    v += __shfl_xor(v, 4);
    v += __shfl_xor(v, 2);
    v += __shfl_xor(v, 1);
    if(valid && c == 0) sEv[e] = v;
  }

  {
    int rr = r0 + (eo < 6 ? eo : 0);
    bool valid = (eo < 6);
    int deg = sRO[rr+1] - sRO[rr];
    float invd = 1.f / (float)(deg > 0 ? deg : 1);
    float mp = 0.f;
    #pragma unroll
    for(int k=0;k<16;k++) mp += sEaSum[rr][k] * wr[k];
    float v = lrelu(sXl2[rr][c] + sXr2[rr][c] + mp*invd) * av;
    v += __shfl_xor(v, 4);
    v += __shfl_xor(v, 2);
    v += __shfl_xor(v, 1);
    if(valid && c == 0) sSelfE[rr] = v;
  }

  float gs = 0.f, gq = 0.f;
  #pragma unroll
  for(int j=0;j<6;j++){
    int r = r0 + j;
    int a = sRO[r], b = sRO[r+1];
    float selfE = sSelfE[r];
    float mx = -3.4e38f;
    for(int e=a+lane; e<b; e+=64) mx = fmaxf(mx, sEv[e]);
    mx = fmaxf(mx, __shfl_xor(mx, 32));
    mx = fmaxf(mx, __shfl_xor(mx, 16));
    mx = fmaxf(mx, __shfl_xor(mx, 8));
    mx = fmaxf(mx, __shfl_xor(mx, 4));
    mx = fmaxf(mx, __shfl_xor(mx, 2));
    mx = fmaxf(mx, __shfl_xor(mx, 1));
    float m = fmaxf(mx, selfE);
    float ds = 0.f;
    for(int e=a+lane; e<b; e+=64){
      float z = sexp(sEv[e] - m);
      sEv[e] = z;
      ds += z;
    }
    ds += __shfl_xor(ds, 32);
    ds += __shfl_xor(ds, 16);
    ds += __shfl_xor(ds, 8);
    ds += __shfl_xor(ds, 4);
    ds += __shfl_xor(ds, 2);
    ds += __shfl_xor(ds, 1);
    float selfZ = sexp(selfE - m);
    float rden = 1.f / fmaxf(ds + selfZ, 1e-30f);
    float acc = 0.f;
    for(int e=a+eo; e<b; e+=8){
      int sl = sSl[e] & 31; if(sl > 23) sl = 0;
      acc += sEv[e] * sXl2[sl][c];
    }
    acc += __shfl_xor(acc, 8);
    acc += __shfl_xor(acc, 16);
    acc += __shfl_xor(acc, 32);
    float out = (acc + selfZ * sXl2[r][c]) * rden;
    float s = 1.f / (1.f + __expf(-(out + bv)));
    if(eo == 0){ gs += s; gq += s*s; }
  }
  if(eo == 0){ sGS[wid][c] = gs; sGQ[wid][c] = gq; }
  __syncthreads();
  if(t < 8){
    gsum2[g*8+t] = sGS[0][t]+sGS[1][t]+sGS[2][t]+sGS[3][t];
    gsq2[g*8+t]  = sGQ[0][t]+sGQ[1][t]+sGQ[2][t]+sGQ[3][t];
  }
}

// -------- fallback: recompute layer1 + layer2 (ws-lean, round-3 verbatim) --------
__global__ __launch_bounds__(256) void k_fused2_rec(
    const void* __restrict__ x, const void* __restrict__ ea,
    const float* __restrict__ wb, const float* __restrict__ stats1,
    const int* __restrict__ offs, const int* __restrict__ spack, const int* __restrict__ dflag,
    float* __restrict__ gsum2, float* __restrict__ gsq2)
{
  __shared__ float sXrow[24][76];
  __shared__ float sEaF[CAP][17];
  __shared__ __align__(16) float sXl[24][36];
  __shared__ __align__(16) float sXr[24][36];
  __shared__ __align__(16) float sOut[24][36];
  __shared__ float sH[24][33];
  __shared__ float sXl2[24][12], sXr2[24][12], sOut2[24][12];
  __shared__ float sEapSum[24][32];
  __shared__ float sEv[CAP], sEz[CAP];
  __shared__ int   sSp[CAP];
  __shared__ int   sDeg[24];
  __shared__ u32   sMaxU[24];
  __shared__ float sMaxF[24], sDen[24], sSelfZ[24];
  __shared__ float sAtt[32], sBo[32], sSc[32], sSh[32];

  const int t = threadIdx.x;
  const int g = blockIdx.x;
  const int isf = dflag[0];
  int eb = offs[g*24], ee = offs[(g+1)*24];
  if(eb < 0) eb = 0; if(eb > EE) eb = EE;
  if(ee < eb) ee = eb; if(ee > EE) ee = EE;
  int ecnt = ee - eb; if(ecnt > CAP) ecnt = CAP;

  for(int i=t; i<24*74; i+=256){
    int r = i/74, c = i%74;
    sXrow[r][c] = ldf(x, (size_t)(g*PP + r)*96 + c, isf);
  }
  for(int i=t; i<CAP; i+=256) sSp[i] = (i<ecnt) ? spack[eb+i] : 0;
  if(t < 32){ sAtt[t]=wb[oatt1+t]; sBo[t]=wb[obo1+t]; sSc[t]=stats1[t]; sSh[t]=stats1[32+t]; }
  if(t < 24){ sDeg[t]=0; sMaxU[t]=0u; sDen[t]=0.f; }
  for(int i=t; i<24*32; i+=256) sEapSum[i>>5][i&31] = 0.f;
  __syncthreads();
  for(int i=t; i<CAP*16; i+=256){
    int e = i>>4, c = i&15;
    float v = 0.f;
    if(e < ecnt){
      u32 id = ((u32)sSp[e]) >> 10;
      if(id >= (u32)EE) id = 0;
      v = ldf(ea, (size_t)id*16 + c, isf);
    }
    sEaF[e][c] = v;
  }
  __syncthreads();

  {
    int c = t & 31, rr0 = t >> 5;
    for(int r = rr0; r < 24; r += 8){
      float al = wb[obl1+c], ar = wb[obr1+c];
      for(int k=0;k<74;k++){
        float xv = sXrow[r][k];
        al += xv * wb[oWl1 + k*32 + c];
        ar += xv * wb[oWr1 + k*32 + c];
      }
      sXl[r][c] = al; sXr[r][c] = ar;
    }
  }
  __syncthreads();

  for(int e=t; e<ecnt; e+=256){
    int sp = sSp[e];
    int sl = sp & 31; if(sl > 23) sl = 0;
    int dl = (sp >> 5) & 31; if(dl > 23) dl = 0;
    float ev = 0.f;
    for(int c=0;c<32;c++){
      float p = 0.f;
      for(int k=0;k<16;k++) p += sEaF[e][k] * wb[oWe1 + k*32 + c];
      atomicAdd(&sEapSum[dl][c], p);
      ev += lrelu(sXl[sl][c] + sXr[dl][c] + p) * sAtt[c];
    }
    sEv[e] = ev;
    atomicMax(&sMaxU[dl], fkey(ev));
    atomicAdd(&sDeg[dl], 1);
  }
  __syncthreads();

  if(t < 24){
    float invd = 1.f / (float)(sDeg[t] > 0 ? sDeg[t] : 1);
    float ev = 0.f;
    for(int c=0;c<32;c++)
      ev += lrelu(sXl[t][c] + sXr[t][c] + sEapSum[t][c]*invd) * sAtt[c];
    float mxv = (sDeg[t] > 0) ? fmaxf(funkey(sMaxU[t]), ev) : ev;
    sMaxF[t] = mxv;
    float z = sexp(ev - mxv);
    sSelfZ[t] = z;
    sDen[t] = z;
  }
  __syncthreads();

  for(int e=t; e<ecnt; e+=256){
    int dl = (sSp[e]>>5)&31; if(dl > 23) dl = 0;
    float z = sexp(sEv[e] - sMaxF[dl]);
    sEz[e] = z;
    atomicAdd(&sDen[dl], z);
  }
  __syncthreads();

  for(int e=t; e<ecnt; e+=256){
    int dl = (sSp[e]>>5)&31; if(dl > 23) dl = 0;
    sEz[e] /= fmaxf(sDen[dl], 1e-30f);
  }
  if(t < 24) sSelfZ[t] /= fmaxf(sDen[t], 1e-30f);
  __syncthreads();

  for(int o=t; o<24*8; o+=256){
    int nl = o >> 3, cq = (o & 7)*4;
    float al = sSelfZ[nl];
    f4_t xv = *(const f4_t*)&sXl[nl][cq];
    f4_t r;
    #pragma unroll
    for(int j=0;j<4;j++) r[j] = al*xv[j];
    *(f4_t*)&sOut[nl][cq] = r;
  }
  __syncthreads();

  for(int o=t; o<ecnt*8; o+=256){
    int e = o >> 3, cq = (o & 7)*4;
    int sp = sSp[e];
    int sl = sp & 31; if(sl > 23) sl = 0;
    int dl = (sp >> 5) & 31; if(dl > 23) dl = 0;
    float al = sEz[e];
    f4_t xv = *(const f4_t*)&sXl[sl][cq];
    atomicAdd(&sOut[dl][cq+0], al*xv[0]);
    atomicAdd(&sOut[dl][cq+1], al*xv[1]);
    atomicAdd(&sOut[dl][cq+2], al*xv[2]);
    atomicAdd(&sOut[dl][cq+3], al*xv[3]);
  }
  __syncthreads();

  for(int i=t; i<24*32; i+=256){
    int r = i>>5, c = i&31;
    float v = fmaxf(sOut[r][c] + sBo[c], 0.f);
    sH[r][c] = v*sSc[c] + sSh[c];
  }
  __syncthreads();
  if(t < 24){ sDeg[t]=0; sMaxU[t]=0u; sDen[t]=0.f; }
  for(int i=t; i<24*8; i+=256) sEapSum[i>>3][i&7] = 0.f;
  __syncthreads();

  if(t < 24*8*2){
    int mat = t/192, rem = t%192, r = rem/8, c = rem&7;
    const float* Wm = wb + (mat ? oWr2 : oWl2);
    float s = wb[(mat ? obr2 : obl2) + c];
    for(int k=0;k<32;k++) s += sH[r][k]*Wm[k*8+c];
    if(mat) sXr2[r][c] = s; else sXl2[r][c] = s;
  }
  __syncthreads();

  for(int e=t; e<ecnt; e+=256){
    int sp = sSp[e];
    int sl = sp & 31; if(sl > 23) sl = 0;
    int dl = (sp >> 5) & 31; if(dl > 23) dl = 0;
    float ev = 0.f;
    for(int c=0;c<8;c++){
      float p = 0.f;
      for(int k=0;k<16;k++) p += sEaF[e][k] * wb[oWe2 + k*8 + c];
      atomicAdd(&sEapSum[dl][c], p);
      ev += lrelu(sXl2[sl][c] + sXr2[dl][c] + p) * wb[oatt2+c];
    }
    sEv[e] = ev;
    atomicMax(&sMaxU[dl], fkey(ev));
    atomicAdd(&sDeg[dl], 1);
  }
  __syncthreads();

  if(t < 24){
    float invd = 1.f / (float)(sDeg[t] > 0 ? sDeg[t] : 1);
    float ev = 0.f;
    for(int c=0;c<8;c++)
      ev += lrelu(sXl2[t][c] + sXr2[t][c] + sEapSum[t][c]*invd) * wb[oatt2+c];
    float mxv = (sDeg[t] > 0) ? fmaxf(funkey(sMaxU[t]), ev) : ev;
    sMaxF[t] = mxv;
    float z = sexp(ev - mxv);
    sSelfZ[t] = z;
    sDen[t] = z;
  }
  __syncthreads();

  for(int e=t; e<ecnt; e+=256){
    int dl = (sSp[e]>>5)&31; if(dl > 23) dl = 0;
    float z = sexp(sEv[e] - sMaxF[dl]);
    sEz[e] = z;
    atomicAdd(&sDen[dl], z);
  }
  __syncthreads();

  for(int e=t; e<ecnt; e+=256){
    int dl = (sSp[e]>>5)&31; if(dl > 23) dl = 0;
    sEz[e] /= fmaxf(sDen[dl], 1e-30f);
  }
  if(t < 24) sSelfZ[t] /= fmaxf(sDen[t], 1e-30f);
  __syncthreads();

  for(int o=t; o<24*8; o+=256){
    int nl = o >> 3, c = o & 7;
    sOut2[nl][c] = sSelfZ[nl] * sXl2[nl][c];
  }
  __syncthreads();

  for(int o=t; o<ecnt*8; o+=256){
    int e = o >> 3, c = o & 7;
    int sp = sSp[e];
    int sl = sp & 31; if(sl > 23) sl = 0;
    int dl = (sp >> 5) & 31; if(dl > 23) dl = 0;
    atomicAdd(&sOut2[dl][c], sEz[e]*sXl2[sl][c]);
  }
  __syncthreads();

  if(t < 8){
    float gs=0.f, gq=0.f;
    for(int nl=0; nl<24; nl++){
      float v = sOut2[nl][t] + wb[obo2+t];
      float s = 1.f / (1.f + __expf(-v));
      gs += s; gq += s*s;
    }
    gsum2[g*8+t] = gs; gsq2[g*8+t] = gq;
  }
}

// ---------------- MLP head ----------------
__global__ __launch_bounds__(256) void k_mlp(
    const float* __restrict__ gsum2, const float* __restrict__ stats2,
    const void* __restrict__ x, const int* __restrict__ dflag,
    const float* __restrict__ wb, float* __restrict__ out)
{
  __shared__ float w[1702];
  int t = threadIdx.x;
  for(int i=t; i<1702; i+=256) w[i] = wb[6048+i];
  __syncthreads();
  int g = blockIdx.x*256 + t;
  int isf = dflag[0];
  float a[30], b[32];
  for(int c=0;c<8;c++) a[c] = stats2[c]*(gsum2[(size_t)g*8+c]*(1.f/24.f)) + stats2[8+c];
  size_t xoff = (size_t)g*PP*96 + 74;
  for(int j=0;j<22;j++) a[8+j] = ldf(x, xoff+j, isf);
  for(int o=0;o<32;o++){ float s = w[960+o];  for(int i=0;i<30;i++) s += a[i]*w[i*32+o];      b[o]=fmaxf(s,0.f); }
  for(int o=0;o<16;o++){ float s = w[1504+o]; for(int i=0;i<32;i++) s += b[i]*w[992+i*16+o];  a[o]=fmaxf(s,0.f); }
  for(int o=0;o<8;o++){  float s = w[1648+o]; for(int i=0;i<16;i++) s += a[i]*w[1520+i*8+o];  b[o]=fmaxf(s,0.f); }
  for(int o=0;o<4;o++){  float s = w[1688+o]; for(int i=0;i<8;i++)  s += b[i]*w[1656+i*4+o];  a[o]=fmaxf(s,0.f); }
  for(int o=0;o<2;o++){
    float s = w[1700+o];
    for(int i=0;i<4;i++) s += a[i]*w[1692+i*2+o];
    out[(size_t)g*2+o] = s;
  }
}

extern "C" void kernel_launch(void* const* d_in, const int* in_sizes, int n_in,
                              void* d_out, int out_size, void* d_ws, size_t ws_size,
                              hipStream_t stream)
{
  (void)in_sizes; (void)n_in; (void)out_size;
  const void* x    = d_in[0];
  const int* eidx  = (const int*)d_in[1];
  const void* ea   = d_in[2];

  const int* srcA = eidx;
  const int* dstA = eidx + EE;

  constexpr size_t O_WB    = 0;
  constexpr size_t O_WQ    = 32768;
  constexpr size_t O_OFFS  = 57344;
  constexpr size_t O_CUR   = O_OFFS + (size_t)(NN+512)*4;
  constexpr size_t O_SPACK = O_CUR  + (size_t)NN*4;
  constexpr size_t O_P1S   = O_SPACK + (size_t)EE*4;
  constexpr size_t O_P1Q   = O_P1S   + (size_t)GG*32*4;
  constexpr size_t O_ST1   = O_P1Q   + (size_t)GG*32*4;
  constexpr size_t O_GS2   = O_ST1   + 256;
  constexpr size_t O_GQ2   = O_GS2   + (size_t)GG*8*4;
  constexpr size_t O_ST2   = O_GQ2   + (size_t)GG*8*4;
  constexpr size_t O_FLAG  = O_ST2   + 256;
  constexpr size_t REQUIRED_BASE = O_FLAG + 256;
  constexpr size_t O_H1    = REQUIRED_BASE;
  constexpr size_t REQUIRED_BIG = O_H1 + (size_t)NN*32*4;
  constexpr size_t O_EAP1  = REQUIRED_BIG;                       // eap: EE*16 f32 (or u16, p-tier bf16)
  constexpr size_t O_P2    = O_EAP1 + (size_t)EE*16*4;           // p2: EE*8 f32
  constexpr size_t REQUIRED_P = O_P2 + (size_t)EE*8*4;
  constexpr size_t REQUIRED_EAP16 = O_EAP1 + (size_t)EE*16*4;

  if(ws_size < REQUIRED_BASE){
    k_zero<<<(GG*2+255)/256, 256, 0, stream>>>((float*)d_out);
    return;
  }
  const int use_h1  = (ws_size >= REQUIRED_BIG)   ? 1 : 0;
  const int use_p   = (use_h1 && ws_size >= REQUIRED_P) ? 1 : 0;
  const int use_eap = (!use_p && ws_size >= REQUIRED_EAP16) ? 1 : 0;

  char* W = (char*)d_ws;
  float* wb     = (float*)(W + O_WB);
  float* wq     = (float*)(W + O_WQ);
  int*   offs   = (int*)(W + O_OFFS);
  int*   bsum   = offs + NN + 64;
  int*   cnt    = (int*)(W + O_CUR);
  int*   cursor = (int*)(W + O_CUR);
  int*   spack  = (int*)(W + O_SPACK);
  float* p1sum  = (float*)(W + O_P1S);
  float* p1sq   = (float*)(W + O_P1Q);
  float* stats1 = (float*)(W + O_ST1);
  float* gsum2  = (float*)(W + O_GS2);
  float* gsq2   = (float*)(W + O_GQ2);
  float* stats2 = (float*)(W + O_ST2);
  int*   dflag  = (int*)(W + O_FLAG);
  float* h1     = (float*)(W + O_H1);
  void*  eap1   = (void*)(W + O_EAP1);
  float* p2     = (float*)(W + O_P2);

  hipMemsetAsync(cnt, 0, (size_t)NN*sizeof(int), stream);
  k_count  <<<EE/256, 256, 0, stream>>>(dstA, cnt);
  k_scanA  <<<192, 1024, 0, stream>>>(cnt, offs, bsum);
  k_scanB  <<<1, 256, 0, stream>>>(bsum, offs);
  k_scanC  <<<192, 1024, 0, stream>>>(offs, bsum, cursor);
  k_scatter<<<EE/256, 256, 0, stream>>>(srcA, dstA, cursor, spack);
  k_wconv  <<<1, 256, 0, stream>>>(wb, wq, dflag, (const u32*)x,
            d_in[4], d_in[5], d_in[6], d_in[7], d_in[8], d_in[9], d_in[10],
            d_in[11], d_in[12], d_in[13], d_in[14], d_in[15], d_in[16], d_in[17],
            d_in[22], d_in[23], d_in[24], d_in[25], d_in[26], d_in[27],
            d_in[28], d_in[29], d_in[30], d_in[31]);
  if(use_p){
    k_eapermB<<<EE/256, 256, 0, stream>>>(spack, offs, ea, dflag, wb, eap1, p2);
    k_l1stats_p<<<GG, 256, 0, stream>>>(x, eap1, wb, wq, offs, spack, dflag,
                                        p1sum, p1sq, h1);
  } else {
    if(use_eap)
      k_eaperm<<<EE/256, 256, 0, stream>>>(spack, offs, ea, dflag, (float*)eap1);
    k_l1stats<<<GG, 256, 0, stream>>>(x, ea, use_eap ? (float*)eap1 : (float*)nullptr,
                                      wb, wq, offs, spack, dflag,
                                      p1sum, p1sq, h1, use_h1);
  }
  k_reduce <<<32, 256, 0, stream>>>(p1sum, p1sq, d_in[18], d_in[19], dflag, stats1, 32);
  k_prep2  <<<1, 256, 0, stream>>>(wq, wb, stats1);
  if(use_p)
    k_fused2_p<<<GG, 256, 0, stream>>>(p2, wb, wq, h1, offs, spack, gsum2, gsq2);
  else if(use_h1)
    k_fused2_h1<<<GG, 256, 0, stream>>>(ea, use_eap ? (float*)eap1 : (float*)nullptr,
                                        wb, wq, h1, offs, spack, dflag, gsum2, gsq2);
  else
    k_fused2_rec<<<GG, 256, 0, stream>>>(x, ea, wb, stats1, offs, spack, dflag, gsum2, gsq2);
  k_reduce <<<8, 256, 0, stream>>>(gsum2, gsq2, d_in[20], d_in[21], dflag, stats2, 8);
  k_mlp    <<<GG/256, 256, 0, stream>>>(gsum2, stats2, x, dflag, wb, (float*)d_out);
}

// Round 11
// 582.355 us; speedup vs baseline: 1.1262x; 1.0169x over previous
//
#include <hip/hip_runtime.h>

typedef unsigned short u16;
typedef unsigned int   u32;
typedef __attribute__((ext_vector_type(4))) float f4_t;
typedef __attribute__((ext_vector_type(4))) unsigned short us4_t;
typedef __attribute__((ext_vector_type(4))) unsigned int   u4_t;

#define GG 8192
#define PP 24
#define NN 196608
#define EE 786432
#define CAP 176

// ---- packed f32 weight buffer offsets (wb region) ----
#define oWl1 0
#define oWr1 2368
#define obl1 4736
#define obr1 4768
#define oWe1 4800
#define oatt1 5312
#define obo1 5344
#define oWl2 5376
#define oWr2 5632
#define obl2 5888
#define obr2 5896
#define oWe2 5904
#define oatt2 6032
#define obo2 6040
#define ofc1W 6048
#define ofc1b 7008
#define ofc2W 7040
#define ofc2b 7552
#define ofc3W 7568
#define ofc3b 7696
#define ofc4W 7704
#define ofc4b 7736
#define ooutW 7740
#define ooutb 7748

// ---- wq buffer ----
#define oW1I 0        // 76x64 interleaved W1 (rows 74,75 zero) = 4864 floats
#define oW2P 4864     // 32x16 BN-folded W2' = 512 floats
#define oB2P 5376     // 16 floats

__device__ __forceinline__ float bf2f(u16 u){
  union { u32 i; float f; } x; x.i = ((u32)u) << 16; return x.f;
}
__device__ __forceinline__ u32 fkey(float f){
  int i = __float_as_int(f);
  return (i >= 0) ? (((u32)i) | 0x80000000u) : ~((u32)i);
}
__device__ __forceinline__ float funkey(u32 k){
  u32 i = (k & 0x80000000u) ? (k & 0x7FFFFFFFu) : ~k;
  return __uint_as_float(i);
}
__device__ __forceinline__ float lrelu(float m){ return m > 0.f ? m : 0.2f*m; }
__device__ __forceinline__ float sexp(float a){ return __expf(fminf(a, 0.f)); }
__device__ __forceinline__ float ldf(const void* p, size_t i, int isf){
  return isf ? ((const float*)p)[i] : bf2f(((const u16*)p)[i]);
}

__global__ void k_zero(float* __restrict__ out){
  int i = blockIdx.x*256 + threadIdx.x;
  if(i < GG*2) out[i] = 0.f;
}

// ---------------- per-NODE bucketing ----------------
__global__ void k_count(const int* __restrict__ dst, int* __restrict__ cnt){
  int e = blockIdx.x*256 + threadIdx.x;
  if(e < EE){
    u32 d = (u32)dst[e];
    if(d < (u32)NN) atomicAdd(&cnt[d], 1);
  }
}

__global__ void k_scanA(const int* __restrict__ cnt, int* __restrict__ offs,
                        int* __restrict__ bsum){
  __shared__ int part[1024];
  int t = threadIdx.x;
  int i = blockIdx.x*1024 + t;
  int c = cnt[i];
  part[t] = c; __syncthreads();
  for(int off=1; off<1024; off<<=1){
    int v = (t>=off) ? part[t-off] : 0;
    __syncthreads();
    part[t] += v;
    __syncthreads();
  }
  offs[i] = part[t] - c;
  if(t==1023) bsum[blockIdx.x] = part[1023];
}

__global__ void k_scanB(int* __restrict__ bsum, int* __restrict__ offs){
  __shared__ int part[256];
  int t = threadIdx.x;
  int c = (t < 192) ? bsum[t] : 0;
  part[t] = c; __syncthreads();
  for(int off=1; off<256; off<<=1){
    int v = (t>=off) ? part[t-off] : 0;
    __syncthreads();
    part[t] += v;
    __syncthreads();
  }
  if(t < 192) bsum[t] = part[t] - c;
  if(t == 255) offs[NN] = part[255];
}

__global__ void k_scanC(int* __restrict__ offs, const int* __restrict__ bsum,
                        int* __restrict__ cursor){
  int t = threadIdx.x;
  int i = blockIdx.x*1024 + t;
  int v = offs[i] + bsum[blockIdx.x];
  offs[i] = v;
  cursor[i] = v;
}

// pack: sl(5b) | dl(5b)<<5 | edge_id(20b)<<10 ; sorted by dst node
__global__ void k_scatter(const int* __restrict__ src, const int* __restrict__ dst,
                          int* __restrict__ cursor, int* __restrict__ spack){
  int e = blockIdx.x*256 + threadIdx.x;
  if(e < EE){
    u32 d = (u32)dst[e];
    if(d >= (u32)NN) return;
    int g = d / PP;
    int pos = atomicAdd(&cursor[d], 1);
    if((u32)pos < (u32)EE){
      int sl = src[e] - g*PP;
      if((u32)sl > 23u) sl = 0;
      spack[pos] = sl | ((int)(d - g*PP) << 5) | (e << 10);
    }
  }
}

// ---------- mid tier: permute ea into sorted order, f32 16-wide ----------
__global__ void k_eaperm(const int* __restrict__ spack, const int* __restrict__ offs,
                         const void* __restrict__ ea, const int* __restrict__ dflag,
                         float* __restrict__ eap){
  int i = blockIdx.x*256 + threadIdx.x;
  if(i >= EE) return;
  if(i >= offs[NN]) return;
  int isf = dflag[0];
  u32 id = ((u32)spack[i]) >> 10;
  if(id >= (u32)EE) id = 0;
  float* o = eap + (size_t)i*16;
  if(isf){
    const float* er = (const float*)ea + (size_t)id*16;
    #pragma unroll
    for(int q=0;q<4;q++) *(f4_t*)(o + q*4) = *(const f4_t*)(er + q*4);
  } else {
    const u16* er = (const u16*)ea + (size_t)id*16;
    #pragma unroll
    for(int c=0;c<16;c++) o[c] = bf2f(er[c]);
  }
}

// ---------- p tier: permute ea in INPUT dtype (lossless). No p2 materialization:
// fused2_p recomputes ea@We2 from this L2-warm stream (128 MACs/edge, trivial). ----------
__global__ void k_eapermB(const int* __restrict__ spack, const int* __restrict__ offs,
                          const void* __restrict__ ea, const int* __restrict__ dflag,
                          void* __restrict__ eap){
  int i = blockIdx.x*256 + threadIdx.x;
  if(i >= EE) return;
  if(i >= offs[NN]) return;
  int isf = dflag[0];
  u32 id = ((u32)spack[i]) >> 10;
  if(id >= (u32)EE) id = 0;
  if(isf){
    const float* er = (const float*)ea + (size_t)id*16;
    float* o = (float*)eap + (size_t)i*16;
    #pragma unroll
    for(int q=0;q<4;q++) *(f4_t*)(o + q*4) = *(const f4_t*)(er + q*4);
  } else {
    const u4_t* s4 = (const u4_t*)((const u16*)ea + (size_t)id*16);
    u4_t* o4 = (u4_t*)((u16*)eap + (size_t)i*16);
    o4[0] = s4[0];
    o4[1] = s4[1];
  }
}

// ---------- fused dtype-detect + weight conversion (8 blocks; each block
// redundantly detects dtype from the same 8 KB of x, converts its stripe) ----------
__global__ void k_wconv(float* __restrict__ wb, float* __restrict__ wq, int* __restrict__ dflag,
    const u32* __restrict__ xw,
    const void* Wl1, const void* bl1, const void* Wr1, const void* br1,
    const void* We1, const void* att1, const void* bo1,
    const void* Wl2, const void* bl2, const void* Wr2, const void* br2,
    const void* We2, const void* att2, const void* bo2,
    const void* f1W, const void* f1b, const void* f2W, const void* f2b,
    const void* f3W, const void* f3b, const void* f4W, const void* f4b,
    const void* oW,  const void* ob)
{
  __shared__ u32 mx[256];
  int t = threadIdx.x;
  int bid = blockIdx.x;
  u32 m = 0;
  for(int i=t; i<2048; i+=256){
    u32 e = (xw[i] >> 7) & 0xFFu;
    m = m > e ? m : e;
  }
  mx[t] = m; __syncthreads();
  for(int off=128; off>0; off>>=1){
    if(t<off) mx[t] = mx[t] > mx[t+off] ? mx[t] : mx[t+off];
    __syncthreads();
  }
  int isf = (mx[0] > 140u) ? 1 : 0;
  if(t==0 && bid==0) dflag[0] = isf;
  const int stp = 8*256;
  #define CP(off,src,len) for(int i=bid*256+t;i<(len);i+=stp) wb[(off)+i]=ldf(src,i,isf);
  CP(oWl1,Wl1,2368) CP(oWr1,Wr1,2368) CP(obl1,bl1,32) CP(obr1,br1,32)
  CP(oWe1,We1,512)  CP(oatt1,att1,32) CP(obo1,bo1,32)
  CP(oWl2,Wl2,256)  CP(oWr2,Wr2,256)  CP(obl2,bl2,8)  CP(obr2,br2,8)
  CP(oWe2,We2,128)  CP(oatt2,att2,8)  CP(obo2,bo2,8)
  CP(ofc1W,f1W,960) CP(ofc1b,f1b,32)  CP(ofc2W,f2W,512) CP(ofc2b,f2b,16)
  CP(ofc3W,f3W,128) CP(ofc3b,f3b,8)   CP(ofc4W,f4W,32)  CP(ofc4b,f4b,4)
  CP(ooutW,oW,8)    CP(ooutb,ob,2)
  #undef CP
  for(int i=bid*256+t; i<76*64; i+=stp){
    int k = i>>6, cc = i&63, mat = cc>>5, c = cc&31;
    wq[oW1I + i] = (k < 74) ? ldf(mat ? Wr1 : Wl1, k*32 + c, isf) : 0.f;
  }
}

// ---------- BN-fold for layer 2 ----------
__global__ void k_prep2(float* __restrict__ wq, const float* __restrict__ wb,
                        const float* __restrict__ stats1){
  int t = threadIdx.x;
  for(int i=t; i<512; i+=256){
    int k = i>>4, cc = i&15, mat = cc>>3, c = cc&7;
    wq[oW2P + i] = stats1[k] * wb[(mat ? oWr2 : oWl2) + k*8 + c];
  }
  if(t < 16){
    int mat = t>>3, c = t&7;
    float s = wb[(mat ? obr2 : obl2) + c];
    for(int k=0;k<32;k++) s += stats1[32+k] * wb[(mat ? oWr2 : oWl2) + k*8 + c];
    wq[oB2P + t] = s;
  }
}

// ======== p-tier pass 1: rows parallel, p1 computed into LDS (not HBM) ========
// LDS ~40 KB -> 4 blocks/CU. sP padded to 36 floats/row. Config measured
// 198 us (rounds 6/9/10); trimmed-LDS and in-kernel-gather variants both
// measured slower (268 / 303 us). Byte-identical to round 10.
__global__ __launch_bounds__(256, 4) void k_l1stats_p(
    const void* __restrict__ x, const void* __restrict__ eap,
    const float* __restrict__ wb, const float* __restrict__ wq,
    const int* __restrict__ offs, const int* __restrict__ spack, const int* __restrict__ dflag,
    float* __restrict__ p1sum, float* __restrict__ p1sq,
    float* __restrict__ h1)
{
  __shared__ __align__(16) float sP[CAP][36];    // ea@We1 per edge (cols 0..31)
  __shared__ __align__(16) float sXl[24][36];
  __shared__ __align__(16) float sXr[24][36];
  __shared__ __align__(16) float sPS[24][32];
  __shared__ __align__(16) float sPQ[24][32];
  __shared__ float sEv[CAP];
  __shared__ int   sSl[CAP];
  __shared__ int   sRO[25];

  const int t = threadIdx.x;
  const int g = blockIdx.x;
  const int isf = dflag[0];
  const int nb = g*PP;
  const int eb = offs[nb];
  int ecnt = offs[nb+24] - eb;
  if(ecnt < 0) ecnt = 0; if(ecnt > CAP) ecnt = CAP;

  if(t < 25){
    int v = offs[nb+t] - eb;
    if(v < 0) v = 0; if(v > CAP) v = CAP;
    sRO[t] = v;
  }
  for(int i=t; i<ecnt; i+=256){
    int sl = spack[eb+i] & 31; if(sl > 23) sl = 0;
    sSl[i] = sl;
  }

  // ---- phase A1: projection xl/xr (wave w -> rows 6w..6w+5) ----
  {
    const int c = t & 31, mat = (t>>5)&1, w = t>>6, cc = t&63;
    const float* gW = wq + oW1I;
    float bi = wb[(mat ? obr1 : obl1) + c];
    float acc[6];
    #pragma unroll
    for(int j=0;j<6;j++) acc[j] = bi;
    if(isf){
      const float* xr0 = (const float*)x + (size_t)(nb + w*6)*96;
      for(int kb=0; kb<19; kb++){
        float w0 = gW[(kb*4+0)*64 + cc];
        float w1 = gW[(kb*4+1)*64 + cc];
        float w2 = gW[(kb*4+2)*64 + cc];
        float w3 = gW[(kb*4+3)*64 + cc];
        #pragma unroll
        for(int j=0;j<6;j++){
          f4_t xv = *(const f4_t*)(xr0 + (size_t)j*96 + kb*4);
          acc[j] += xv[0]*w0 + xv[1]*w1 + xv[2]*w2 + xv[3]*w3;
        }
      }
    } else {
      const u16* xr0 = (const u16*)x + (size_t)(nb + w*6)*96;
      for(int kb=0; kb<19; kb++){
        float w0 = gW[(kb*4+0)*64 + cc];
        float w1 = gW[(kb*4+1)*64 + cc];
        float w2 = gW[(kb*4+2)*64 + cc];
        float w3 = gW[(kb*4+3)*64 + cc];
        #pragma unroll
        for(int j=0;j<6;j++){
          us4_t xv = *(const us4_t*)(xr0 + (size_t)j*96 + kb*4);
          acc[j] += bf2f(xv[0])*w0 + bf2f(xv[1])*w1 + bf2f(xv[2])*w2 + bf2f(xv[3])*w3;
        }
      }
    }
    if(mat){
      #pragma unroll
      for(int j=0;j<6;j++) sXr[w*6+j][c] = acc[j];
    } else {
      #pragma unroll
      for(int j=0;j<6;j++) sXl[w*6+j][c] = acc[j];
    }
  }

  // ---- phase A2: p1 into LDS. task (e, q): cols q*4..q*4+3 of edge e ----
  for(int i=t; i<ecnt*8; i+=256){
    int e = i>>3, q = i&7;
    float ev[16];
    if(isf){
      const float* er = (const float*)eap + (size_t)(eb+e)*16;  // 64-B row, 8 tasks share
      #pragma unroll
      for(int qq=0;qq<4;qq++){
        f4_t v = *(const f4_t*)(er + qq*4);
        ev[qq*4+0]=v[0]; ev[qq*4+1]=v[1]; ev[qq*4+2]=v[2]; ev[qq*4+3]=v[3];
      }
    } else {
      const u16* er = (const u16*)eap + (size_t)(eb+e)*16;      // 32-B row, 8 tasks share
      #pragma unroll
      for(int qq=0;qq<4;qq++){
        us4_t v = *(const us4_t*)(er + qq*4);
        ev[qq*4+0]=bf2f(v[0]); ev[qq*4+1]=bf2f(v[1]); ev[qq*4+2]=bf2f(v[2]); ev[qq*4+3]=bf2f(v[3]);
      }
    }
    float s0=0.f, s1=0.f, s2=0.f, s3=0.f;
    #pragma unroll
    for(int k=0;k<16;k++){
      f4_t w = *(const f4_t*)(wb + oWe1 + k*32 + q*4);
      s0 += ev[k]*w[0]; s1 += ev[k]*w[1]; s2 += ev[k]*w[2]; s3 += ev[k]*w[3];
    }
    f4_t r; r[0]=s0; r[1]=s1; r[2]=s2; r[3]=s3;
    *(f4_t*)&sP[e][q*4] = r;                     // e*144 + q*16 bytes: 16-B aligned
  }
  __syncthreads();   // barrier 1

  if(t < 192){       // 8 lanes per row, 24 rows in parallel
    const int r = t >> 3, sub = t & 7;
    const int a = sRO[r], b = sRO[r+1];
    const int deg = b - a;
    const float* att = wb + oatt1;

    // e-values: lane owns edges a+sub, a+sub+8, ... ; p1 from LDS
    float emax = -3.4e38f;
    for(int e=a+sub; e<b; e+=8){
      int sl = sSl[e];
      float ev = 0.f;
      #pragma unroll
      for(int q=0;q<8;q++){
        f4_t pv  = *(const f4_t*)&sP[e][q*4];
        f4_t xlv = *(const f4_t*)&sXl[sl][q*4];
        f4_t xrv = *(const f4_t*)&sXr[r][q*4];
        ev += att[q*4+0]*lrelu(xlv[0]+xrv[0]+pv[0]);
        ev += att[q*4+1]*lrelu(xlv[1]+xrv[1]+pv[1]);
        ev += att[q*4+2]*lrelu(xlv[2]+xrv[2]+pv[2]);
        ev += att[q*4+3]*lrelu(xlv[3]+xrv[3]+pv[3]);
      }
      sEv[e] = ev;
      emax = fmaxf(emax, ev);
    }
    emax = fmaxf(emax, __shfl_xor(emax, 1));
    emax = fmaxf(emax, __shfl_xor(emax, 2));
    emax = fmaxf(emax, __shfl_xor(emax, 4));

    // self-loop via linearity: mean of p1 over edges; lane owns cols sub*4..+3
    float m0=0.f, m1=0.f, m2=0.f, m3=0.f;
    for(int e=a; e<b; ++e){
      f4_t pv = *(const f4_t*)&sP[e][sub*4];     // banks (e*4+sub*4)%32: conflict-free
      m0 += pv[0]; m1 += pv[1]; m2 += pv[2]; m3 += pv[3];
    }
    float invd = 1.f / (float)(deg > 0 ? deg : 1);
    float sv;
    {
      int c0 = sub*4;
      sv  = att[c0+0]*lrelu(sXl[r][c0+0] + sXr[r][c0+0] + m0*invd);
      sv += att[c0+1]*lrelu(sXl[r][c0+1] + sXr[r][c0+1] + m1*invd);
      sv += att[c0+2]*lrelu(sXl[r][c0+2] + sXr[r][c0+2] + m2*invd);
      sv += att[c0+3]*lrelu(sXl[r][c0+3] + sXr[r][c0+3] + m3*invd);
    }
    sv += __shfl_xor(sv, 1);
    sv += __shfl_xor(sv, 2);
    sv += __shfl_xor(sv, 4);

    // softmax (z in place in sEv)
    float m = fmaxf(emax, sv);
    float ssum = 0.f;
    for(int e=a+sub; e<b; e+=8){
      float z = sexp(sEv[e] - m);
      sEv[e] = z;
      ssum += z;
    }
    ssum += __shfl_xor(ssum, 1);
    ssum += __shfl_xor(ssum, 2);
    ssum += __shfl_xor(ssum, 4);
    float selfZ = sexp(sv - m);
    float rden = 1.f / fmaxf(ssum + selfZ, 1e-30f);

    // aggregation: lane owns cols sub*4..+3
    float a0=0.f, a1=0.f, a2=0.f, a3=0.f;
    for(int e=a; e<b; ++e){
      float z = sEv[e];
      f4_t xlv = *(const f4_t*)&sXl[sSl[e]][sub*4];
      a0 += z*xlv[0]; a1 += z*xlv[1]; a2 += z*xlv[2]; a3 += z*xlv[3];
    }
    f4_t xself = *(const f4_t*)&sXl[r][sub*4];
    f4_t outv, sqv;
    {
      float o;
      o = (a0 + selfZ*xself[0]) * rden; o = fmaxf(o + wb[obo1+sub*4+0], 0.f); outv[0]=o; sqv[0]=o*o;
      o = (a1 + selfZ*xself[1]) * rden; o = fmaxf(o + wb[obo1+sub*4+1], 0.f); outv[1]=o; sqv[1]=o*o;
      o = (a2 + selfZ*xself[2]) * rden; o = fmaxf(o + wb[obo1+sub*4+2], 0.f); outv[2]=o; sqv[2]=o*o;
      o = (a3 + selfZ*xself[3]) * rden; o = fmaxf(o + wb[obo1+sub*4+3], 0.f); outv[3]=o; sqv[3]=o*o;
    }
    *(f4_t*)&h1[((size_t)nb + r)*32 + sub*4] = outv;
    *(f4_t*)&sPS[r][sub*4] = outv;
    *(f4_t*)&sPQ[r][sub*4] = sqv;
  }
  __syncthreads();   // barrier 2
  if(t < 32){
    float s=0.f, q=0.f;
    #pragma unroll
    for(int r=0;r<24;r++){ s += sPS[r][t]; q += sPQ[r][t]; }
    p1sum[g*32+t] = s; p1sq[g*32+t] = q;
  }
}

// ======== p-tier pass 2: layer2 from h1; p2 recomputed into LDS from eap ========
// (summation order identical to the old k_eapermB p2 loop -> bit-identical sP2)
__global__ __launch_bounds__(256, 6) void k_fused2_p(
    const void* __restrict__ eap, const int* __restrict__ dflag,
    const float* __restrict__ wb, const float* __restrict__ wq,
    const float* __restrict__ h1,
    const int* __restrict__ offs, const int* __restrict__ spack,
    float* __restrict__ gsum2, float* __restrict__ gsq2)
{
  __shared__ __align__(16) float sP2[CAP][12];   // ea@We2 tile; pad-12 rotates banks
  __shared__ float sXl2[24][13];
  __shared__ float sXr2[24][13];
  __shared__ float sEv[CAP];
  __shared__ int   sSl[CAP];
  __shared__ int   sRO[25];
  __shared__ float sGS[24][8];
  __shared__ float sGQ[24][8];

  const int t = threadIdx.x;
  const int g = blockIdx.x;
  const int wid = t >> 6;
  const int lane = t & 63;
  const int isf = dflag[0];
  const int nb = g*PP;
  const int eb = offs[nb];
  int ecnt = offs[nb+24] - eb;
  if(ecnt < 0) ecnt = 0; if(ecnt > CAP) ecnt = CAP;

  if(t < 25){
    int v = offs[nb+t] - eb;
    if(v < 0) v = 0; if(v > CAP) v = CAP;
    sRO[t] = v;
  }
  for(int i=t; i<ecnt; i+=256){
    int sl = spack[eb+i] & 31; if(sl > 23) sl = 0;
    sSl[i] = sl;
  }
  // stage p2 tile: recompute ea@We2 from the (L2-warm) permuted ea stream.
  // task (e, half): cols half*4..half*4+3; 2 tasks share each eap row.
  for(int i=t; i<ecnt*2; i+=256){
    int e = i>>1, half = i&1;
    float eav[16];
    if(isf){
      const float* er = (const float*)eap + (size_t)(eb+e)*16;
      #pragma unroll
      for(int qq=0;qq<4;qq++){
        f4_t v = *(const f4_t*)(er + qq*4);
        eav[qq*4+0]=v[0]; eav[qq*4+1]=v[1]; eav[qq*4+2]=v[2]; eav[qq*4+3]=v[3];
      }
    } else {
      const u16* er = (const u16*)eap + (size_t)(eb+e)*16;
      #pragma unroll
      for(int qq=0;qq<4;qq++){
        us4_t v = *(const us4_t*)(er + qq*4);
        eav[qq*4+0]=bf2f(v[0]); eav[qq*4+1]=bf2f(v[1]); eav[qq*4+2]=bf2f(v[2]); eav[qq*4+3]=bf2f(v[3]);
      }
    }
    int c = half*4;
    float s0=0.f, s1=0.f, s2=0.f, s3=0.f;
    #pragma unroll
    for(int k=0;k<16;k++){
      f4_t w = *(const f4_t*)(wb + oWe2 + k*8 + c);
      s0 += eav[k]*w[0]; s1 += eav[k]*w[1]; s2 += eav[k]*w[2]; s3 += eav[k]*w[3];
    }
    f4_t r; r[0]=s0; r[1]=s1; r[2]=s2; r[3]=s3;
    *(f4_t*)&sP2[e][half*4] = r;     // e*48 + half*16 bytes: 16-B aligned
  }
  // projection xl2/xr2 (BN folded): wave wid computes rows 6*wid..6*wid+5
  {
    int rz = wid*6;
    for(int i=lane; i<96; i+=64){
      int rl = i>>4, cc = i&15;
      int r = rz + rl;
      float s = wq[oB2P + cc];
      const float* hr = h1 + ((size_t)nb + r)*32;
      #pragma unroll
      for(int q=0;q<8;q++){
        f4_t hv = *(const f4_t*)(hr + q*4);
        s += hv[0]*wq[oW2P+(q*4+0)*16+cc] + hv[1]*wq[oW2P+(q*4+1)*16+cc]
           + hv[2]*wq[oW2P+(q*4+2)*16+cc] + hv[3]*wq[oW2P+(q*4+3)*16+cc];
      }
      if(cc < 8) sXl2[r][cc] = s; else sXr2[r][cc-8] = s;
    }
  }
  __syncthreads();   // barrier 1

  if(t < 192){
    const int r = t >> 3, sub = t & 7;
    const int a = sRO[r], b = sRO[r+1];
    const int deg = b - a;
    const float* att2 = wb + oatt2;

    float emax = -3.4e38f;
    for(int e=a+sub; e<b; e+=8){
      int sl = sSl[e];
      f4_t q0 = *(const f4_t*)&sP2[e][0];
      f4_t q1 = *(const f4_t*)&sP2[e][4];
      float ev = 0.f;
      #pragma unroll
      for(int j=0;j<4;j++) ev += att2[j]  *lrelu(sXl2[sl][j]   + sXr2[r][j]   + q0[j]);
      #pragma unroll
      for(int j=0;j<4;j++) ev += att2[4+j]*lrelu(sXl2[sl][4+j] + sXr2[r][4+j] + q1[j]);
      sEv[e] = ev;
      emax = fmaxf(emax, ev);
    }
    emax = fmaxf(emax, __shfl_xor(emax, 1));
    emax = fmaxf(emax, __shfl_xor(emax, 2));
    emax = fmaxf(emax, __shfl_xor(emax, 4));

    // self-loop via mean p2 (LDS); lane owns col sub
    float mpc = 0.f;
    for(int e=a; e<b; ++e)
      mpc += sP2[e][sub];
    float invd = 1.f / (float)(deg > 0 ? deg : 1);
    float sv = att2[sub]*lrelu(sXl2[r][sub] + sXr2[r][sub] + mpc*invd);
    sv += __shfl_xor(sv, 1);
    sv += __shfl_xor(sv, 2);
    sv += __shfl_xor(sv, 4);

    float m = fmaxf(emax, sv);
    float ssum = 0.f;
    for(int e=a+sub; e<b; e+=8){
      float z = sexp(sEv[e] - m);
      sEv[e] = z;
      ssum += z;
    }
    ssum += __shfl_xor(ssum, 1);
    ssum += __shfl_xor(ssum, 2);
    ssum += __shfl_xor(ssum, 4);
    float selfZ = sexp(sv - m);
    float rden = 1.f / fmaxf(ssum + selfZ, 1e-30f);

    float acc = 0.f;
    for(int e=a; e<b; ++e)
      acc += sEv[e] * sXl2[sSl[e]][sub];
    float o = (acc + selfZ*sXl2[r][sub]) * rden;
    float s = 1.f / (1.f + __expf(-(o + wb[obo2+sub])));
    sGS[r][sub] = s;
    sGQ[r][sub] = s*s;
  }
  __syncthreads();   // barrier 2
  if(t < 8){
    float gs=0.f, gq=0.f;
    #pragma unroll
    for(int r=0;r<24;r++){ gs += sGS[r][t]; gq += sGQ[r][t]; }
    gsum2[g*8+t] = gs; gsq2[g*8+t] = gq;
  }
}

// ======== mid tier (round-3) kernels, verbatim fallback ========
__global__ __launch_bounds__(256, 6) void k_l1stats(
    const void* __restrict__ x, const void* __restrict__ ea, const float* __restrict__ eap,
    const float* __restrict__ wb, const float* __restrict__ wq,
    const int* __restrict__ offs, const int* __restrict__ spack, const int* __restrict__ dflag,
    float* __restrict__ p1sum, float* __restrict__ p1sq,
    float* __restrict__ h1, int use_h1)
{
  __shared__ __align__(16) float sEaF[CAP][16];
  __shared__ __align__(16) float sXl[24][36];
  __shared__ float sXr[24][33];
  __shared__ float sEaSum[24][17];
  __shared__ float sEv[CAP];
  __shared__ int   sSl[CAP];
  __shared__ int   sRO[25];
  __shared__ float sSelfE[24];
  __shared__ float sPS[4][32], sPQ[4][32];

  const int t = threadIdx.x;
  const int g = blockIdx.x;
  const int wid = t >> 6;
  const int lane = t & 63;
  const int isf = dflag[0];
  const int nb = g*PP;
  const int eb = offs[nb];
  int ecnt = offs[nb+24] - eb; if(ecnt < 0) ecnt = 0; if(ecnt > CAP) ecnt = CAP;

  if(t < 25){
    int v = offs[nb+t] - eb;
    if(v < 0) v = 0; if(v > CAP) v = CAP;
    sRO[t] = v;
  }
  if(eap){
    for(int i=t; i<ecnt; i+=256) sSl[i] = spack[eb+i] & 1023;
    for(int i=t; i<ecnt*4; i+=256){
      int e = i>>2, q = i&3;
      *(f4_t*)&sEaF[e][q*4] = *(const f4_t*)(eap + ((size_t)(eb+e))*16 + q*4);
    }
  } else {
    for(int i=t; i<ecnt; i+=256){
      int sp = spack[eb+i];
      sSl[i] = sp & 1023;
      u32 id = ((u32)sp) >> 10;
      if(id >= (u32)EE) id = 0;
      if(isf){
        const float* er = (const float*)ea + (size_t)id*16;
        #pragma unroll
        for(int q=0;q<4;q++) *(f4_t*)&sEaF[i][q*4] = *(const f4_t*)(er + q*4);
      } else {
        #pragma unroll
        for(int c=0;c<16;c++) sEaF[i][c] = bf2f(((const u16*)ea)[(size_t)id*16 + c]);
      }
    }
  }
  {
    int rz = wid*6;
    for(int i=lane; i<6*17; i+=64) sEaSum[rz + i/17][i%17] = 0.f;
  }

  {
    const int c = t & 31, mat = (t>>5)&1, w = wid, cc = t&63;
    const float* gW = wq + oW1I;
    float bi = wb[(mat ? obr1 : obl1) + c];
    float acc[6];
    #pragma unroll
    for(int j=0;j<6;j++) acc[j] = bi;
    if(isf){
      const float* xr0 = (const float*)x + (size_t)(nb + w*6)*96;
      for(int kb=0; kb<19; kb++){
        float w0 = gW[(kb*4+0)*64 + cc];
        float w1 = gW[(kb*4+1)*64 + cc];
        float w2 = gW[(kb*4+2)*64 + cc];
        float w3 = gW[(kb*4+3)*64 + cc];
        #pragma unroll
        for(int j=0;j<6;j++){
          f4_t xv = *(const f4_t*)(xr0 + (size_t)j*96 + kb*4);
          acc[j] += xv[0]*w0 + xv[1]*w1 + xv[2]*w2 + xv[3]*w3;
        }
      }
    } else {
      const u16* xr0 = (const u16*)x + (size_t)(nb + w*6)*96;
      for(int kb=0; kb<19; kb++){
        float w0 = gW[(kb*4+0)*64 + cc];
        float w1 = gW[(kb*4+1)*64 + cc];
        float w2 = gW[(kb*4+2)*64 + cc];
        float w3 = gW[(kb*4+3)*64 + cc];
        #pragma unroll
        for(int j=0;j<6;j++){
          us4_t xv = *(const us4_t*)(xr0 + (size_t)j*96 + kb*4);
          acc[j] += bf2f(xv[0])*w0 + bf2f(xv[1])*w1 + bf2f(xv[2])*w2 + bf2f(xv[3])*w3;
        }
      }
    }
    if(mat){
      #pragma unroll
      for(int j=0;j<6;j++) sXr[w*6+j][c] = acc[j];
    } else {
      #pragma unroll
      for(int j=0;j<6;j++) sXl[w*6+j][c] = acc[j];
    }
  }
  __syncthreads();

  const int r0 = wid*6;
  const int a0 = sRO[r0], a1 = sRO[r0+6];
  const int c = t & 31, eo = (t>>5)&1;

  float wr[16];
  #pragma unroll
  for(int k=0;k<16;k++) wr[k] = wb[oWe1 + k*32 + c];
  const float av = wb[oatt1 + c];
  const float bv = wb[obo1 + c];

  for(int base=a0; base<a1; base+=2){
    int e = base + eo;
    bool valid = (e < a1);
    int ec = valid ? e : a0;
    int sp = sSl[ec];
    int sl = sp & 31; if(sl > 23) sl = 0;
    int dl = (sp >> 5) & 31; if(dl > 23) dl = 0;
    f4_t A0 = *(const f4_t*)&sEaF[ec][0];
    f4_t A1 = *(const f4_t*)&sEaF[ec][4];
    f4_t A2 = *(const f4_t*)&sEaF[ec][8];
    f4_t A3 = *(const f4_t*)&sEaF[ec][12];
    float p = A0[0]*wr[0]+A0[1]*wr[1]+A0[2]*wr[2]+A0[3]*wr[3]
            + A1[0]*wr[4]+A1[1]*wr[5]+A1[2]*wr[6]+A1[3]*wr[7]
            + A2[0]*wr[8]+A2[1]*wr[9]+A2[2]*wr[10]+A2[3]*wr[11]
            + A3[0]*wr[12]+A3[1]*wr[13]+A3[2]*wr[14]+A3[3]*wr[15];
    if(valid && c < 16) atomicAdd(&sEaSum[dl][c], sEaF[ec][c]);
    float v = lrelu(sXl[sl][c] + sXr[dl][c] + p) * av;
    v += __shfl_xor(v, 16);
    v += __shfl_xor(v, 8);
    v += __shfl_xor(v, 4);
    v += __shfl_xor(v, 2);
    v += __shfl_xor(v, 1);
    if(valid && c == 0) sEv[e] = v;
  }

  #pragma unroll
  for(int rp=0; rp<3; rp++){
    int r = r0 + rp*2 + eo;
    int deg = sRO[r+1] - sRO[r];
    float invd = 1.f / (float)(deg > 0 ? deg : 1);
    float mp = 0.f;
    #pragma unroll
    for(int k=0;k<16;k++) mp += sEaSum[r][k] * wr[k];
    float v = lrelu(sXl[r][c] + sXr[r][c] + mp*invd) * av;
    v += __shfl_xor(v, 16);
    v += __shfl_xor(v, 8);
    v += __shfl_xor(v, 4);
    v += __shfl_xor(v, 2);
    v += __shfl_xor(v, 1);
    if(c == 0) sSelfE[r] = v;
  }

  float ps = 0.f, pq = 0.f;
  const int h = (t >> 5) & 1;
  #pragma unroll
  for(int j=0;j<6;j++){
    int r = r0 + j;
    int a = sRO[r], b = sRO[r+1];
    float selfE = sSelfE[r];
    float mx = -3.4e38f;
    for(int e=a+lane; e<b; e+=64) mx = fmaxf(mx, sEv[e]);
    mx = fmaxf(mx, __shfl_xor(mx, 32));
    mx = fmaxf(mx, __shfl_xor(mx, 16));
    mx = fmaxf(mx, __shfl_xor(mx, 8));
    mx = fmaxf(mx, __shfl_xor(mx, 4));
    mx = fmaxf(mx, __shfl_xor(mx, 2));
    mx = fmaxf(mx, __shfl_xor(mx, 1));
    float m = fmaxf(mx, selfE);
    float ds = 0.f;
    for(int e=a+lane; e<b; e+=64){
      float z = sexp(sEv[e] - m);
      sEv[e] = z;
      ds += z;
    }
    ds += __shfl_xor(ds, 32);
    ds += __shfl_xor(ds, 16);
    ds += __shfl_xor(ds, 8);
    ds += __shfl_xor(ds, 4);
    ds += __shfl_xor(ds, 2);
    ds += __shfl_xor(ds, 1);
    float selfZ = sexp(selfE - m);
    float rden = 1.f / fmaxf(ds + selfZ, 1e-30f);
    float acc = 0.f;
    for(int e=a+h; e<b; e+=2){
      int sl = sSl[e] & 31; if(sl > 23) sl = 0;
      acc += sEv[e] * sXl[sl][c];
    }
    acc += __shfl_xor(acc, 32);
    float out = (acc + selfZ * sXl[r][c]) * rden;
    out = fmaxf(out + bv, 0.f);
    if(h == 0){
      if(use_h1) h1[((size_t)nb + r)*32 + c] = out;
      ps += out; pq += out*out;
    }
  }
  if(h == 0){ sPS[wid][c] = ps; sPQ[wid][c] = pq; }
  __syncthreads();
  if(t < 32){
    p1sum[g*32+t] = sPS[0][t]+sPS[1][t]+sPS[2][t]+sPS[3][t];
    p1sq[g*32+t]  = sPQ[0][t]+sPQ[1][t]+sPQ[2][t]+sPQ[3][t];
  }
}

// ---------------- BN stats -> affine ----------------
__global__ void k_reduce(const float* __restrict__ ps, const float* __restrict__ pq,
                         const void* __restrict__ gamma, const void* __restrict__ beta,
                         const int* __restrict__ dflag,
                         float* __restrict__ stats, int F){
  __shared__ float rs[256], rq[256];
  int f = blockIdx.x, t = threadIdx.x;
  float s=0.f, q=0.f;
  for(int g=t; g<GG; g+=256){ s += ps[g*F+f]; q += pq[g*F+f]; }
  rs[t]=s; rq[t]=q; __syncthreads();
  for(int off=128; off>0; off>>=1){
    if(t<off){ rs[t]+=rs[t+off]; rq[t]+=rq[t+off]; }
    __syncthreads();
  }
  if(t==0){
    int isf = dflag[0];
    float mu  = rs[0] * (1.f/(float)NN);
    float var = rq[0] * (1.f/(float)NN) - mu*mu;
    if(var < 0.f) var = 0.f;
    float sc  = ldf(gamma,f,isf) / sqrtf(var + 1e-5f);
    stats[f]   = sc;
    stats[F+f] = ldf(beta,f,isf) - mu*sc;
  }
}

// -------- mid-tier layer2 from stored h1, wave-local (round-3, verbatim) --------
__global__ __launch_bounds__(256, 6) void k_fused2_h1(
    const void* __restrict__ ea, const float* __restrict__ eap,
    const float* __restrict__ wb, const float* __restrict__ wq,
    const float* __restrict__ h1,
    const int* __restrict__ offs, const int* __restrict__ spack, const int* __restrict__ dflag,
    float* __restrict__ gsum2, float* __restrict__ gsq2)
{
  __shared__ __align__(16) float sEaF[CAP][16];
  __shared__ float sXl2[24][12], sXr2[24][12];
  __shared__ float sEaSum[24][17];
  __shared__ float sEv[CAP];
  __shared__ int   sSl[CAP];
  __shared__ int   sRO[25];
  __shared__ float sSelfE[24];
  __shared__ float sGS[4][8], sGQ[4][8];

  const int t = threadIdx.x;
  const int g = blockIdx.x;
  const int wid = t >> 6;
  const int lane = t & 63;
  const int isf = dflag[0];
  const int nb = g*PP;
  const int eb = offs[nb];
  int ecnt = offs[nb+24] - eb; if(ecnt < 0) ecnt = 0; if(ecnt > CAP) ecnt = CAP;

  if(t < 25){
    int v = offs[nb+t] - eb;
    if(v < 0) v = 0; if(v > CAP) v = CAP;
    sRO[t] = v;
  }
  if(eap){
    for(int i=t; i<ecnt; i+=256) sSl[i] = spack[eb+i] & 1023;
    for(int i=t; i<ecnt*4; i+=256){
      int e = i>>2, q = i&3;
      *(f4_t*)&sEaF[e][q*4] = *(const f4_t*)(eap + ((size_t)(eb+e))*16 + q*4);
    }
  } else {
    for(int i=t; i<ecnt; i+=256){
      int sp = spack[eb+i];
      sSl[i] = sp & 1023;
      u32 id = ((u32)sp) >> 10;
      if(id >= (u32)EE) id = 0;
      if(isf){
        const float* er = (const float*)ea + (size_t)id*16;
        #pragma unroll
        for(int q=0;q<4;q++) *(f4_t*)&sEaF[i][q*4] = *(const f4_t*)(er + q*4);
      } else {
        #pragma unroll
        for(int c=0;c<16;c++) sEaF[i][c] = bf2f(((const u16*)ea)[(size_t)id*16 + c]);
      }
    }
  }
  {
    int rz = wid*6;
    for(int i=lane; i<6*17; i+=64) sEaSum[rz + i/17][i%17] = 0.f;
    for(int i=lane; i<96; i+=64){
      int rl = i>>4, cc = i&15;
      int r = rz + rl;
      float s = wq[oB2P + cc];
      const float* hr = h1 + ((size_t)nb + r)*32;
      #pragma unroll
      for(int q=0;q<8;q++){
        f4_t hv = *(const f4_t*)(hr + q*4);
        s += hv[0]*wq[oW2P+(q*4+0)*16+cc] + hv[1]*wq[oW2P+(q*4+1)*16+cc]
           + hv[2]*wq[oW2P+(q*4+2)*16+cc] + hv[3]*wq[oW2P+(q*4+3)*16+cc];
      }
      if(cc < 8) sXl2[r][cc] = s; else sXr2[r][cc-8] = s;
    }
  }
  __syncthreads();

  const int r0 = wid*6;
  const int a0 = sRO[r0], a1 = sRO[r0+6];
  const int c = t & 7;
  const int eo = lane >> 3;

  float wr[16];
  #pragma unroll
  for(int k=0;k<16;k++) wr[k] = wb[oWe2 + k*8 + c];
  const float av = wb[oatt2 + c];
  const float bv = wb[obo2 + c];

  for(int base=a0; base<a1; base+=8){
    int e = base + eo;
    bool valid = (e < a1);
    int ec = valid ? e : a0;
    int sp = sSl[ec];
    int sl = sp & 31; if(sl > 23) sl = 0;
    int dl = (sp >> 5) & 31; if(dl > 23) dl = 0;
    f4_t A0 = *(const f4_t*)&sEaF[ec][0];
    f4_t A1 = *(const f4_t*)&sEaF[ec][4];
    f4_t A2 = *(const f4_t*)&sEaF[ec][8];
    f4_t A3 = *(const f4_t*)&sEaF[ec][12];
    float p = A0[0]*wr[0]+A0[1]*wr[1]+A0[2]*wr[2]+A0[3]*wr[3]
            + A1[0]*wr[4]+A1[1]*wr[5]+A1[2]*wr[6]+A1[3]*wr[7]
            + A2[0]*wr[8]+A2[1]*wr[9]+A2[2]*wr[10]+A2[3]*wr[11]
            + A3[0]*wr[12]+A3[1]*wr[13]+A3[2]*wr[14]+A3[3]*wr[15];
    if(valid){
      atomicAdd(&sEaSum[dl][c],   sEaF[ec][c]);
      atomicAdd(&sEaSum[dl][c+8], sEaF[ec][c+8]);
    }
    float v = lrelu(sXl2[sl][c] + sXr2[dl][c] + p) * av;
    v += __shfl_xor(v, 4);
    v += __shfl_xor(v, 2);
    v += __shfl_xor(v, 1);
    if(valid && c == 0) sEv[e] = v;
  }

  {
    int rr = r0 + (eo < 6 ? eo : 0);
    bool valid = (eo < 6);
    int deg = sRO[rr+1] - sRO[rr];
    float invd = 1.f / (float)(deg > 0 ? deg : 1);
    float mp = 0.f;
    #pragma unroll
    for(int k=0;k<16;k++) mp += sEaSum[rr][k] * wr[k];
    float v = lrelu(sXl2[rr][c] + sXr2[rr][c] + mp*invd) * av;
    v += __shfl_xor(v, 4);
    v += __shfl_xor(v, 2);
    v += __shfl_xor(v, 1);
    if(valid && c == 0) sSelfE[rr] = v;
  }

  float gs = 0.f, gq = 0.f;
  #pragma unroll
  for(int j=0;j<6;j++){
    int r = r0 + j;
    int a = sRO[r], b = sRO[r+1];
    float selfE = sSelfE[r];
    float mx = -3.4e38f;
    for(int e=a+lane; e<b; e+=64) mx = fmaxf(mx, sEv[e]);
    mx = fmaxf(mx, __shfl_xor(mx, 32));
    mx = fmaxf(mx, __shfl_xor(mx, 16));
    mx = fmaxf(mx, __shfl_xor(mx, 8));
    mx = fmaxf(mx, __shfl_xor(mx, 4));
    mx = fmaxf(mx, __shfl_xor(mx, 2));
    mx = fmaxf(mx, __shfl_xor(mx, 1));
    float m = fmaxf(mx, selfE);
    float ds = 0.f;
    for(int e=a+lane; e<b; e+=64){
      float z = sexp(sEv[e] - m);
      sEv[e] = z;
      ds += z;
    }
    ds += __shfl_xor(ds, 32);
    ds += __shfl_xor(ds, 16);
    ds += __shfl_xor(ds, 8);
    ds += __shfl_xor(ds, 4);
    ds += __shfl_xor(ds, 2);
    ds += __shfl_xor(ds, 1);
    float selfZ = sexp(selfE - m);
    float rden = 1.f / fmaxf(ds + selfZ, 1e-30f);
    float acc = 0.f;
    for(int e=a+eo; e<b; e+=8){
      int sl = sSl[e] & 31; if(sl > 23) sl = 0;
      acc += sEv[e] * sXl2[sl][c];
    }
    acc += __shfl_xor(acc, 8);
    acc += __shfl_xor(acc, 16);
    acc += __shfl_xor(acc, 32);
    float out = (acc + selfZ * sXl2[r][c]) * rden;
    float s = 1.f / (1.f + __expf(-(out + bv)));
    if(eo == 0){ gs += s; gq += s*s; }
  }
  if(eo == 0){ sGS[wid][c] = gs; sGQ[wid][c] = gq; }
  __syncthreads();
  if(t < 8){
    gsum2[g*8+t] = sGS[0][t]+sGS[1][t]+sGS[2][t]+sGS[3][t];
    gsq2[g*8+t]  = sGQ[0][t]+sGQ[1][t]+sGQ[2][t]+sGQ[3][t];
  }
}

// -------- fallback: recompute layer1 + layer2 (ws-lean, round-3 verbatim) --------
__global__ __launch_bounds__(256) void k_fused2_rec(
    const void* __restrict__ x, const void* __restrict__ ea,
    const float* __restrict__ wb, const float* __restrict__ stats1,
    const int* __restrict__ offs, const int* __restrict__ spack, const int* __restrict__ dflag,
    float* __restrict__ gsum2, float* __restrict__ gsq2)
{
  __shared__ float sXrow[24][76];
  __shared__ float sEaF[CAP][17];
  __shared__ __align__(16) float sXl[24][36];
  __shared__ __align__(16) float sXr[24][36];
  __shared__ __align__(16) float sOut[24][36];
  __shared__ float sH[24][33];
  __shared__ float sXl2[24][12], sXr2[24][12], sOut2[24][12];
  __shared__ float sEapSum[24][32];
  __shared__ float sEv[CAP], sEz[CAP];
  __shared__ int   sSp[CAP];
  __shared__ int   sDeg[24];
  __shared__ u32   sMaxU[24];
  __shared__ float sMaxF[24], sDen[24], sSelfZ[24];
  __shared__ float sAtt[32], sBo[32], sSc[32], sSh[32];

  const int t = threadIdx.x;
  const int g = blockIdx.x;
  const int isf = dflag[0];
  int eb = offs[g*24], ee = offs[(g+1)*24];
  if(eb < 0) eb = 0; if(eb > EE) eb = EE;
  if(ee < eb) ee = eb; if(ee > EE) ee = EE;
  int ecnt = ee - eb; if(ecnt > CAP) ecnt = CAP;

  for(int i=t; i<24*74; i+=256){
    int r = i/74, c = i%74;
    sXrow[r][c] = ldf(x, (size_t)(g*PP + r)*96 + c, isf);
  }
  for(int i=t; i<CAP; i+=256) sSp[i] = (i<ecnt) ? spack[eb+i] : 0;
  if(t < 32){ sAtt[t]=wb[oatt1+t]; sBo[t]=wb[obo1+t]; sSc[t]=stats1[t]; sSh[t]=stats1[32+t]; }
  if(t < 24){ sDeg[t]=0; sMaxU[t]=0u; sDen[t]=0.f; }
  for(int i=t; i<24*32; i+=256) sEapSum[i>>5][i&31] = 0.f;
  __syncthreads();
  for(int i=t; i<CAP*16; i+=256){
    int e = i>>4, c = i&15;
    float v = 0.f;
    if(e < ecnt){
      u32 id = ((u32)sSp[e]) >> 10;
      if(id >= (u32)EE) id = 0;
      v = ldf(ea, (size_t)id*16 + c, isf);
    }
    sEaF[e][c] = v;
  }
  __syncthreads();

  {
    int c = t & 31, rr0 = t >> 5;
    for(int r = rr0; r < 24; r += 8){
      float al = wb[obl1+c], ar = wb[obr1+c];
      for(int k=0;k<74;k++){
        float xv = sXrow[r][k];
        al += xv * wb[oWl1 + k*32 + c];
        ar += xv * wb[oWr1 + k*32 + c];
      }
      sXl[r][c] = al; sXr[r][c] = ar;
    }
  }
  __syncthreads();

  for(int e=t; e<ecnt; e+=256){
    int sp = sSp[e];
    int sl = sp & 31; if(sl > 23) sl = 0;
    int dl = (sp >> 5) & 31; if(dl > 23) dl = 0;
    float ev = 0.f;
    for(int c=0;c<32;c++){
      float p = 0.f;
      for(int k=0;k<16;k++) p += sEaF[e][k] * wb[oWe1 + k*32 + c];
      atomicAdd(&sEapSum[dl][c], p);
      ev += lrelu(sXl[sl][c] + sXr[dl][c] + p) * sAtt[c];
    }
    sEv[e] = ev;
    atomicMax(&sMaxU[dl], fkey(ev));
    atomicAdd(&sDeg[dl], 1);
  }
  __syncthreads();

  if(t < 24){
    float invd = 1.f / (float)(sDeg[t] > 0 ? sDeg[t] : 1);
    float ev = 0.f;
    for(int c=0;c<32;c++)
      ev += lrelu(sXl[t][c] + sXr[t][c] + sEapSum[t][c]*invd) * sAtt[c];
    float mxv = (sDeg[t] > 0) ? fmaxf(funkey(sMaxU[t]), ev) : ev;
    sMaxF[t] = mxv;
    float z = sexp(ev - mxv);
    sSelfZ[t] = z;
    sDen[t] = z;
  }
  __syncthreads();

  for(int e=t; e<ecnt; e+=256){
    int dl = (sSp[e]>>5)&31; if(dl > 23) dl = 0;
    float z = sexp(sEv[e] - sMaxF[dl]);
    sEz[e] = z;
    atomicAdd(&sDen[dl], z);
  }
  __syncthreads();

  for(int e=t; e<ecnt; e+=256){
    int dl = (sSp[e]>>5)&31; if(dl > 23) dl = 0;
    sEz[e] /= fmaxf(sDen[dl], 1e-30f);
  }
  if(t < 24) sSelfZ[t] /= fmaxf(sDen[t], 1e-30f);
  __syncthreads();

  for(int o=t; o<24*8; o+=256){
    int nl = o >> 3, cq = (o & 7)*4;
    float al = sSelfZ[nl];
    f4_t xv = *(const f4_t*)&sXl[nl][cq];
    f4_t r;
    #pragma unroll
    for(int j=0;j<4;j++) r[j] = al*xv[j];
    *(f4_t*)&sOut[nl][cq] = r;
  }
  __syncthreads();

  for(int o=t; o<ecnt*8; o+=256){
    int e = o >> 3, cq = (o & 7)*4;
    int sp = sSp[e];
    int sl = sp & 31; if(sl > 23) sl = 0;
    int dl = (sp >> 5) & 31; if(dl > 23) dl = 0;
    float al = sEz[e];
    f4_t xv = *(const f4_t*)&sXl[sl][cq];
    atomicAdd(&sOut[dl][cq+0], al*xv[0]);
    atomicAdd(&sOut[dl][cq+1], al*xv[1]);
    atomicAdd(&sOut[dl][cq+2], al*xv[2]);
    atomicAdd(&sOut[dl][cq+3], al*xv[3]);
  }
  __syncthreads();

  for(int i=t; i<24*32; i+=256){
    int r = i>>5, c = i&31;
    float v = fmaxf(sOut[r][c] + sBo[c], 0.f);
    sH[r][c] = v*sSc[c] + sSh[c];
  }
  __syncthreads();
  if(t < 24){ sDeg[t]=0; sMaxU[t]=0u; sDen[t]=0.f; }
  for(int i=t; i<24*8; i+=256) sEapSum[i>>3][i&7] = 0.f;
  __syncthreads();

  if(t < 24*8*2){
    int mat = t/192, rem = t%192, r = rem/8, c = rem&7;
    const float* Wm = wb + (mat ? oWr2 : oWl2);
    float s = wb[(mat ? obr2 : obl2) + c];
    for(int k=0;k<32;k++) s += sH[r][k]*Wm[k*8+c];
    if(mat) sXr2[r][c] = s; else sXl2[r][c] = s;
  }
  __syncthreads();

  for(int e=t; e<ecnt; e+=256){
    int sp = sSp[e];
    int sl = sp & 31; if(sl > 23) sl = 0;
    int dl = (sp >> 5) & 31; if(dl > 23) dl = 0;
    float ev = 0.f;
    for(int c=0;c<8;c++){
      float p = 0.f;
      for(int k=0;k<16;k++) p += sEaF[e][k] * wb[oWe2 + k*8 + c];
      atomicAdd(&sEapSum[dl][c], p);
      ev += lrelu(sXl2[sl][c] + sXr2[dl][c] + p) * wb[oatt2+c];
    }
    sEv[e] = ev;
    atomicMax(&sMaxU[dl], fkey(ev));
    atomicAdd(&sDeg[dl], 1);
  }
  __syncthreads();

  if(t < 24){
    float invd = 1.f / (float)(sDeg[t] > 0 ? sDeg[t] : 1);
    float ev = 0.f;
    for(int c=0;c<8;c++)
      ev += lrelu(sXl2[t][c] + sXr2[t][c] + sEapSum[t][c]*invd) * wb[oatt2+c];
    float mxv = (sDeg[t] > 0) ? fmaxf(funkey(sMaxU[t]), ev) : ev;
    sMaxF[t] = mxv;
    float z = sexp(ev - mxv);
    sSelfZ[t] = z;
    sDen[t] = z;
  }
  __syncthreads();

  for(int e=t; e<ecnt; e+=256){
    int dl = (sSp[e]>>5)&31; if(dl > 23) dl = 0;
    float z = sexp(sEv[e] - sMaxF[dl]);
    sEz[e] = z;
    atomicAdd(&sDen[dl], z);
  }
  __syncthreads();

  for(int e=t; e<ecnt; e+=256){
    int dl = (sSp[e]>>5)&31; if(dl > 23) dl = 0;
    sEz[e] /= fmaxf(sDen[dl], 1e-30f);
  }
  if(t < 24) sSelfZ[t] /= fmaxf(sDen[t], 1e-30f);
  __syncthreads();

  for(int o=t; o<24*8; o+=256){
    int nl = o >> 3, c = o & 7;
    sOut2[nl][c] = sSelfZ[nl] * sXl2[nl][c];
  }
  __syncthreads();

  for(int o=t; o<ecnt*8; o+=256){
    int e = o >> 3, c = o & 7;
    int sp = sSp[e];
    int sl = sp & 31; if(sl > 23) sl = 0;
    int dl = (sp >> 5) & 31; if(dl > 23) dl = 0;
    atomicAdd(&sOut2[dl][c], sEz[e]*sXl2[sl][c]);
  }
  __syncthreads();

  if(t < 8){
    float gs=0.f, gq=0.f;
    for(int nl=0; nl<24; nl++){
      float v = sOut2[nl][t] + wb[obo2+t];
      float s = 1.f / (1.f + __expf(-v));
      gs += s; gq += s*s;
    }
    gsum2[g*8+t] = gs; gsq2[g*8+t] = gq;
  }
}

// ---------------- MLP head (128 blocks x 64 threads: wider CU spread) ----------------
__global__ __launch_bounds__(64) void k_mlp(
    const float* __restrict__ gsum2, const float* __restrict__ stats2,
    const void* __restrict__ x, const int* __restrict__ dflag,
    const float* __restrict__ wb, float* __restrict__ out)
{
  __shared__ float w[1702];
  int t = threadIdx.x;
  for(int i=t; i<1702; i+=64) w[i] = wb[6048+i];
  __syncthreads();
  int g = blockIdx.x*64 + t;
  int isf = dflag[0];
  float a[30], b[32];
  for(int c=0;c<8;c++) a[c] = stats2[c]*(gsum2[(size_t)g*8+c]*(1.f/24.f)) + stats2[8+c];
  size_t xoff = (size_t)g*PP*96 + 74;
  for(int j=0;j<22;j++) a[8+j] = ldf(x, xoff+j, isf);
  for(int o=0;o<32;o++){ float s = w[960+o];  for(int i=0;i<30;i++) s += a[i]*w[i*32+o];      b[o]=fmaxf(s,0.f); }
  for(int o=0;o<16;o++){ float s = w[1504+o]; for(int i=0;i<32;i++) s += b[i]*w[992+i*16+o];  a[o]=fmaxf(s,0.f); }
  for(int o=0;o<8;o++){  float s = w[1648+o]; for(int i=0;i<16;i++) s += a[i]*w[1520+i*8+o];  b[o]=fmaxf(s,0.f); }
  for(int o=0;o<4;o++){  float s = w[1688+o]; for(int i=0;i<8;i++)  s += b[i]*w[1656+i*4+o];  a[o]=fmaxf(s,0.f); }
  for(int o=0;o<2;o++){
    float s = w[1700+o];
    for(int i=0;i<4;i++) s += a[i]*w[1692+i*2+o];
    out[(size_t)g*2+o] = s;
  }
}

extern "C" void kernel_launch(void* const* d_in, const int* in_sizes, int n_in,
                              void* d_out, int out_size, void* d_ws, size_t ws_size,
                              hipStream_t stream)
{
  (void)in_sizes; (void)n_in; (void)out_size;
  const void* x    = d_in[0];
  const int* eidx  = (const int*)d_in[1];
  const void* ea   = d_in[2];

  const int* srcA = eidx;
  const int* dstA = eidx + EE;

  constexpr size_t O_WB    = 0;
  constexpr size_t O_WQ    = 32768;
  constexpr size_t O_OFFS  = 57344;
  constexpr size_t O_CUR   = O_OFFS + (size_t)(NN+512)*4;
  constexpr size_t O_SPACK = O_CUR  + (size_t)NN*4;
  constexpr size_t O_P1S   = O_SPACK + (size_t)EE*4;
  constexpr size_t O_P1Q   = O_P1S   + (size_t)GG*32*4;
  constexpr size_t O_ST1   = O_P1Q   + (size_t)GG*32*4;
  constexpr size_t O_GS2   = O_ST1   + 256;
  constexpr size_t O_GQ2   = O_GS2   + (size_t)GG*8*4;
  constexpr size_t O_ST2   = O_GQ2   + (size_t)GG*8*4;
  constexpr size_t O_FLAG  = O_ST2   + 256;
  constexpr size_t REQUIRED_BASE = O_FLAG + 256;
  constexpr size_t O_H1    = REQUIRED_BASE;
  constexpr size_t REQUIRED_BIG = O_H1 + (size_t)NN*32*4;
  constexpr size_t O_EAP1  = REQUIRED_BIG;                       // eap: EE*16 f32 (or u16 when bf16)
  constexpr size_t REQUIRED_P     = O_EAP1 + (size_t)EE*16*4;
  constexpr size_t REQUIRED_EAP16 = O_EAP1 + (size_t)EE*16*4;

  if(ws_size < REQUIRED_BASE){
    k_zero<<<(GG*2+255)/256, 256, 0, stream>>>((float*)d_out);
    return;
  }
  const int use_h1  = (ws_size >= REQUIRED_BIG)   ? 1 : 0;
  const int use_p   = (use_h1 && ws_size >= REQUIRED_P) ? 1 : 0;
  const int use_eap = (!use_p && ws_size >= REQUIRED_EAP16) ? 1 : 0;

  char* W = (char*)d_ws;
  float* wb     = (float*)(W + O_WB);
  float* wq     = (float*)(W + O_WQ);
  int*   offs   = (int*)(W + O_OFFS);
  int*   bsum   = offs + NN + 64;
  int*   cnt    = (int*)(W + O_CUR);
  int*   cursor = (int*)(W + O_CUR);
  int*   spack  = (int*)(W + O_SPACK);
  float* p1sum  = (float*)(W + O_P1S);
  float* p1sq   = (float*)(W + O_P1Q);
  float* stats1 = (float*)(W + O_ST1);
  float* gsum2  = (float*)(W + O_GS2);
  float* gsq2   = (float*)(W + O_GQ2);
  float* stats2 = (float*)(W + O_ST2);
  int*   dflag  = (int*)(W + O_FLAG);
  float* h1     = (float*)(W + O_H1);
  void*  eap1   = (void*)(W + O_EAP1);

  hipMemsetAsync(cnt, 0, (size_t)NN*sizeof(int), stream);
  k_count  <<<EE/256, 256, 0, stream>>>(dstA, cnt);
  k_scanA  <<<192, 1024, 0, stream>>>(cnt, offs, bsum);
  k_scanB  <<<1, 256, 0, stream>>>(bsum, offs);
  k_scanC  <<<192, 1024, 0, stream>>>(offs, bsum, cursor);
  k_scatter<<<EE/256, 256, 0, stream>>>(srcA, dstA, cursor, spack);
  k_wconv  <<<8, 256, 0, stream>>>(wb, wq, dflag, (const u32*)x,
            d_in[4], d_in[5], d_in[6], d_in[7], d_in[8], d_in[9], d_in[10],
            d_in[11], d_in[12], d_in[13], d_in[14], d_in[15], d_in[16], d_in[17],
            d_in[22], d_in[23], d_in[24], d_in[25], d_in[26], d_in[27],
            d_in[28], d_in[29], d_in[30], d_in[31]);
  if(use_p){
    k_eapermB<<<EE/256, 256, 0, stream>>>(spack, offs, ea, dflag, eap1);
    k_l1stats_p<<<GG, 256, 0, stream>>>(x, eap1, wb, wq, offs, spack, dflag,
                                        p1sum, p1sq, h1);
  } else {
    if(use_eap)
      k_eaperm<<<EE/256, 256, 0, stream>>>(spack, offs, ea, dflag, (float*)eap1);
    k_l1stats<<<GG, 256, 0, stream>>>(x, ea, use_eap ? (float*)eap1 : (float*)nullptr,
                                      wb, wq, offs, spack, dflag,
                                      p1sum, p1sq, h1, use_h1);
  }
  k_reduce <<<32, 256, 0, stream>>>(p1sum, p1sq, d_in[18], d_in[19], dflag, stats1, 32);
  k_prep2  <<<1, 256, 0, stream>>>(wq, wb, stats1);
  if(use_p)
    k_fused2_p<<<GG, 256, 0, stream>>>(eap1, dflag, wb, wq, h1, offs, spack, gsum2, gsq2);
  else if(use_h1)
    k_fused2_h1<<<GG, 256, 0, stream>>>(ea, use_eap ? (float*)eap1 : (float*)nullptr,
                                        wb, wq, h1, offs, spack, dflag, gsum2, gsq2);
  else
    k_fused2_rec<<<GG, 256, 0, stream>>>(x, ea, wb, stats1, offs, spack, dflag, gsum2, gsq2);
  k_reduce <<<8, 256, 0, stream>>>(gsum2, gsq2, d_in[20], d_in[21], dflag, stats2, 8);
  k_mlp    <<<GG/64, 64, 0, stream>>>(gsum2, stats2, x, dflag, wb, (float*)d_out);
}

// Round 12
// 576.754 us; speedup vs baseline: 1.1371x; 1.0097x over previous
//
#include <hip/hip_runtime.h>

typedef unsigned short u16;
typedef unsigned int   u32;
typedef __attribute__((ext_vector_type(4))) float f4_t;
typedef __attribute__((ext_vector_type(4))) unsigned short us4_t;
typedef __attribute__((ext_vector_type(4))) unsigned int   u4_t;

#define GG 8192
#define PP 24
#define NN 196608
#define EE 786432
#define CAP 176

// ---- packed f32 weight buffer offsets (wb region) ----
#define oWl1 0
#define oWr1 2368
#define obl1 4736
#define obr1 4768
#define oWe1 4800
#define oatt1 5312
#define obo1 5344
#define oWl2 5376
#define oWr2 5632
#define obl2 5888
#define obr2 5896
#define oWe2 5904
#define oatt2 6032
#define obo2 6040
#define ofc1W 6048
#define ofc1b 7008
#define ofc2W 7040
#define ofc2b 7552
#define ofc3W 7568
#define ofc3b 7696
#define ofc4W 7704
#define ofc4b 7736
#define ooutW 7740
#define ooutb 7748

// ---- wq buffer ----
#define oW1I 0        // 76x64 interleaved W1 (rows 74,75 zero) = 4864 floats
#define oW2P 4864     // 32x16 BN-folded W2' = 512 floats
#define oB2P 5376     // 16 floats

__device__ __forceinline__ float bf2f(u16 u){
  union { u32 i; float f; } x; x.i = ((u32)u) << 16; return x.f;
}
__device__ __forceinline__ u32 fkey(float f){
  int i = __float_as_int(f);
  return (i >= 0) ? (((u32)i) | 0x80000000u) : ~((u32)i);
}
__device__ __forceinline__ float funkey(u32 k){
  u32 i = (k & 0x80000000u) ? (k & 0x7FFFFFFFu) : ~k;
  return __uint_as_float(i);
}
__device__ __forceinline__ float lrelu(float m){ return m > 0.f ? m : 0.2f*m; }
__device__ __forceinline__ float sexp(float a){ return __expf(fminf(a, 0.f)); }
__device__ __forceinline__ float ldf(const void* p, size_t i, int isf){
  return isf ? ((const float*)p)[i] : bf2f(((const u16*)p)[i]);
}

__global__ void k_zero(float* __restrict__ out){
  int i = blockIdx.x*256 + threadIdx.x;
  if(i < GG*2) out[i] = 0.f;
}

// ---------------- per-NODE bucketing ----------------
__global__ void k_count(const int* __restrict__ dst, int* __restrict__ cnt){
  int e = blockIdx.x*256 + threadIdx.x;
  if(e < EE){
    u32 d = (u32)dst[e];
    if(d < (u32)NN) atomicAdd(&cnt[d], 1);
  }
}

__global__ void k_scanA(const int* __restrict__ cnt, int* __restrict__ offs,
                        int* __restrict__ bsum){
  __shared__ int part[1024];
  int t = threadIdx.x;
  int i = blockIdx.x*1024 + t;
  int c = cnt[i];
  part[t] = c; __syncthreads();
  for(int off=1; off<1024; off<<=1){
    int v = (t>=off) ? part[t-off] : 0;
    __syncthreads();
    part[t] += v;
    __syncthreads();
  }
  offs[i] = part[t] - c;
  if(t==1023) bsum[blockIdx.x] = part[1023];
}

__global__ void k_scanB(int* __restrict__ bsum, int* __restrict__ offs){
  __shared__ int part[256];
  int t = threadIdx.x;
  int c = (t < 192) ? bsum[t] : 0;
  part[t] = c; __syncthreads();
  for(int off=1; off<256; off<<=1){
    int v = (t>=off) ? part[t-off] : 0;
    __syncthreads();
    part[t] += v;
    __syncthreads();
  }
  if(t < 192) bsum[t] = part[t] - c;
  if(t == 255) offs[NN] = part[255];
}

__global__ void k_scanC(int* __restrict__ offs, const int* __restrict__ bsum,
                        int* __restrict__ cursor){
  int t = threadIdx.x;
  int i = blockIdx.x*1024 + t;
  int v = offs[i] + bsum[blockIdx.x];
  offs[i] = v;
  cursor[i] = v;
}

// pack: sl(5b) | dl(5b)<<5 | edge_id(20b)<<10 ; sorted by dst node
__global__ void k_scatter(const int* __restrict__ src, const int* __restrict__ dst,
                          int* __restrict__ cursor, int* __restrict__ spack){
  int e = blockIdx.x*256 + threadIdx.x;
  if(e < EE){
    u32 d = (u32)dst[e];
    if(d >= (u32)NN) return;
    int g = d / PP;
    int pos = atomicAdd(&cursor[d], 1);
    if((u32)pos < (u32)EE){
      int sl = src[e] - g*PP;
      if((u32)sl > 23u) sl = 0;
      spack[pos] = sl | ((int)(d - g*PP) << 5) | (e << 10);
    }
  }
}

// ---------- mid tier: permute ea into sorted order, f32 16-wide ----------
__global__ void k_eaperm(const int* __restrict__ spack, const int* __restrict__ offs,
                         const void* __restrict__ ea, const int* __restrict__ dflag,
                         float* __restrict__ eap){
  int i = blockIdx.x*256 + threadIdx.x;
  if(i >= EE) return;
  if(i >= offs[NN]) return;
  int isf = dflag[0];
  u32 id = ((u32)spack[i]) >> 10;
  if(id >= (u32)EE) id = 0;
  float* o = eap + (size_t)i*16;
  if(isf){
    const float* er = (const float*)ea + (size_t)id*16;
    #pragma unroll
    for(int q=0;q<4;q++) *(f4_t*)(o + q*4) = *(const f4_t*)(er + q*4);
  } else {
    const u16* er = (const u16*)ea + (size_t)id*16;
    #pragma unroll
    for(int c=0;c<16;c++) o[c] = bf2f(er[c]);
  }
}

// ---------- p tier: permute ea in INPUT dtype (lossless). No p2 materialization:
// fused2_p recomputes ea@We2 from this L2-warm stream (128 MACs/edge, trivial). ----------
__global__ void k_eapermB(const int* __restrict__ spack, const int* __restrict__ offs,
                          const void* __restrict__ ea, const int* __restrict__ dflag,
                          void* __restrict__ eap){
  int i = blockIdx.x*256 + threadIdx.x;
  if(i >= EE) return;
  if(i >= offs[NN]) return;
  int isf = dflag[0];
  u32 id = ((u32)spack[i]) >> 10;
  if(id >= (u32)EE) id = 0;
  if(isf){
    const float* er = (const float*)ea + (size_t)id*16;
    float* o = (float*)eap + (size_t)i*16;
    #pragma unroll
    for(int q=0;q<4;q++) *(f4_t*)(o + q*4) = *(const f4_t*)(er + q*4);
  } else {
    const u4_t* s4 = (const u4_t*)((const u16*)ea + (size_t)id*16);
    u4_t* o4 = (u4_t*)((u16*)eap + (size_t)i*16);
    o4[0] = s4[0];
    o4[1] = s4[1];
  }
}

// ---------- fused dtype-detect + weight conversion (8 blocks) ----------
__global__ void k_wconv(float* __restrict__ wb, float* __restrict__ wq, int* __restrict__ dflag,
    const u32* __restrict__ xw,
    const void* Wl1, const void* bl1, const void* Wr1, const void* br1,
    const void* We1, const void* att1, const void* bo1,
    const void* Wl2, const void* bl2, const void* Wr2, const void* br2,
    const void* We2, const void* att2, const void* bo2,
    const void* f1W, const void* f1b, const void* f2W, const void* f2b,
    const void* f3W, const void* f3b, const void* f4W, const void* f4b,
    const void* oW,  const void* ob)
{
  __shared__ u32 mx[256];
  int t = threadIdx.x;
  int bid = blockIdx.x;
  u32 m = 0;
  for(int i=t; i<2048; i+=256){
    u32 e = (xw[i] >> 7) & 0xFFu;
    m = m > e ? m : e;
  }
  mx[t] = m; __syncthreads();
  for(int off=128; off>0; off>>=1){
    if(t<off) mx[t] = mx[t] > mx[t+off] ? mx[t] : mx[t+off];
    __syncthreads();
  }
  int isf = (mx[0] > 140u) ? 1 : 0;
  if(t==0 && bid==0) dflag[0] = isf;
  const int stp = 8*256;
  #define CP(off,src,len) for(int i=bid*256+t;i<(len);i+=stp) wb[(off)+i]=ldf(src,i,isf);
  CP(oWl1,Wl1,2368) CP(oWr1,Wr1,2368) CP(obl1,bl1,32) CP(obr1,br1,32)
  CP(oWe1,We1,512)  CP(oatt1,att1,32) CP(obo1,bo1,32)
  CP(oWl2,Wl2,256)  CP(oWr2,Wr2,256)  CP(obl2,bl2,8)  CP(obr2,br2,8)
  CP(oWe2,We2,128)  CP(oatt2,att2,8)  CP(obo2,bo2,8)
  CP(ofc1W,f1W,960) CP(ofc1b,f1b,32)  CP(ofc2W,f2W,512) CP(ofc2b,f2b,16)
  CP(ofc3W,f3W,128) CP(ofc3b,f3b,8)   CP(ofc4W,f4W,32)  CP(ofc4b,f4b,4)
  CP(ooutW,oW,8)    CP(ooutb,ob,2)
  #undef CP
  for(int i=bid*256+t; i<76*64; i+=stp){
    int k = i>>6, cc = i&63, mat = cc>>5, c = cc&31;
    wq[oW1I + i] = (k < 74) ? ldf(mat ? Wr1 : Wl1, k*32 + c, isf) : 0.f;
  }
}

// ---------- BN-fold for layer 2 ----------
__global__ void k_prep2(float* __restrict__ wq, const float* __restrict__ wb,
                        const float* __restrict__ stats1){
  int t = threadIdx.x;
  for(int i=t; i<512; i+=256){
    int k = i>>4, cc = i&15, mat = cc>>3, c = cc&7;
    wq[oW2P + i] = stats1[k] * wb[(mat ? oWr2 : oWl2) + k*8 + c];
  }
  if(t < 16){
    int mat = t>>3, c = t&7;
    float s = wb[(mat ? obr2 : obl2) + c];
    for(int k=0;k<32;k++) s += stats1[32+k] * wb[(mat ? oWr2 : oWl2) + k*8 + c];
    wq[oB2P + t] = s;
  }
}

// ======== p-tier pass 1: rows parallel, p1 computed into LDS (not HBM) ========
// LDS ~40 KB -> 4 blocks/CU. Config measured 195-198 us across rounds 6/9/10/11;
// trimmed-LDS and in-kernel-gather variants both measured slower (268 / 303 us).
// Only change vs round 11: p1sum/p1sq written in TRANSPOSED [32][GG] layout so
// k_reduce reads coalesced (scattered 4-B stores here are L2-absorbed).
__global__ __launch_bounds__(256, 4) void k_l1stats_p(
    const void* __restrict__ x, const void* __restrict__ eap,
    const float* __restrict__ wb, const float* __restrict__ wq,
    const int* __restrict__ offs, const int* __restrict__ spack, const int* __restrict__ dflag,
    float* __restrict__ p1sum, float* __restrict__ p1sq,
    float* __restrict__ h1)
{
  __shared__ __align__(16) float sP[CAP][36];    // ea@We1 per edge (cols 0..31)
  __shared__ __align__(16) float sXl[24][36];
  __shared__ __align__(16) float sXr[24][36];
  __shared__ __align__(16) float sPS[24][32];
  __shared__ __align__(16) float sPQ[24][32];
  __shared__ float sEv[CAP];
  __shared__ int   sSl[CAP];
  __shared__ int   sRO[25];

  const int t = threadIdx.x;
  const int g = blockIdx.x;
  const int isf = dflag[0];
  const int nb = g*PP;
  const int eb = offs[nb];
  int ecnt = offs[nb+24] - eb;
  if(ecnt < 0) ecnt = 0; if(ecnt > CAP) ecnt = CAP;

  if(t < 25){
    int v = offs[nb+t] - eb;
    if(v < 0) v = 0; if(v > CAP) v = CAP;
    sRO[t] = v;
  }
  for(int i=t; i<ecnt; i+=256){
    int sl = spack[eb+i] & 31; if(sl > 23) sl = 0;
    sSl[i] = sl;
  }

  // ---- phase A1: projection xl/xr (wave w -> rows 6w..6w+5) ----
  {
    const int c = t & 31, mat = (t>>5)&1, w = t>>6, cc = t&63;
    const float* gW = wq + oW1I;
    float bi = wb[(mat ? obr1 : obl1) + c];
    float acc[6];
    #pragma unroll
    for(int j=0;j<6;j++) acc[j] = bi;
    if(isf){
      const float* xr0 = (const float*)x + (size_t)(nb + w*6)*96;
      for(int kb=0; kb<19; kb++){
        float w0 = gW[(kb*4+0)*64 + cc];
        float w1 = gW[(kb*4+1)*64 + cc];
        float w2 = gW[(kb*4+2)*64 + cc];
        float w3 = gW[(kb*4+3)*64 + cc];
        #pragma unroll
        for(int j=0;j<6;j++){
          f4_t xv = *(const f4_t*)(xr0 + (size_t)j*96 + kb*4);
          acc[j] += xv[0]*w0 + xv[1]*w1 + xv[2]*w2 + xv[3]*w3;
        }
      }
    } else {
      const u16* xr0 = (const u16*)x + (size_t)(nb + w*6)*96;
      for(int kb=0; kb<19; kb++){
        float w0 = gW[(kb*4+0)*64 + cc];
        float w1 = gW[(kb*4+1)*64 + cc];
        float w2 = gW[(kb*4+2)*64 + cc];
        float w3 = gW[(kb*4+3)*64 + cc];
        #pragma unroll
        for(int j=0;j<6;j++){
          us4_t xv = *(const us4_t*)(xr0 + (size_t)j*96 + kb*4);
          acc[j] += bf2f(xv[0])*w0 + bf2f(xv[1])*w1 + bf2f(xv[2])*w2 + bf2f(xv[3])*w3;
        }
      }
    }
    if(mat){
      #pragma unroll
      for(int j=0;j<6;j++) sXr[w*6+j][c] = acc[j];
    } else {
      #pragma unroll
      for(int j=0;j<6;j++) sXl[w*6+j][c] = acc[j];
    }
  }

  // ---- phase A2: p1 into LDS. task (e, q): cols q*4..q*4+3 of edge e ----
  for(int i=t; i<ecnt*8; i+=256){
    int e = i>>3, q = i&7;
    float ev[16];
    if(isf){
      const float* er = (const float*)eap + (size_t)(eb+e)*16;  // 64-B row, 8 tasks share
      #pragma unroll
      for(int qq=0;qq<4;qq++){
        f4_t v = *(const f4_t*)(er + qq*4);
        ev[qq*4+0]=v[0]; ev[qq*4+1]=v[1]; ev[qq*4+2]=v[2]; ev[qq*4+3]=v[3];
      }
    } else {
      const u16* er = (const u16*)eap + (size_t)(eb+e)*16;      // 32-B row, 8 tasks share
      #pragma unroll
      for(int qq=0;qq<4;qq++){
        us4_t v = *(const us4_t*)(er + qq*4);
        ev[qq*4+0]=bf2f(v[0]); ev[qq*4+1]=bf2f(v[1]); ev[qq*4+2]=bf2f(v[2]); ev[qq*4+3]=bf2f(v[3]);
      }
    }
    float s0=0.f, s1=0.f, s2=0.f, s3=0.f;
    #pragma unroll
    for(int k=0;k<16;k++){
      f4_t w = *(const f4_t*)(wb + oWe1 + k*32 + q*4);
      s0 += ev[k]*w[0]; s1 += ev[k]*w[1]; s2 += ev[k]*w[2]; s3 += ev[k]*w[3];
    }
    f4_t r; r[0]=s0; r[1]=s1; r[2]=s2; r[3]=s3;
    *(f4_t*)&sP[e][q*4] = r;                     // e*144 + q*16 bytes: 16-B aligned
  }
  __syncthreads();   // barrier 1

  if(t < 192){       // 8 lanes per row, 24 rows in parallel
    const int r = t >> 3, sub = t & 7;
    const int a = sRO[r], b = sRO[r+1];
    const int deg = b - a;
    const float* att = wb + oatt1;

    // e-values: lane owns edges a+sub, a+sub+8, ... ; p1 from LDS
    float emax = -3.4e38f;
    for(int e=a+sub; e<b; e+=8){
      int sl = sSl[e];
      float ev = 0.f;
      #pragma unroll
      for(int q=0;q<8;q++){
        f4_t pv  = *(const f4_t*)&sP[e][q*4];
        f4_t xlv = *(const f4_t*)&sXl[sl][q*4];
        f4_t xrv = *(const f4_t*)&sXr[r][q*4];
        ev += att[q*4+0]*lrelu(xlv[0]+xrv[0]+pv[0]);
        ev += att[q*4+1]*lrelu(xlv[1]+xrv[1]+pv[1]);
        ev += att[q*4+2]*lrelu(xlv[2]+xrv[2]+pv[2]);
        ev += att[q*4+3]*lrelu(xlv[3]+xrv[3]+pv[3]);
      }
      sEv[e] = ev;
      emax = fmaxf(emax, ev);
    }
    emax = fmaxf(emax, __shfl_xor(emax, 1));
    emax = fmaxf(emax, __shfl_xor(emax, 2));
    emax = fmaxf(emax, __shfl_xor(emax, 4));

    // self-loop via linearity: mean of p1 over edges; lane owns cols sub*4..+3
    float m0=0.f, m1=0.f, m2=0.f, m3=0.f;
    for(int e=a; e<b; ++e){
      f4_t pv = *(const f4_t*)&sP[e][sub*4];     // banks (e*4+sub*4)%32: conflict-free
      m0 += pv[0]; m1 += pv[1]; m2 += pv[2]; m3 += pv[3];
    }
    float invd = 1.f / (float)(deg > 0 ? deg : 1);
    float sv;
    {
      int c0 = sub*4;
      sv  = att[c0+0]*lrelu(sXl[r][c0+0] + sXr[r][c0+0] + m0*invd);
      sv += att[c0+1]*lrelu(sXl[r][c0+1] + sXr[r][c0+1] + m1*invd);
      sv += att[c0+2]*lrelu(sXl[r][c0+2] + sXr[r][c0+2] + m2*invd);
      sv += att[c0+3]*lrelu(sXl[r][c0+3] + sXr[r][c0+3] + m3*invd);
    }
    sv += __shfl_xor(sv, 1);
    sv += __shfl_xor(sv, 2);
    sv += __shfl_xor(sv, 4);

    // softmax (z in place in sEv)
    float m = fmaxf(emax, sv);
    float ssum = 0.f;
    for(int e=a+sub; e<b; e+=8){
      float z = sexp(sEv[e] - m);
      sEv[e] = z;
      ssum += z;
    }
    ssum += __shfl_xor(ssum, 1);
    ssum += __shfl_xor(ssum, 2);
    ssum += __shfl_xor(ssum, 4);
    float selfZ = sexp(sv - m);
    float rden = 1.f / fmaxf(ssum + selfZ, 1e-30f);

    // aggregation: lane owns cols sub*4..+3
    float a0=0.f, a1=0.f, a2=0.f, a3=0.f;
    for(int e=a; e<b; ++e){
      float z = sEv[e];
      f4_t xlv = *(const f4_t*)&sXl[sSl[e]][sub*4];
      a0 += z*xlv[0]; a1 += z*xlv[1]; a2 += z*xlv[2]; a3 += z*xlv[3];
    }
    f4_t xself = *(const f4_t*)&sXl[r][sub*4];
    f4_t outv, sqv;
    {
      float o;
      o = (a0 + selfZ*xself[0]) * rden; o = fmaxf(o + wb[obo1+sub*4+0], 0.f); outv[0]=o; sqv[0]=o*o;
      o = (a1 + selfZ*xself[1]) * rden; o = fmaxf(o + wb[obo1+sub*4+1], 0.f); outv[1]=o; sqv[1]=o*o;
      o = (a2 + selfZ*xself[2]) * rden; o = fmaxf(o + wb[obo1+sub*4+2], 0.f); outv[2]=o; sqv[2]=o*o;
      o = (a3 + selfZ*xself[3]) * rden; o = fmaxf(o + wb[obo1+sub*4+3], 0.f); outv[3]=o; sqv[3]=o*o;
    }
    *(f4_t*)&h1[((size_t)nb + r)*32 + sub*4] = outv;
    *(f4_t*)&sPS[r][sub*4] = outv;
    *(f4_t*)&sPQ[r][sub*4] = sqv;
  }
  __syncthreads();   // barrier 2
  if(t < 32){
    float s=0.f, q=0.f;
    #pragma unroll
    for(int r=0;r<24;r++){ s += sPS[r][t]; q += sPQ[r][t]; }
    p1sum[(size_t)t*GG + g] = s;   // transposed [32][GG]: k_reduce reads coalesced
    p1sq [(size_t)t*GG + g] = q;
  }
}

// ======== p-tier pass 2: layer2 from h1; p2 recomputed into LDS from eap ========
__global__ __launch_bounds__(256, 6) void k_fused2_p(
    const void* __restrict__ eap, const int* __restrict__ dflag,
    const float* __restrict__ wb, const float* __restrict__ wq,
    const float* __restrict__ h1,
    const int* __restrict__ offs, const int* __restrict__ spack,
    float* __restrict__ gsum2, float* __restrict__ gsq2)
{
  __shared__ __align__(16) float sP2[CAP][12];   // ea@We2 tile; pad-12 rotates banks
  __shared__ float sXl2[24][13];
  __shared__ float sXr2[24][13];
  __shared__ float sEv[CAP];
  __shared__ int   sSl[CAP];
  __shared__ int   sRO[25];
  __shared__ float sGS[24][8];
  __shared__ float sGQ[24][8];

  const int t = threadIdx.x;
  const int g = blockIdx.x;
  const int wid = t >> 6;
  const int lane = t & 63;
  const int isf = dflag[0];
  const int nb = g*PP;
  const int eb = offs[nb];
  int ecnt = offs[nb+24] - eb;
  if(ecnt < 0) ecnt = 0; if(ecnt > CAP) ecnt = CAP;

  if(t < 25){
    int v = offs[nb+t] - eb;
    if(v < 0) v = 0; if(v > CAP) v = CAP;
    sRO[t] = v;
  }
  for(int i=t; i<ecnt; i+=256){
    int sl = spack[eb+i] & 31; if(sl > 23) sl = 0;
    sSl[i] = sl;
  }
  // stage p2 tile: recompute ea@We2 from the (L2-warm) permuted ea stream.
  for(int i=t; i<ecnt*2; i+=256){
    int e = i>>1, half = i&1;
    float eav[16];
    if(isf){
      const float* er = (const float*)eap + (size_t)(eb+e)*16;
      #pragma unroll
      for(int qq=0;qq<4;qq++){
        f4_t v = *(const f4_t*)(er + qq*4);
        eav[qq*4+0]=v[0]; eav[qq*4+1]=v[1]; eav[qq*4+2]=v[2]; eav[qq*4+3]=v[3];
      }
    } else {
      const u16* er = (const u16*)eap + (size_t)(eb+e)*16;
      #pragma unroll
      for(int qq=0;qq<4;qq++){
        us4_t v = *(const us4_t*)(er + qq*4);
        eav[qq*4+0]=bf2f(v[0]); eav[qq*4+1]=bf2f(v[1]); eav[qq*4+2]=bf2f(v[2]); eav[qq*4+3]=bf2f(v[3]);
      }
    }
    int c = half*4;
    float s0=0.f, s1=0.f, s2=0.f, s3=0.f;
    #pragma unroll
    for(int k=0;k<16;k++){
      f4_t w = *(const f4_t*)(wb + oWe2 + k*8 + c);
      s0 += eav[k]*w[0]; s1 += eav[k]*w[1]; s2 += eav[k]*w[2]; s3 += eav[k]*w[3];
    }
    f4_t r; r[0]=s0; r[1]=s1; r[2]=s2; r[3]=s3;
    *(f4_t*)&sP2[e][half*4] = r;     // e*48 + half*16 bytes: 16-B aligned
  }
  // projection xl2/xr2 (BN folded): wave wid computes rows 6*wid..6*wid+5
  {
    int rz = wid*6;
    for(int i=lane; i<96; i+=64){
      int rl = i>>4, cc = i&15;
      int r = rz + rl;
      float s = wq[oB2P + cc];
      const float* hr = h1 + ((size_t)nb + r)*32;
      #pragma unroll
      for(int q=0;q<8;q++){
        f4_t hv = *(const f4_t*)(hr + q*4);
        s += hv[0]*wq[oW2P+(q*4+0)*16+cc] + hv[1]*wq[oW2P+(q*4+1)*16+cc]
           + hv[2]*wq[oW2P+(q*4+2)*16+cc] + hv[3]*wq[oW2P+(q*4+3)*16+cc];
      }
      if(cc < 8) sXl2[r][cc] = s; else sXr2[r][cc-8] = s;
    }
  }
  __syncthreads();   // barrier 1

  if(t < 192){
    const int r = t >> 3, sub = t & 7;
    const int a = sRO[r], b = sRO[r+1];
    const int deg = b - a;
    const float* att2 = wb + oatt2;

    float emax = -3.4e38f;
    for(int e=a+sub; e<b; e+=8){
      int sl = sSl[e];
      f4_t q0 = *(const f4_t*)&sP2[e][0];
      f4_t q1 = *(const f4_t*)&sP2[e][4];
      float ev = 0.f;
      #pragma unroll
      for(int j=0;j<4;j++) ev += att2[j]  *lrelu(sXl2[sl][j]   + sXr2[r][j]   + q0[j]);
      #pragma unroll
      for(int j=0;j<4;j++) ev += att2[4+j]*lrelu(sXl2[sl][4+j] + sXr2[r][4+j] + q1[j]);
      sEv[e] = ev;
      emax = fmaxf(emax, ev);
    }
    emax = fmaxf(emax, __shfl_xor(emax, 1));
    emax = fmaxf(emax, __shfl_xor(emax, 2));
    emax = fmaxf(emax, __shfl_xor(emax, 4));

    // self-loop via mean p2 (LDS); lane owns col sub
    float mpc = 0.f;
    for(int e=a; e<b; ++e)
      mpc += sP2[e][sub];
    float invd = 1.f / (float)(deg > 0 ? deg : 1);
    float sv = att2[sub]*lrelu(sXl2[r][sub] + sXr2[r][sub] + mpc*invd);
    sv += __shfl_xor(sv, 1);
    sv += __shfl_xor(sv, 2);
    sv += __shfl_xor(sv, 4);

    float m = fmaxf(emax, sv);
    float ssum = 0.f;
    for(int e=a+sub; e<b; e+=8){
      float z = sexp(sEv[e] - m);
      sEv[e] = z;
      ssum += z;
    }
    ssum += __shfl_xor(ssum, 1);
    ssum += __shfl_xor(ssum, 2);
    ssum += __shfl_xor(ssum, 4);
    float selfZ = sexp(sv - m);
    float rden = 1.f / fmaxf(ssum + selfZ, 1e-30f);

    float acc = 0.f;
    for(int e=a; e<b; ++e)
      acc += sEv[e] * sXl2[sSl[e]][sub];
    float o = (acc + selfZ*sXl2[r][sub]) * rden;
    float s = 1.f / (1.f + __expf(-(o + wb[obo2+sub])));
    sGS[r][sub] = s;
    sGQ[r][sub] = s*s;
  }
  __syncthreads();   // barrier 2
  if(t < 8){
    float gs=0.f, gq=0.f;
    #pragma unroll
    for(int r=0;r<24;r++){ gs += sGS[r][t]; gq += sGQ[r][t]; }
    gsum2[g*8+t] = gs; gsq2[g*8+t] = gq;
  }
}

// ======== mid tier (round-3) kernels, fallback (p1sum write transposed too) ========
__global__ __launch_bounds__(256, 6) void k_l1stats(
    const void* __restrict__ x, const void* __restrict__ ea, const float* __restrict__ eap,
    const float* __restrict__ wb, const float* __restrict__ wq,
    const int* __restrict__ offs, const int* __restrict__ spack, const int* __restrict__ dflag,
    float* __restrict__ p1sum, float* __restrict__ p1sq,
    float* __restrict__ h1, int use_h1)
{
  __shared__ __align__(16) float sEaF[CAP][16];
  __shared__ __align__(16) float sXl[24][36];
  __shared__ float sXr[24][33];
  __shared__ float sEaSum[24][17];
  __shared__ float sEv[CAP];
  __shared__ int   sSl[CAP];
  __shared__ int   sRO[25];
  __shared__ float sSelfE[24];
  __shared__ float sPS[4][32], sPQ[4][32];

  const int t = threadIdx.x;
  const int g = blockIdx.x;
  const int wid = t >> 6;
  const int lane = t & 63;
  const int isf = dflag[0];
  const int nb = g*PP;
  const int eb = offs[nb];
  int ecnt = offs[nb+24] - eb; if(ecnt < 0) ecnt = 0; if(ecnt > CAP) ecnt = CAP;

  if(t < 25){
    int v = offs[nb+t] - eb;
    if(v < 0) v = 0; if(v > CAP) v = CAP;
    sRO[t] = v;
  }
  if(eap){
    for(int i=t; i<ecnt; i+=256) sSl[i] = spack[eb+i] & 1023;
    for(int i=t; i<ecnt*4; i+=256){
      int e = i>>2, q = i&3;
      *(f4_t*)&sEaF[e][q*4] = *(const f4_t*)(eap + ((size_t)(eb+e))*16 + q*4);
    }
  } else {
    for(int i=t; i<ecnt; i+=256){
      int sp = spack[eb+i];
      sSl[i] = sp & 1023;
      u32 id = ((u32)sp) >> 10;
      if(id >= (u32)EE) id = 0;
      if(isf){
        const float* er = (const float*)ea + (size_t)id*16;
        #pragma unroll
        for(int q=0;q<4;q++) *(f4_t*)&sEaF[i][q*4] = *(const f4_t*)(er + q*4);
      } else {
        #pragma unroll
        for(int c=0;c<16;c++) sEaF[i][c] = bf2f(((const u16*)ea)[(size_t)id*16 + c]);
      }
    }
  }
  {
    int rz = wid*6;
    for(int i=lane; i<6*17; i+=64) sEaSum[rz + i/17][i%17] = 0.f;
  }

  {
    const int c = t & 31, mat = (t>>5)&1, w = wid, cc = t&63;
    const float* gW = wq + oW1I;
    float bi = wb[(mat ? obr1 : obl1) + c];
    float acc[6];
    #pragma unroll
    for(int j=0;j<6;j++) acc[j] = bi;
    if(isf){
      const float* xr0 = (const float*)x + (size_t)(nb + w*6)*96;
      for(int kb=0; kb<19; kb++){
        float w0 = gW[(kb*4+0)*64 + cc];
        float w1 = gW[(kb*4+1)*64 + cc];
        float w2 = gW[(kb*4+2)*64 + cc];
        float w3 = gW[(kb*4+3)*64 + cc];
        #pragma unroll
        for(int j=0;j<6;j++){
          f4_t xv = *(const f4_t*)(xr0 + (size_t)j*96 + kb*4);
          acc[j] += xv[0]*w0 + xv[1]*w1 + xv[2]*w2 + xv[3]*w3;
        }
      }
    } else {
      const u16* xr0 = (const u16*)x + (size_t)(nb + w*6)*96;
      for(int kb=0; kb<19; kb++){
        float w0 = gW[(kb*4+0)*64 + cc];
        float w1 = gW[(kb*4+1)*64 + cc];
        float w2 = gW[(kb*4+2)*64 + cc];
        float w3 = gW[(kb*4+3)*64 + cc];
        #pragma unroll
        for(int j=0;j<6;j++){
          us4_t xv = *(const us4_t*)(xr0 + (size_t)j*96 + kb*4);
          acc[j] += bf2f(xv[0])*w0 + bf2f(xv[1])*w1 + bf2f(xv[2])*w2 + bf2f(xv[3])*w3;
        }
      }
    }
    if(mat){
      #pragma unroll
      for(int j=0;j<6;j++) sXr[w*6+j][c] = acc[j];
    } else {
      #pragma unroll
      for(int j=0;j<6;j++) sXl[w*6+j][c] = acc[j];
    }
  }
  __syncthreads();

  const int r0 = wid*6;
  const int a0 = sRO[r0], a1 = sRO[r0+6];
  const int c = t & 31, eo = (t>>5)&1;

  float wr[16];
  #pragma unroll
  for(int k=0;k<16;k++) wr[k] = wb[oWe1 + k*32 + c];
  const float av = wb[oatt1 + c];
  const float bv = wb[obo1 + c];

  for(int base=a0; base<a1; base+=2){
    int e = base + eo;
    bool valid = (e < a1);
    int ec = valid ? e : a0;
    int sp = sSl[ec];
    int sl = sp & 31; if(sl > 23) sl = 0;
    int dl = (sp >> 5) & 31; if(dl > 23) dl = 0;
    f4_t A0 = *(const f4_t*)&sEaF[ec][0];
    f4_t A1 = *(const f4_t*)&sEaF[ec][4];
    f4_t A2 = *(const f4_t*)&sEaF[ec][8];
    f4_t A3 = *(const f4_t*)&sEaF[ec][12];
    float p = A0[0]*wr[0]+A0[1]*wr[1]+A0[2]*wr[2]+A0[3]*wr[3]
            + A1[0]*wr[4]+A1[1]*wr[5]+A1[2]*wr[6]+A1[3]*wr[7]
            + A2[0]*wr[8]+A2[1]*wr[9]+A2[2]*wr[10]+A2[3]*wr[11]
            + A3[0]*wr[12]+A3[1]*wr[13]+A3[2]*wr[14]+A3[3]*wr[15];
    if(valid && c < 16) atomicAdd(&sEaSum[dl][c], sEaF[ec][c]);
    float v = lrelu(sXl[sl][c] + sXr[dl][c] + p) * av;
    v += __shfl_xor(v, 16);
    v += __shfl_xor(v, 8);
    v += __shfl_xor(v, 4);
    v += __shfl_xor(v, 2);
    v += __shfl_xor(v, 1);
    if(valid && c == 0) sEv[e] = v;
  }

  #pragma unroll
  for(int rp=0; rp<3; rp++){
    int r = r0 + rp*2 + eo;
    int deg = sRO[r+1] - sRO[r];
    float invd = 1.f / (float)(deg > 0 ? deg : 1);
    float mp = 0.f;
    #pragma unroll
    for(int k=0;k<16;k++) mp += sEaSum[r][k] * wr[k];
    float v = lrelu(sXl[r][c] + sXr[r][c] + mp*invd) * av;
    v += __shfl_xor(v, 16);
    v += __shfl_xor(v, 8);
    v += __shfl_xor(v, 4);
    v += __shfl_xor(v, 2);
    v += __shfl_xor(v, 1);
    if(c == 0) sSelfE[r] = v;
  }

  float ps = 0.f, pq = 0.f;
  const int h = (t >> 5) & 1;
  #pragma unroll
  for(int j=0;j<6;j++){
    int r = r0 + j;
    int a = sRO[r], b = sRO[r+1];
    float selfE = sSelfE[r];
    float mx = -3.4e38f;
    for(int e=a+lane; e<b; e+=64) mx = fmaxf(mx, sEv[e]);
    mx = fmaxf(mx, __shfl_xor(mx, 32));
    mx = fmaxf(mx, __shfl_xor(mx, 16));
    mx = fmaxf(mx, __shfl_xor(mx, 8));
    mx = fmaxf(mx, __shfl_xor(mx, 4));
    mx = fmaxf(mx, __shfl_xor(mx, 2));
    mx = fmaxf(mx, __shfl_xor(mx, 1));
    float m = fmaxf(mx, selfE);
    float ds = 0.f;
    for(int e=a+lane; e<b; e+=64){
      float z = sexp(sEv[e] - m);
      sEv[e] = z;
      ds += z;
    }
    ds += __shfl_xor(ds, 32);
    ds += __shfl_xor(ds, 16);
    ds += __shfl_xor(ds, 8);
    ds += __shfl_xor(ds, 4);
    ds += __shfl_xor(ds, 2);
    ds += __shfl_xor(ds, 1);
    float selfZ = sexp(selfE - m);
    float rden = 1.f / fmaxf(ds + selfZ, 1e-30f);
    float acc = 0.f;
    for(int e=a+h; e<b; e+=2){
      int sl = sSl[e] & 31; if(sl > 23) sl = 0;
      acc += sEv[e] * sXl[sl][c];
    }
    acc += __shfl_xor(acc, 32);
    float out = (acc + selfZ * sXl[r][c]) * rden;
    out = fmaxf(out + bv, 0.f);
    if(h == 0){
      if(use_h1) h1[((size_t)nb + r)*32 + c] = out;
      ps += out; pq += out*out;
    }
  }
  if(h == 0){ sPS[wid][c] = ps; sPQ[wid][c] = pq; }
  __syncthreads();
  if(t < 32){
    p1sum[(size_t)t*GG + g] = sPS[0][t]+sPS[1][t]+sPS[2][t]+sPS[3][t];
    p1sq [(size_t)t*GG + g] = sPQ[0][t]+sPQ[1][t]+sPQ[2][t]+sPQ[3][t];
  }
}

// ---------------- BN stats -> affine ----------------
// tr=1: ps/pq laid out [F][GG] (coalesced reads). tr=0: legacy [GG][F].
__global__ void k_reduce(const float* __restrict__ ps, const float* __restrict__ pq,
                         const void* __restrict__ gamma, const void* __restrict__ beta,
                         const int* __restrict__ dflag,
                         float* __restrict__ stats, int F, int tr){
  __shared__ float rs[256], rq[256];
  int f = blockIdx.x, t = threadIdx.x;
  float s=0.f, q=0.f;
  if(tr){
    const float* psf = ps + (size_t)f*GG;
    const float* pqf = pq + (size_t)f*GG;
    for(int g=t; g<GG; g+=256){ s += psf[g]; q += pqf[g]; }
  } else {
    for(int g=t; g<GG; g+=256){ s += ps[(size_t)g*F+f]; q += pq[(size_t)g*F+f]; }
  }
  rs[t]=s; rq[t]=q; __syncthreads();
  for(int off=128; off>0; off>>=1){
    if(t<off){ rs[t]+=rs[t+off]; rq[t]+=rq[t+off]; }
    __syncthreads();
  }
  if(t==0){
    int isf = dflag[0];
    float mu  = rs[0] * (1.f/(float)NN);
    float var = rq[0] * (1.f/(float)NN) - mu*mu;
    if(var < 0.f) var = 0.f;
    float sc  = ldf(gamma,f,isf) / sqrtf(var + 1e-5f);
    stats[f]   = sc;
    stats[F+f] = ldf(beta,f,isf) - mu*sc;
  }
}

// -------- mid-tier layer2 from stored h1, wave-local (round-3, verbatim) --------
__global__ __launch_bounds__(256, 6) void k_fused2_h1(
    const void* __restrict__ ea, const float* __restrict__ eap,
    const float* __restrict__ wb, const float* __restrict__ wq,
    const float* __restrict__ h1,
    const int* __restrict__ offs, const int* __restrict__ spack, const int* __restrict__ dflag,
    float* __restrict__ gsum2, float* __restrict__ gsq2)
{
  __shared__ __align__(16) float sEaF[CAP][16];
  __shared__ float sXl2[24][12], sXr2[24][12];
  __shared__ float sEaSum[24][17];
  __shared__ float sEv[CAP];
  __shared__ int   sSl[CAP];
  __shared__ int   sRO[25];
  __shared__ float sSelfE[24];
  __shared__ float sGS[4][8], sGQ[4][8];

  const int t = threadIdx.x;
  const int g = blockIdx.x;
  const int wid = t >> 6;
  const int lane = t & 63;
  const int isf = dflag[0];
  const int nb = g*PP;
  const int eb = offs[nb];
  int ecnt = offs[nb+24] - eb; if(ecnt < 0) ecnt = 0; if(ecnt > CAP) ecnt = CAP;

  if(t < 25){
    int v = offs[nb+t] - eb;
    if(v < 0) v = 0; if(v > CAP) v = CAP;
    sRO[t] = v;
  }
  if(eap){
    for(int i=t; i<ecnt; i+=256) sSl[i] = spack[eb+i] & 1023;
    for(int i=t; i<ecnt*4; i+=256){
      int e = i>>2, q = i&3;
      *(f4_t*)&sEaF[e][q*4] = *(const f4_t*)(eap + ((size_t)(eb+e))*16 + q*4);
    }
  } else {
    for(int i=t; i<ecnt; i+=256){
      int sp = spack[eb+i];
      sSl[i] = sp & 1023;
      u32 id = ((u32)sp) >> 10;
      if(id >= (u32)EE) id = 0;
      if(isf){
        const float* er = (const float*)ea + (size_t)id*16;
        #pragma unroll
        for(int q=0;q<4;q++) *(f4_t*)&sEaF[i][q*4] = *(const f4_t*)(er + q*4);
      } else {
        #pragma unroll
        for(int c=0;c<16;c++) sEaF[i][c] = bf2f(((const u16*)ea)[(size_t)id*16 + c]);
      }
    }
  }
  {
    int rz = wid*6;
    for(int i=lane; i<6*17; i+=64) sEaSum[rz + i/17][i%17] = 0.f;
    for(int i=lane; i<96; i+=64){
      int rl = i>>4, cc = i&15;
      int r = rz + rl;
      float s = wq[oB2P + cc];
      const float* hr = h1 + ((size_t)nb + r)*32;
      #pragma unroll
      for(int q=0;q<8;q++){
        f4_t hv = *(const f4_t*)(hr + q*4);
        s += hv[0]*wq[oW2P+(q*4+0)*16+cc] + hv[1]*wq[oW2P+(q*4+1)*16+cc]
           + hv[2]*wq[oW2P+(q*4+2)*16+cc] + hv[3]*wq[oW2P+(q*4+3)*16+cc];
      }
      if(cc < 8) sXl2[r][cc] = s; else sXr2[r][cc-8] = s;
    }
  }
  __syncthreads();

  const int r0 = wid*6;
  const int a0 = sRO[r0], a1 = sRO[r0+6];
  const int c = t & 7;
  const int eo = lane >> 3;

  float wr[16];
  #pragma unroll
  for(int k=0;k<16;k++) wr[k] = wb[oWe2 + k*8 + c];
  const float av = wb[oatt2 + c];
  const float bv = wb[obo2 + c];

  for(int base=a0; base<a1; base+=8){
    int e = base + eo;
    bool valid = (e < a1);
    int ec = valid ? e : a0;
    int sp = sSl[ec];
    int sl = sp & 31; if(sl > 23) sl = 0;
    int dl = (sp >> 5) & 31; if(dl > 23) dl = 0;
    f4_t A0 = *(const f4_t*)&sEaF[ec][0];
    f4_t A1 = *(const f4_t*)&sEaF[ec][4];
    f4_t A2 = *(const f4_t*)&sEaF[ec][8];
    f4_t A3 = *(const f4_t*)&sEaF[ec][12];
    float p = A0[0]*wr[0]+A0[1]*wr[1]+A0[2]*wr[2]+A0[3]*wr[3]
            + A1[0]*wr[4]+A1[1]*wr[5]+A1[2]*wr[6]+A1[3]*wr[7]
            + A2[0]*wr[8]+A2[1]*wr[9]+A2[2]*wr[10]+A2[3]*wr[11]
            + A3[0]*wr[12]+A3[1]*wr[13]+A3[2]*wr[14]+A3[3]*wr[15];
    if(valid){
      atomicAdd(&sEaSum[dl][c],   sEaF[ec][c]);
      atomicAdd(&sEaSum[dl][c+8], sEaF[ec][c+8]);
    }
    float v = lrelu(sXl2[sl][c] + sXr2[dl][c] + p) * av;
    v += __shfl_xor(v, 4);
    v += __shfl_xor(v, 2);
    v += __shfl_xor(v, 1);
    if(valid && c == 0) sEv[e] = v;
  }

  {
    int rr = r0 + (eo < 6 ? eo : 0);
    bool valid = (eo < 6);
    int deg = sRO[rr+1] - sRO[rr];
    float invd = 1.f / (float)(deg > 0 ? deg : 1);
    float mp = 0.f;
    #pragma unroll
    for(int k=0;k<16;k++) mp += sEaSum[rr][k] * wr[k];
    float v = lrelu(sXl2[rr][c] + sXr2[rr][c] + mp*invd) * av;
    v += __shfl_xor(v, 4);
    v += __shfl_xor(v, 2);
    v += __shfl_xor(v, 1);
    if(valid && c == 0) sSelfE[rr] = v;
  }

  float gs = 0.f, gq = 0.f;
  #pragma unroll
  for(int j=0;j<6;j++){
    int r = r0 + j;
    int a = sRO[r], b = sRO[r+1];
    float selfE = sSelfE[r];
    float mx = -3.4e38f;
    for(int e=a+lane; e<b; e+=64) mx = fmaxf(mx, sEv[e]);
    mx = fmaxf(mx, __shfl_xor(mx, 32));
    mx = fmaxf(mx, __shfl_xor(mx, 16));
    mx = fmaxf(mx, __shfl_xor(mx, 8));
    mx = fmaxf(mx, __shfl_xor(mx, 4));
    mx = fmaxf(mx, __shfl_xor(mx, 2));
    mx = fmaxf(mx, __shfl_xor(mx, 1));
    float m = fmaxf(mx, selfE);
    float ds = 0.f;
    for(int e=a+lane; e<b; e+=64){
      float z = sexp(sEv[e] - m);
      sEv[e] = z;
      ds += z;
    }
    ds += __shfl_xor(ds, 32);
    ds += __shfl_xor(ds, 16);
    ds += __shfl_xor(ds, 8);
    ds += __shfl_xor(ds, 4);
    ds += __shfl_xor(ds, 2);
    ds += __shfl_xor(ds, 1);
    float selfZ = sexp(selfE - m);
    float rden = 1.f / fmaxf(ds + selfZ, 1e-30f);
    float acc = 0.f;
    for(int e=a+eo; e<b; e+=8){
      int sl = sSl[e] & 31; if(sl > 23) sl = 0;
      acc += sEv[e] * sXl2[sl][c];
    }
    acc += __shfl_xor(acc, 8);
    acc += __shfl_xor(acc, 16);
    acc += __shfl_xor(acc, 32);
    float out = (acc + selfZ * sXl2[r][c]) * rden;
    float s = 1.f / (1.f + __expf(-(out + bv)));
    if(eo == 0){ gs += s; gq += s*s; }
  }
  if(eo == 0){ sGS[wid][c] = gs; sGQ[wid][c] = gq; }
  __syncthreads();
  if(t < 8){
    gsum2[g*8+t] = sGS[0][t]+sGS[1][t]+sGS[2][t]+sGS[3][t];
    gsq2[g*8+t]  = sGQ[0][t]+sGQ[1][t]+sGQ[2][t]+sGQ[3][t];
  }
}

// -------- fallback: recompute layer1 + layer2 (ws-lean, round-3 verbatim) --------
__global__ __launch_bounds__(256) void k_fused2_rec(
    const void* __restrict__ x, const void* __restrict__ ea,
    const float* __restrict__ wb, const float* __restrict__ stats1,
    const int* __restrict__ offs, const int* __restrict__ spack, const int* __restrict__ dflag,
    float* __restrict__ gsum2, float* __restrict__ gsq2)
{
  __shared__ float sXrow[24][76];
  __shared__ float sEaF[CAP][17];
  __shared__ __align__(16) float sXl[24][36];
  __shared__ __align__(16) float sXr[24][36];
  __shared__ __align__(16) float sOut[24][36];
  __shared__ float sH[24][33];
  __shared__ float sXl2[24][12], sXr2[24][12], sOut2[24][12];
  __shared__ float sEapSum[24][32];
  __shared__ float sEv[CAP], sEz[CAP];
  __shared__ int   sSp[CAP];
  __shared__ int   sDeg[24];
  __shared__ u32   sMaxU[24];
  __shared__ float sMaxF[24], sDen[24], sSelfZ[24];
  __shared__ float sAtt[32], sBo[32], sSc[32], sSh[32];

  const int t = threadIdx.x;
  const int g = blockIdx.x;
  const int isf = dflag[0];
  int eb = offs[g*24], ee = offs[(g+1)*24];
  if(eb < 0) eb = 0; if(eb > EE) eb = EE;
  if(ee < eb) ee = eb; if(ee > EE) ee = EE;
  int ecnt = ee - eb; if(ecnt > CAP) ecnt = CAP;

  for(int i=t; i<24*74; i+=256){
    int r = i/74, c = i%74;
    sXrow[r][c] = ldf(x, (size_t)(g*PP + r)*96 + c, isf);
  }
  for(int i=t; i<CAP; i+=256) sSp[i] = (i<ecnt) ? spack[eb+i] : 0;
  if(t < 32){ sAtt[t]=wb[oatt1+t]; sBo[t]=wb[obo1+t]; sSc[t]=stats1[t]; sSh[t]=stats1[32+t]; }
  if(t < 24){ sDeg[t]=0; sMaxU[t]=0u; sDen[t]=0.f; }
  for(int i=t; i<24*32; i+=256) sEapSum[i>>5][i&31] = 0.f;
  __syncthreads();
  for(int i=t; i<CAP*16; i+=256){
    int e = i>>4, c = i&15;
    float v = 0.f;
    if(e < ecnt){
      u32 id = ((u32)sSp[e]) >> 10;
      if(id >= (u32)EE) id = 0;
      v = ldf(ea, (size_t)id*16 + c, isf);
    }
    sEaF[e][c] = v;
  }
  __syncthreads();

  {
    int c = t & 31, rr0 = t >> 5;
    for(int r = rr0; r < 24; r += 8){
      float al = wb[obl1+c], ar = wb[obr1+c];
      for(int k=0;k<74;k++){
        float xv = sXrow[r][k];
        al += xv * wb[oWl1 + k*32 + c];
        ar += xv * wb[oWr1 + k*32 + c];
      }
      sXl[r][c] = al; sXr[r][c] = ar;
    }
  }
  __syncthreads();

  for(int e=t; e<ecnt; e+=256){
    int sp = sSp[e];
    int sl = sp & 31; if(sl > 23) sl = 0;
    int dl = (sp >> 5) & 31; if(dl > 23) dl = 0;
    float ev = 0.f;
    for(int c=0;c<32;c++){
      float p = 0.f;
      for(int k=0;k<16;k++) p += sEaF[e][k] * wb[oWe1 + k*32 + c];
      atomicAdd(&sEapSum[dl][c], p);
      ev += lrelu(sXl[sl][c] + sXr[dl][c] + p) * sAtt[c];
    }
    sEv[e] = ev;
    atomicMax(&sMaxU[dl], fkey(ev));
    atomicAdd(&sDeg[dl], 1);
  }
  __syncthreads();

  if(t < 24){
    float invd = 1.f / (float)(sDeg[t] > 0 ? sDeg[t] : 1);
    float ev = 0.f;
    for(int c=0;c<32;c++)
      ev += lrelu(sXl[t][c] + sXr[t][c] + sEapSum[t][c]*invd) * sAtt[c];
    float mxv = (sDeg[t] > 0) ? fmaxf(funkey(sMaxU[t]), ev) : ev;
    sMaxF[t] = mxv;
    float z = sexp(ev - mxv);
    sSelfZ[t] = z;
    sDen[t] = z;
  }
  __syncthreads();

  for(int e=t; e<ecnt; e+=256){
    int dl = (sSp[e]>>5)&31; if(dl > 23) dl = 0;
    float z = sexp(sEv[e] - sMaxF[dl]);
    sEz[e] = z;
    atomicAdd(&sDen[dl], z);
  }
  __syncthreads();

  for(int e=t; e<ecnt; e+=256){
    int dl = (sSp[e]>>5)&31; if(dl > 23) dl = 0;
    sEz[e] /= fmaxf(sDen[dl], 1e-30f);
  }
  if(t < 24) sSelfZ[t] /= fmaxf(sDen[t], 1e-30f);
  __syncthreads();

  for(int o=t; o<24*8; o+=256){
    int nl = o >> 3, cq = (o & 7)*4;
    float al = sSelfZ[nl];
    f4_t xv = *(const f4_t*)&sXl[nl][cq];
    f4_t r;
    #pragma unroll
    for(int j=0;j<4;j++) r[j] = al*xv[j];
    *(f4_t*)&sOut[nl][cq] = r;
  }
  __syncthreads();

  for(int o=t; o<ecnt*8; o+=256){
    int e = o >> 3, cq = (o & 7)*4;
    int sp = sSp[e];
    int sl = sp & 31; if(sl > 23) sl = 0;
    int dl = (sp >> 5) & 31; if(dl > 23) dl = 0;
    float al = sEz[e];
    f4_t xv = *(const f4_t*)&sXl[sl][cq];
    atomicAdd(&sOut[dl][cq+0], al*xv[0]);
    atomicAdd(&sOut[dl][cq+1], al*xv[1]);
    atomicAdd(&sOut[dl][cq+2], al*xv[2]);
    atomicAdd(&sOut[dl][cq+3], al*xv[3]);
  }
  __syncthreads();

  for(int i=t; i<24*32; i+=256){
    int r = i>>5, c = i&31;
    float v = fmaxf(sOut[r][c] + sBo[c], 0.f);
    sH[r][c] = v*sSc[c] + sSh[c];
  }
  __syncthreads();
  if(t < 24){ sDeg[t]=0; sMaxU[t]=0u; sDen[t]=0.f; }
  for(int i=t; i<24*8; i+=256) sEapSum[i>>3][i&7] = 0.f;
  __syncthreads();

  if(t < 24*8*2){
    int mat = t/192, rem = t%192, r = rem/8, c = rem&7;
    const float* Wm = wb + (mat ? oWr2 : oWl2);
    float s = wb[(mat ? obr2 : obl2) + c];
    for(int k=0;k<32;k++) s += sH[r][k]*Wm[k*8+c];
    if(mat) sXr2[r][c] = s; else sXl2[r][c] = s;
  }
  __syncthreads();

  for(int e=t; e<ecnt; e+=256){
    int sp = sSp[e];
    int sl = sp & 31; if(sl > 23) sl = 0;
    int dl = (sp >> 5) & 31; if(dl > 23) dl = 0;
    float ev = 0.f;
    for(int c=0;c<8;c++){
      float p = 0.f;
      for(int k=0;k<16;k++) p += sEaF[e][k] * wb[oWe2 + k*8 + c];
      atomicAdd(&sEapSum[dl][c], p);
      ev += lrelu(sXl2[sl][c] + sXr2[dl][c] + p) * wb[oatt2+c];
    }
    sEv[e] = ev;
    atomicMax(&sMaxU[dl], fkey(ev));
    atomicAdd(&sDeg[dl], 1);
  }
  __syncthreads();

  if(t < 24){
    float invd = 1.f / (float)(sDeg[t] > 0 ? sDeg[t] : 1);
    float ev = 0.f;
    for(int c=0;c<8;c++)
      ev += lrelu(sXl2[t][c] + sXr2[t][c] + sEapSum[t][c]*invd) * wb[oatt2+c];
    float mxv = (sDeg[t] > 0) ? fmaxf(funkey(sMaxU[t]), ev) : ev;
    sMaxF[t] = mxv;
    float z = sexp(ev - mxv);
    sSelfZ[t] = z;
    sDen[t] = z;
  }
  __syncthreads();

  for(int e=t; e<ecnt; e+=256){
    int dl = (sSp[e]>>5)&31; if(dl > 23) dl = 0;
    float z = sexp(sEv[e] - sMaxF[dl]);
    sEz[e] = z;
    atomicAdd(&sDen[dl], z);
  }
  __syncthreads();

  for(int e=t; e<ecnt; e+=256){
    int dl = (sSp[e]>>5)&31; if(dl > 23) dl = 0;
    sEz[e] /= fmaxf(sDen[dl], 1e-30f);
  }
  if(t < 24) sSelfZ[t] /= fmaxf(sDen[t], 1e-30f);
  __syncthreads();

  for(int o=t; o<24*8; o+=256){
    int nl = o >> 3, c = o & 7;
    sOut2[nl][c] = sSelfZ[nl] * sXl2[nl][c];
  }
  __syncthreads();

  for(int o=t; o<ecnt*8; o+=256){
    int e = o >> 3, c = o & 7;
    int sp = sSp[e];
    int sl = sp & 31; if(sl > 23) sl = 0;
    int dl = (sp >> 5) & 31; if(dl > 23) dl = 0;
    atomicAdd(&sOut2[dl][c], sEz[e]*sXl2[sl][c]);
  }
  __syncthreads();

  if(t < 8){
    float gs=0.f, gq=0.f;
    for(int nl=0; nl<24; nl++){
      float v = sOut2[nl][t] + wb[obo2+t];
      float s = 1.f / (1.f + __expf(-v));
      gs += s; gq += s*s;
    }
    gsum2[g*8+t] = gs; gsq2[g*8+t] = gq;
  }
}

// ---------------- MLP head (128 blocks x 64 threads) ----------------
__global__ __launch_bounds__(64) void k_mlp(
    const float* __restrict__ gsum2, const float* __restrict__ stats2,
    const void* __restrict__ x, const int* __restrict__ dflag,
    const float* __restrict__ wb, float* __restrict__ out)
{
  __shared__ float w[1702];
  int t = threadIdx.x;
  for(int i=t; i<1702; i+=64) w[i] = wb[6048+i];
  __syncthreads();
  int g = blockIdx.x*64 + t;
  int isf = dflag[0];
  float a[30], b[32];
  for(int c=0;c<8;c++) a[c] = stats2[c]*(gsum2[(size_t)g*8+c]*(1.f/24.f)) + stats2[8+c];
  size_t xoff = (size_t)g*PP*96 + 74;
  for(int j=0;j<22;j++) a[8+j] = ldf(x, xoff+j, isf);
  for(int o=0;o<32;o++){ float s = w[960+o];  for(int i=0;i<30;i++) s += a[i]*w[i*32+o];      b[o]=fmaxf(s,0.f); }
  for(int o=0;o<16;o++){ float s = w[1504+o]; for(int i=0;i<32;i++) s += b[i]*w[992+i*16+o];  a[o]=fmaxf(s,0.f); }
  for(int o=0;o<8;o++){  float s = w[1648+o]; for(int i=0;i<16;i++) s += a[i]*w[1520+i*8+o];  b[o]=fmaxf(s,0.f); }
  for(int o=0;o<4;o++){  float s = w[1688+o]; for(int i=0;i<8;i++)  s += b[i]*w[1656+i*4+o];  a[o]=fmaxf(s,0.f); }
  for(int o=0;o<2;o++){
    float s = w[1700+o];
    for(int i=0;i<4;i++) s += a[i]*w[1692+i*2+o];
    out[(size_t)g*2+o] = s;
  }
}

extern "C" void kernel_launch(void* const* d_in, const int* in_sizes, int n_in,
                              void* d_out, int out_size, void* d_ws, size_t ws_size,
                              hipStream_t stream)
{
  (void)in_sizes; (void)n_in; (void)out_size;
  const void* x    = d_in[0];
  const int* eidx  = (const int*)d_in[1];
  const void* ea   = d_in[2];

  const int* srcA = eidx;
  const int* dstA = eidx + EE;

  constexpr size_t O_WB    = 0;
  constexpr size_t O_WQ    = 32768;
  constexpr size_t O_OFFS  = 57344;
  constexpr size_t O_CUR   = O_OFFS + (size_t)(NN+512)*4;
  constexpr size_t O_SPACK = O_CUR  + (size_t)NN*4;
  constexpr size_t O_P1S   = O_SPACK + (size_t)EE*4;
  constexpr size_t O_P1Q   = O_P1S   + (size_t)GG*32*4;
  constexpr size_t O_ST1   = O_P1Q   + (size_t)GG*32*4;
  constexpr size_t O_GS2   = O_ST1   + 256;
  constexpr size_t O_GQ2   = O_GS2   + (size_t)GG*8*4;
  constexpr size_t O_ST2   = O_GQ2   + (size_t)GG*8*4;
  constexpr size_t O_FLAG  = O_ST2   + 256;
  constexpr size_t REQUIRED_BASE = O_FLAG + 256;
  constexpr size_t O_H1    = REQUIRED_BASE;
  constexpr size_t REQUIRED_BIG = O_H1 + (size_t)NN*32*4;
  constexpr size_t O_EAP1  = REQUIRED_BIG;                       // eap: EE*16 f32 (or u16 when bf16)
  constexpr size_t REQUIRED_P     = O_EAP1 + (size_t)EE*16*4;
  constexpr size_t REQUIRED_EAP16 = O_EAP1 + (size_t)EE*16*4;

  if(ws_size < REQUIRED_BASE){
    k_zero<<<(GG*2+255)/256, 256, 0, stream>>>((float*)d_out);
    return;
  }
  const int use_h1  = (ws_size >= REQUIRED_BIG)   ? 1 : 0;
  const int use_p   = (use_h1 && ws_size >= REQUIRED_P) ? 1 : 0;
  const int use_eap = (!use_p && ws_size >= REQUIRED_EAP16) ? 1 : 0;

  char* W = (char*)d_ws;
  float* wb     = (float*)(W + O_WB);
  float* wq     = (float*)(W + O_WQ);
  int*   offs   = (int*)(W + O_OFFS);
  int*   bsum   = offs + NN + 64;
  int*   cnt    = (int*)(W + O_CUR);
  int*   cursor = (int*)(W + O_CUR);
  int*   spack  = (int*)(W + O_SPACK);
  float* p1sum  = (float*)(W + O_P1S);
  float* p1sq   = (float*)(W + O_P1Q);
  float* stats1 = (float*)(W + O_ST1);
  float* gsum2  = (float*)(W + O_GS2);
  float* gsq2   = (float*)(W + O_GQ2);
  float* stats2 = (float*)(W + O_ST2);
  int*   dflag  = (int*)(W + O_FLAG);
  float* h1     = (float*)(W + O_H1);
  void*  eap1   = (void*)(W + O_EAP1);

  hipMemsetAsync(cnt, 0, (size_t)NN*sizeof(int), stream);
  k_count  <<<EE/256, 256, 0, stream>>>(dstA, cnt);
  k_scanA  <<<192, 1024, 0, stream>>>(cnt, offs, bsum);
  k_scanB  <<<1, 256, 0, stream>>>(bsum, offs);
  k_scanC  <<<192, 1024, 0, stream>>>(offs, bsum, cursor);
  k_scatter<<<EE/256, 256, 0, stream>>>(srcA, dstA, cursor, spack);
  k_wconv  <<<8, 256, 0, stream>>>(wb, wq, dflag, (const u32*)x,
            d_in[4], d_in[5], d_in[6], d_in[7], d_in[8], d_in[9], d_in[10],
            d_in[11], d_in[12], d_in[13], d_in[14], d_in[15], d_in[16], d_in[17],
            d_in[22], d_in[23], d_in[24], d_in[25], d_in[26], d_in[27],
            d_in[28], d_in[29], d_in[30], d_in[31]);
  if(use_p){
    k_eapermB<<<EE/256, 256, 0, stream>>>(spack, offs, ea, dflag, eap1);
    k_l1stats_p<<<GG, 256, 0, stream>>>(x, eap1, wb, wq, offs, spack, dflag,
                                        p1sum, p1sq, h1);
    k_reduce <<<32, 256, 0, stream>>>(p1sum, p1sq, d_in[18], d_in[19], dflag, stats1, 32, 1);
  } else {
    if(use_eap)
      k_eaperm<<<EE/256, 256, 0, stream>>>(spack, offs, ea, dflag, (float*)eap1);
    k_l1stats<<<GG, 256, 0, stream>>>(x, ea, use_eap ? (float*)eap1 : (float*)nullptr,
                                      wb, wq, offs, spack, dflag,
                                      p1sum, p1sq, h1, use_h1);
    k_reduce <<<32, 256, 0, stream>>>(p1sum, p1sq, d_in[18], d_in[19], dflag, stats1, 32, 1);
  }
  k_prep2  <<<1, 256, 0, stream>>>(wq, wb, stats1);
  if(use_p)
    k_fused2_p<<<GG, 256, 0, stream>>>(eap1, dflag, wb, wq, h1, offs, spack, gsum2, gsq2);
  else if(use_h1)
    k_fused2_h1<<<GG, 256, 0, stream>>>(ea, use_eap ? (float*)eap1 : (float*)nullptr,
                                        wb, wq, h1, offs, spack, dflag, gsum2, gsq2);
  else
    k_fused2_rec<<<GG, 256, 0, stream>>>(x, ea, wb, stats1, offs, spack, dflag, gsum2, gsq2);
  k_reduce <<<8, 256, 0, stream>>>(gsum2, gsq2, d_in[20], d_in[21], dflag, stats2, 8, 0);
  k_mlp    <<<GG/64, 64, 0, stream>>>(gsum2, stats2, x, dflag, wb, (float*)d_out);
}